// Round 5
// baseline (1591.074 us; speedup 1.0000x reference)
//
#include <hip/hip_runtime.h>
#include <math.h>

#define H 128
#define I_DIM 128
#define T_STEPS 30
#define M_MODES 6
#define N_AG 8192
#define B_TOT (M_MODES * N_AG)   /* 49152 */
#define LN_EPS 1e-5f
#define MIN_SCALE 0.001f

typedef short bf16x8 __attribute__((ext_vector_type(8)));
typedef float f32x4 __attribute__((ext_vector_type(4)));

#define MFMA16x16x32(A, B, C) __builtin_amdgcn_mfma_f32_16x16x32_bf16(A, B, C, 0, 0, 0)

__device__ __forceinline__ short f2b(float f) {
    union { float f; unsigned u; } v; v.f = f;
    return (short)((v.u + 0x7FFFu + ((v.u >> 16) & 1u)) >> 16);
}

__device__ __forceinline__ bf16x8 load8_cvt(const float* __restrict__ p) {
    const float4 a = ((const float4*)p)[0];
    const float4 b = ((const float4*)p)[1];
    bf16x8 r;
    r[0]=f2b(a.x); r[1]=f2b(a.y); r[2]=f2b(a.z); r[3]=f2b(a.w);
    r[4]=f2b(b.x); r[5]=f2b(b.y); r[6]=f2b(b.z); r[7]=f2b(b.w);
    return r;
}

__device__ __forceinline__ float fast_sigm(float x) {
    return __builtin_amdgcn_rcpf(1.f + __expf(-x));
}
__device__ __forceinline__ float fast_tanh(float x) {
    return 1.f - 2.f * __builtin_amdgcn_rcpf(1.f + __expf(2.f * x));
}

// ===========================================================================
// Fused GRU recurrence + loc/scale heads. 3072 blocks x 256 thr (4 waves),
// 16 rows/block. Iteration i: A-frags of h(i) feed BOTH the gh GEMM and the
// heads GEMM (output index i-1). Heads epilogue folds around the two
// existing per-step barriers. No h-history materialization.
// Wave roles: GRU -> wave w owns hidden ch [32w,32w+32) of all 3 gates;
//             heads -> head = w>>1 (loc/sc), channel half = w&1.
// ===========================================================================
__global__ __launch_bounds__(256, 2) void gru_fused_kernel(
    const float* __restrict__ local_embed, const float* __restrict__ global_embed,
    const float* __restrict__ W_ih, const float* __restrict__ W_hh,
    const float* __restrict__ b_ih, const float* __restrict__ b_hh,
    const float* __restrict__ loc1_w, const float* __restrict__ loc1_b,
    const float* __restrict__ loc_ln_g, const float* __restrict__ loc_ln_b,
    const float* __restrict__ loc2_w, const float* __restrict__ loc2_b,
    const float* __restrict__ sc1_w, const float* __restrict__ sc1_b,
    const float* __restrict__ sc_ln_g, const float* __restrict__ sc_ln_b,
    const float* __restrict__ sc2_w, const float* __restrict__ sc2_b,
    float* __restrict__ traj)
{
    __shared__ short xbuf[16][136];        // padded: row stride 272 B
    __shared__ short hbf[16][136];
    __shared__ float red[2][16][4];        // [head][row][s0,q0,s1,q1]
    __shared__ float red2[2][16][2][2];    // [head][row][pairwave][o]

    const int tid = threadIdx.x;
    const int w  = tid >> 6;               // wave 0..3
    const int l  = tid & 63;
    const int ln = l & 15;                 // D col / A row / B col
    const int lg = l >> 4;                 // D row group / A,B k group
    const int head = w >> 1;               // 0 = loc, 1 = sc
    const int wp = w & 1;                  // channel half within head
    const int b0 = blockIdx.x * 16;

    // ---- stage x (bf16) and h0 (fp32 regs + bf16 LDS) ----
    float h_reg[2][4];
    #pragma unroll
    for (int u = 0; u < 2; ++u) {
        const int j = 32*w + 16*u + ln;
        #pragma unroll
        for (int rg = 0; rg < 4; ++rg) {
            const int r = lg*4 + rg;
            const int b = b0 + r;
            const int n = b & (N_AG - 1);
            xbuf[r][j] = f2b(global_embed[(size_t)b * I_DIM + j]);
            const float h0 = local_embed[(size_t)n * H + j];
            h_reg[u][rg] = h0;
            hbf[r][j] = f2b(h0);
        }
    }

    // ---- W_ih B-fragments (temporary; overwritten by W_hh below) ----
    bf16x8 wf[3][2][4];
    #pragma unroll
    for (int g = 0; g < 3; ++g)
        #pragma unroll
        for (int u = 0; u < 2; ++u) {
            const int crow = g*H + 32*w + 16*u + ln;
            #pragma unroll
            for (int kt = 0; kt < 4; ++kt)
                wf[g][u][kt] = load8_cvt(W_ih + (size_t)crow * I_DIM + kt*32 + lg*8);
        }

    __syncthreads();

    // ---- gx = x @ W_ih^T + b_ih (once; same input every timestep) ----
    float gx[3][2][4];
    {
        bf16x8 af[4];
        #pragma unroll
        for (int kt = 0; kt < 4; ++kt)
            af[kt] = *(const bf16x8*)&xbuf[ln][kt*32 + lg*8];
        f32x4 acc[3][2];
        #pragma unroll
        for (int g = 0; g < 3; ++g)
            #pragma unroll
            for (int u = 0; u < 2; ++u)
                acc[g][u] = (f32x4)(0.f);
        #pragma unroll
        for (int kt = 0; kt < 4; ++kt)
            #pragma unroll
            for (int g = 0; g < 3; ++g)
                #pragma unroll
                for (int u = 0; u < 2; ++u)
                    acc[g][u] = MFMA16x16x32(af[kt], wf[g][u][kt], acc[g][u]);
        #pragma unroll
        for (int g = 0; g < 3; ++g)
            #pragma unroll
            for (int u = 0; u < 2; ++u) {
                const float bi = b_ih[g*H + 32*w + 16*u + ln];
                #pragma unroll
                for (int rg = 0; rg < 4; ++rg)
                    gx[g][u][rg] = acc[g][u][rg] + bi;
            }
    }

    // ---- W_hh B-fragments; fold bhr/bhz into gx (bhn multiplies by r) ----
    float bhn[2];
    #pragma unroll
    for (int u = 0; u < 2; ++u) {
        const int c = 32*w + 16*u + ln;
        const float bhr = b_hh[c], bhz = b_hh[H + c];
        bhn[u] = b_hh[2*H + c];
        #pragma unroll
        for (int rg = 0; rg < 4; ++rg) { gx[0][u][rg] += bhr; gx[1][u][rg] += bhz; }
        #pragma unroll
        for (int g = 0; g < 3; ++g) {
            const int crow = g*H + c;
            #pragma unroll
            for (int kt = 0; kt < 4; ++kt)
                wf[g][u][kt] = load8_cvt(W_hh + (size_t)crow * H + kt*32 + lg*8);
        }
    }

    // ---- heads weights + params (per wave: head, channel half) ----
    const float* __restrict__ W1  = head ? sc1_w   : loc1_w;
    const float* __restrict__ B1v = head ? sc1_b   : loc1_b;
    const float* __restrict__ Gv  = head ? sc_ln_g : loc_ln_g;
    const float* __restrict__ Bv  = head ? sc_ln_b : loc_ln_b;
    const float* __restrict__ W2  = head ? sc2_w   : loc2_w;

    bf16x8 whf[4][4];
    float bias1[4], lng[4], lnb[4], w2a[4], w2b[4];
    #pragma unroll
    for (int nt = 0; nt < 4; ++nt) {
        const int c = 64*wp + 16*nt + ln;
        #pragma unroll
        for (int kt = 0; kt < 4; ++kt)
            whf[nt][kt] = load8_cvt(W1 + (size_t)c * H + kt*32 + lg*8);
        bias1[nt] = B1v[c]; lng[nt] = Gv[c]; lnb[nt] = Bv[c];
        w2a[nt] = W2[c];    w2b[nt] = W2[H + c];
    }
    // store-stage bias (threads 0..63: o = tid&3 -> head o>>1, out o&1)
    float b2s = 0.f;
    if (tid < 64) {
        const int o = tid & 3;
        b2s = (o >= 2) ? sc2_b[o - 2] : loc2_b[o];
    }

    // ======================= main loop: i = 0..T ==========================
    for (int i = 0; i <= T_STEPS; ++i) {
        const bool do_g = (i < T_STEPS);   // block-uniform
        const bool do_h = (i > 0);

        // A-frags of h(i)
        bf16x8 af[4];
        #pragma unroll
        for (int kt = 0; kt < 4; ++kt)
            af[kt] = *(const bf16x8*)&hbf[ln][kt*32 + lg*8];

        // gh GEMM
        f32x4 ga[3][2];
        if (do_g) {
            #pragma unroll
            for (int g = 0; g < 3; ++g)
                #pragma unroll
                for (int u = 0; u < 2; ++u) ga[g][u] = (f32x4)(0.f);
            #pragma unroll
            for (int kt = 0; kt < 4; ++kt)
                #pragma unroll
                for (int g = 0; g < 3; ++g)
                    #pragma unroll
                    for (int u = 0; u < 2; ++u)
                        ga[g][u] = MFMA16x16x32(af[kt], wf[g][u][kt], ga[g][u]);
        }

        // heads GEMM on the SAME fragments (output index i-1)
        f32x4 ha[4];
        if (do_h) {
            #pragma unroll
            for (int nt = 0; nt < 4; ++nt) ha[nt] = (f32x4)(0.f);
            #pragma unroll
            for (int kt = 0; kt < 4; ++kt)
                #pragma unroll
                for (int nt = 0; nt < 4; ++nt)
                    ha[nt] = MFMA16x16x32(af[kt], whf[nt][kt], ha[nt]);
        }

        // gates -> h(i+1)
        unsigned short hb[2][4];
        if (do_g) {
            #pragma unroll
            for (int u = 0; u < 2; ++u) {
                #pragma unroll
                for (int rg = 0; rg < 4; ++rg) {
                    const float rr = fast_sigm(gx[0][u][rg] + ga[0][u][rg]);
                    const float zz = fast_sigm(gx[1][u][rg] + ga[1][u][rg]);
                    const float nn = fast_tanh(gx[2][u][rg] + rr * (ga[2][u][rg] + bhn[u]));
                    const float h  = (1.f - zz) * nn + zz * h_reg[u][rg];
                    h_reg[u][rg] = h;
                    hb[u][rg] = (unsigned short)f2b(h);
                }
            }
        }

        // heads LN stats partials (pre-B1)
        if (do_h) {
            #pragma unroll
            for (int rg = 0; rg < 4; ++rg) {
                float s = 0.f, q = 0.f;
                #pragma unroll
                for (int nt = 0; nt < 4; ++nt) {
                    const float a = ha[nt][rg] + bias1[nt];
                    ha[nt][rg] = a;
                    s += a; q += a*a;
                }
                #pragma unroll
                for (int off = 1; off < 16; off <<= 1) {
                    s += __shfl_xor(s, off);
                    q += __shfl_xor(q, off);
                }
                if (ln == 0) {
                    const int row = lg*4 + rg;
                    red[head][row][wp*2+0] = s;
                    red[head][row][wp*2+1] = q;
                }
            }
        }
        __syncthreads();   // B1: af reads done, red visible

        // write h(i+1)
        if (do_g) {
            #pragma unroll
            for (int u = 0; u < 2; ++u) {
                const int j = 32*w + 16*u + ln;
                #pragma unroll
                for (int rg = 0; rg < 4; ++rg)
                    hbf[lg*4 + rg][j] = (short)hb[u][rg];
            }
        }

        // heads LN + relu + linear-2 partials
        if (do_h) {
            #pragma unroll
            for (int rg = 0; rg < 4; ++rg) {
                const int row = lg*4 + rg;
                const float4 rv = *(const float4*)&red[head][row][0];
                const float S = rv.x + rv.z, Q = rv.y + rv.w;
                const float mu = S * (1.f/H);
                const float var = Q * (1.f/H) - mu*mu;
                const float rs = rsqrtf(var + LN_EPS);
                float p0 = 0.f, p1 = 0.f;
                #pragma unroll
                for (int nt = 0; nt < 4; ++nt) {
                    float v = (ha[nt][rg] - mu) * rs * lng[nt] + lnb[nt];
                    v = fmaxf(v, 0.f);
                    p0 += v * w2a[nt];
                    p1 += v * w2b[nt];
                }
                #pragma unroll
                for (int off = 1; off < 16; off <<= 1) {
                    p0 += __shfl_xor(p0, off);
                    p1 += __shfl_xor(p1, off);
                }
                if (ln == 0) {
                    red2[head][row][wp][0] = p0;
                    red2[head][row][wp][1] = p1;
                }
            }
        }
        __syncthreads();   // B2: h(i+1) + red2 visible

        // store outputs for t = i-1
        if (do_h && tid < 64) {
            const int row = tid >> 2;
            const int o   = tid & 3;
            const int hd  = o >> 1;
            const int oo  = o & 1;
            float val = red2[hd][row][0][oo] + red2[hd][row][1][oo] + b2s;
            if (hd) val = (val > 0.f ? val : expm1f(val)) + 1.0f + MIN_SCALE;
            traj[((size_t)(b0 + row) * T_STEPS + (i - 1)) * 4 + o] = val;
        }
    }
}

// ===========================================================================
// pi head: weight-stationary persistent blocks. 768 blocks x 256 thr,
// grid-striding 1536 tiles of 32 rows.
// ===========================================================================
__global__ __launch_bounds__(256, 2) void pi_persist_kernel(
    const float* __restrict__ local_embed, const float* __restrict__ global_embed,
    const float* __restrict__ pi1_w, const float* __restrict__ pi1_b,
    const float* __restrict__ ln1_g, const float* __restrict__ ln1_b,
    const float* __restrict__ pi2_w, const float* __restrict__ pi2_b,
    const float* __restrict__ ln2_g, const float* __restrict__ ln2_b,
    const float* __restrict__ pi3_w, const float* __restrict__ pi3_b,
    float* __restrict__ pi_out)
{
    __shared__ short inbf[32][264];        // 32 rows x 256 cols
    __shared__ short h1bf[32][136];        // 32 rows x 128 cols
    __shared__ float redL[4][32][2];       // [wave][row][s,q]
    __shared__ float red3[4][32];

    const int tid = threadIdx.x;
    const int w  = tid >> 6;
    const int l  = tid & 63;
    const int ln = l & 15;
    const int lg = l >> 4;

    // ---- weights/params loaded ONCE, stationary in VGPRs ----
    bf16x8 wf1[2][8];
    bf16x8 wf2[2][4];
    float b1[2], g1[2], bb1[2], b2[2], g2[2], bb2[2], w3[2];
    #pragma unroll
    for (int nt = 0; nt < 2; ++nt) {
        const int c = 32*w + 16*nt + ln;
        #pragma unroll
        for (int kt = 0; kt < 8; ++kt)
            wf1[nt][kt] = load8_cvt(pi1_w + (size_t)c * (2*H) + kt*32 + lg*8);
        #pragma unroll
        for (int kt = 0; kt < 4; ++kt)
            wf2[nt][kt] = load8_cvt(pi2_w + (size_t)c * H + kt*32 + lg*8);
        b1[nt] = pi1_b[c]; g1[nt] = ln1_g[c]; bb1[nt] = ln1_b[c];
        b2[nt] = pi2_b[c]; g2[nt] = ln2_g[c]; bb2[nt] = ln2_b[c];
        w3[nt] = pi3_w[c];
    }
    const float b3 = pi3_b[0];

    const int ntiles = B_TOT / 32;

    for (int it = blockIdx.x; it < ntiles; it += gridDim.x) {
        const int r0 = it * 32;

        // ---- stage 32 input rows [local(128) | global(128)] as bf16 ----
        {
            const int r   = tid >> 3;
            const int seg = tid & 7;
            const int b = r0 + r;
            const int n = b & (N_AG - 1);
            const float* src = (seg < 4) ? (local_embed + (size_t)n * H + seg * 32)
                                         : (global_embed + (size_t)b * I_DIM + (seg - 4) * 32);
            short tmp[32];
            #pragma unroll
            for (int i = 0; i < 8; ++i) {
                const float4 v = ((const float4*)src)[i];
                tmp[i*4+0]=f2b(v.x); tmp[i*4+1]=f2b(v.y); tmp[i*4+2]=f2b(v.z); tmp[i*4+3]=f2b(v.w);
            }
            #pragma unroll
            for (int i = 0; i < 4; ++i)
                *(uint4*)&inbf[r][seg*32 + i*8] = *(uint4*)&tmp[i*8];
        }
        __syncthreads();

        // ---- layer 1 ----
        f32x4 acc1[2][2];
        #pragma unroll
        for (int m = 0; m < 2; ++m) {
            #pragma unroll
            for (int nt = 0; nt < 2; ++nt) acc1[m][nt] = (f32x4)(0.f);
            bf16x8 af[8];
            #pragma unroll
            for (int kt = 0; kt < 8; ++kt)
                af[kt] = *(const bf16x8*)&inbf[m*16 + ln][kt*32 + lg*8];
            #pragma unroll
            for (int kt = 0; kt < 8; ++kt)
                #pragma unroll
                for (int nt = 0; nt < 2; ++nt)
                    acc1[m][nt] = MFMA16x16x32(af[kt], wf1[nt][kt], acc1[m][nt]);
        }

        #pragma unroll
        for (int m = 0; m < 2; ++m)
            #pragma unroll
            for (int rg = 0; rg < 4; ++rg) {
                float s = 0.f, q = 0.f;
                #pragma unroll
                for (int nt = 0; nt < 2; ++nt) {
                    const float a = acc1[m][nt][rg] + b1[nt];
                    acc1[m][nt][rg] = a;
                    s += a; q += a*a;
                }
                #pragma unroll
                for (int off = 1; off < 16; off <<= 1) {
                    s += __shfl_xor(s, off);
                    q += __shfl_xor(q, off);
                }
                if (ln == 0) {
                    const int row = m*16 + lg*4 + rg;
                    redL[w][row][0] = s;
                    redL[w][row][1] = q;
                }
            }
        __syncthreads();

        #pragma unroll
        for (int m = 0; m < 2; ++m)
            #pragma unroll
            for (int rg = 0; rg < 4; ++rg) {
                const int row = m*16 + lg*4 + rg;
                const float S = redL[0][row][0] + redL[1][row][0] + redL[2][row][0] + redL[3][row][0];
                const float Q = redL[0][row][1] + redL[1][row][1] + redL[2][row][1] + redL[3][row][1];
                const float mu = S * (1.f/H);
                const float var = Q * (1.f/H) - mu*mu;
                const float rs = rsqrtf(var + LN_EPS);
                #pragma unroll
                for (int nt = 0; nt < 2; ++nt) {
                    const float v = fmaxf((acc1[m][nt][rg] - mu) * rs * g1[nt] + bb1[nt], 0.f);
                    h1bf[row][32*w + 16*nt + ln] = f2b(v);
                }
            }
        __syncthreads();

        // ---- layer 2 ----
        f32x4 acc2[2][2];
        #pragma unroll
        for (int m = 0; m < 2; ++m) {
            #pragma unroll
            for (int nt = 0; nt < 2; ++nt) acc2[m][nt] = (f32x4)(0.f);
            bf16x8 af[4];
            #pragma unroll
            for (int kt = 0; kt < 4; ++kt)
                af[kt] = *(const bf16x8*)&h1bf[m*16 + ln][kt*32 + lg*8];
            #pragma unroll
            for (int kt = 0; kt < 4; ++kt)
                #pragma unroll
                for (int nt = 0; nt < 2; ++nt)
                    acc2[m][nt] = MFMA16x16x32(af[kt], wf2[nt][kt], acc2[m][nt]);
        }

        #pragma unroll
        for (int m = 0; m < 2; ++m)
            #pragma unroll
            for (int rg = 0; rg < 4; ++rg) {
                float s = 0.f, q = 0.f;
                #pragma unroll
                for (int nt = 0; nt < 2; ++nt) {
                    const float a = acc2[m][nt][rg] + b2[nt];
                    acc2[m][nt][rg] = a;
                    s += a; q += a*a;
                }
                #pragma unroll
                for (int off = 1; off < 16; off <<= 1) {
                    s += __shfl_xor(s, off);
                    q += __shfl_xor(q, off);
                }
                if (ln == 0) {
                    const int row = m*16 + lg*4 + rg;
                    redL[w][row][0] = s;
                    redL[w][row][1] = q;
                }
            }
        __syncthreads();

        #pragma unroll
        for (int m = 0; m < 2; ++m)
            #pragma unroll
            for (int rg = 0; rg < 4; ++rg) {
                const int row = m*16 + lg*4 + rg;
                const float S = redL[0][row][0] + redL[1][row][0] + redL[2][row][0] + redL[3][row][0];
                const float Q = redL[0][row][1] + redL[1][row][1] + redL[2][row][1] + redL[3][row][1];
                const float mu = S * (1.f/H);
                const float var = Q * (1.f/H) - mu*mu;
                const float rs = rsqrtf(var + LN_EPS);
                float p = 0.f;
                #pragma unroll
                for (int nt = 0; nt < 2; ++nt) {
                    const float v = fmaxf((acc2[m][nt][rg] - mu) * rs * g2[nt] + bb2[nt], 0.f);
                    p += v * w3[nt];
                }
                #pragma unroll
                for (int off = 1; off < 16; off <<= 1) p += __shfl_xor(p, off);
                if (ln == 0) red3[w][row] = p;
            }
        __syncthreads();

        if (tid < 32) {
            const int row = tid;
            const float p = red3[0][row] + red3[1][row] + red3[2][row] + red3[3][row] + b3;
            const int b = r0 + row;
            const int n = b & (N_AG - 1);
            const int m = b >> 13;
            pi_out[(size_t)n * M_MODES + m] = p;
        }
        __syncthreads();   // red3 reads done before next tile's redL writes
    }
}

extern "C" void kernel_launch(void* const* d_in, const int* in_sizes, int n_in,
                              void* d_out, int out_size, void* d_ws, size_t ws_size,
                              hipStream_t stream) {
    (void)in_sizes; (void)n_in; (void)out_size; (void)d_ws; (void)ws_size;
    const float* local_embed  = (const float*)d_in[0];
    const float* global_embed = (const float*)d_in[1];
    const float* W_ih   = (const float*)d_in[2];
    const float* W_hh   = (const float*)d_in[3];
    const float* b_ih   = (const float*)d_in[4];
    const float* b_hh   = (const float*)d_in[5];
    const float* loc1_w = (const float*)d_in[6];
    const float* loc1_b = (const float*)d_in[7];
    const float* loc_ln_g = (const float*)d_in[8];
    const float* loc_ln_b = (const float*)d_in[9];
    const float* loc2_w = (const float*)d_in[10];
    const float* loc2_b = (const float*)d_in[11];
    const float* sc1_w  = (const float*)d_in[12];
    const float* sc1_b  = (const float*)d_in[13];
    const float* sc_ln_g = (const float*)d_in[14];
    const float* sc_ln_b = (const float*)d_in[15];
    const float* sc2_w  = (const float*)d_in[16];
    const float* sc2_b  = (const float*)d_in[17];
    const float* pi1_w  = (const float*)d_in[18];
    const float* pi1_b  = (const float*)d_in[19];
    const float* pi_ln1_g = (const float*)d_in[20];
    const float* pi_ln1_b = (const float*)d_in[21];
    const float* pi2_w  = (const float*)d_in[22];
    const float* pi2_b  = (const float*)d_in[23];
    const float* pi_ln2_g = (const float*)d_in[24];
    const float* pi_ln2_b = (const float*)d_in[25];
    const float* pi3_w  = (const float*)d_in[26];
    const float* pi3_b  = (const float*)d_in[27];

    float* traj = (float*)d_out;
    float* pi_out = traj + (size_t)B_TOT * T_STEPS * 4;

    pi_persist_kernel<<<768, 256, 0, stream>>>(
        local_embed, global_embed, pi1_w, pi1_b, pi_ln1_g, pi_ln1_b,
        pi2_w, pi2_b, pi_ln2_g, pi_ln2_b, pi3_w, pi3_b, pi_out);

    gru_fused_kernel<<<B_TOT / 16, 256, 0, stream>>>(
        local_embed, global_embed, W_ih, W_hh, b_ih, b_hh,
        loc1_w, loc1_b, loc_ln_g, loc_ln_b, loc2_w, loc2_b,
        sc1_w, sc1_b, sc_ln_g, sc_ln_b, sc2_w, sc2_b, traj);
}

// Round 6
// 1015.469 us; speedup vs baseline: 1.5668x; 1.5668x over previous
//
#include <hip/hip_runtime.h>
#include <math.h>

#define H 128
#define I_DIM 128
#define T_STEPS 30
#define M_MODES 6
#define N_AG 8192
#define B_TOT (M_MODES * N_AG)   /* 49152 */
#define ROWS 16
#define LN_EPS 1e-5f
#define MIN_SCALE 0.001f

typedef short bf16x8 __attribute__((ext_vector_type(8)));
typedef float f32x4 __attribute__((ext_vector_type(4)));

#define MFMA16x16x32(A, B, C) __builtin_amdgcn_mfma_f32_16x16x32_bf16(A, B, C, 0, 0, 0)

__device__ __forceinline__ short f2b(float f) {
    union { float f; unsigned u; } v; v.f = f;
    return (short)((v.u + 0x7FFFu + ((v.u >> 16) & 1u)) >> 16);
}

__device__ __forceinline__ bf16x8 load8_cvt(const float* __restrict__ p) {
    const float4 a = ((const float4*)p)[0];
    const float4 b = ((const float4*)p)[1];
    bf16x8 r;
    r[0]=f2b(a.x); r[1]=f2b(a.y); r[2]=f2b(a.z); r[3]=f2b(a.w);
    r[4]=f2b(b.x); r[5]=f2b(b.y); r[6]=f2b(b.z); r[7]=f2b(b.w);
    return r;
}

__device__ __forceinline__ float fast_sigm(float x) {
    return __builtin_amdgcn_rcpf(1.f + __expf(-x));
}
__device__ __forceinline__ float fast_tanh(float x) {
    return 1.f - 2.f * __builtin_amdgcn_rcpf(1.f + __expf(2.f * x));
}

__device__ __forceinline__ float dot4(float4 a, float4 b) {
    return a.x * b.x + a.y * b.y + a.z * b.z + a.w * b.w;
}

__device__ __forceinline__ float wave_sum(float v) {
    #pragma unroll
    for (int off = 32; off > 0; off >>= 1) v += __shfl_xor(v, off);
    return v;
}

__device__ __forceinline__ float sigm(float x) {
    return 1.0f / (1.0f + expf(-x));
}

// ===========================================================================
// Kernel 0: gx = x @ W_ih^T + b_ih (+ b_hh folded for r,z gates).
// Weight-stationary persistent: 512 blocks x 256 thr; wave w owns 96 output
// channels (nt=0..5). Writes f32 gx [rows, 384] to workspace.
// ===========================================================================
__global__ __launch_bounds__(256, 2) void gx_kernel(
    const float* __restrict__ global_embed,
    const float* __restrict__ W_ih, const float* __restrict__ b_ih,
    const float* __restrict__ b_hh,
    int base, int ntiles, float* __restrict__ gx_ws)
{
    __shared__ short xbuf[16][136];

    const int tid = threadIdx.x;
    const int w  = tid >> 6;
    const int l  = tid & 63;
    const int ln = l & 15;
    const int lg = l >> 4;

    // stationary W_ih fragments + fused bias
    bf16x8 wf[6][4];
    float bias[6];
    #pragma unroll
    for (int nt = 0; nt < 6; ++nt) {
        const int ch = 96*w + 16*nt + ln;
        #pragma unroll
        for (int kt = 0; kt < 4; ++kt)
            wf[nt][kt] = load8_cvt(W_ih + (size_t)ch * I_DIM + kt*32 + lg*8);
        bias[nt] = b_ih[ch] + (ch < 2*H ? b_hh[ch] : 0.f);
    }

    const int s_r = tid >> 4, s_sg = tid & 15;

    for (int it = blockIdx.x; it < ntiles; it += gridDim.x) {
        const int r0 = it * 16;                       // chunk-local row base
        __syncthreads();                              // xbuf reuse safe
        {
            const float* src = global_embed + (size_t)(base + r0 + s_r) * I_DIM + s_sg*8;
            const float4 a = ((const float4*)src)[0];
            const float4 c = ((const float4*)src)[1];
            short tmp[8];
            tmp[0]=f2b(a.x); tmp[1]=f2b(a.y); tmp[2]=f2b(a.z); tmp[3]=f2b(a.w);
            tmp[4]=f2b(c.x); tmp[5]=f2b(c.y); tmp[6]=f2b(c.z); tmp[7]=f2b(c.w);
            *(uint4*)&xbuf[s_r][s_sg*8] = *(uint4*)tmp;
        }
        __syncthreads();

        bf16x8 af[4];
        #pragma unroll
        for (int kt = 0; kt < 4; ++kt)
            af[kt] = *(const bf16x8*)&xbuf[ln][kt*32 + lg*8];

        f32x4 acc[6];
        #pragma unroll
        for (int nt = 0; nt < 6; ++nt) acc[nt] = (f32x4)(0.f);
        #pragma unroll
        for (int kt = 0; kt < 4; ++kt)
            #pragma unroll
            for (int nt = 0; nt < 6; ++nt)
                acc[nt] = MFMA16x16x32(af[kt], wf[nt][kt], acc[nt]);

        #pragma unroll
        for (int nt = 0; nt < 6; ++nt)
            #pragma unroll
            for (int rg = 0; rg < 4; ++rg)
                gx_ws[(size_t)(r0 + lg*4 + rg) * 384 + 96*w + 16*nt + ln]
                    = acc[nt][rg] + bias[nt];
    }
}

// ===========================================================================
// Kernel A: GRU recurrence, persistent weight-stationary. 512 blocks x 256
// thr (4 waves), grid-striding 16-row tiles. W_hh fragments loaded once per
// block. gx read from workspace (b_ih + b_hh(r,z) prefolded).
// ===========================================================================
__global__ __launch_bounds__(256, 2) void gru_rec_kernel(
    const float* __restrict__ local_embed, const float* __restrict__ gx_ws,
    const float* __restrict__ W_hh, const float* __restrict__ b_hh,
    int base, int ntiles, unsigned short* __restrict__ hist)
{
    __shared__ short hbf[16][136];

    const int tid = threadIdx.x;
    const int w  = tid >> 6;
    const int l  = tid & 63;
    const int ln = l & 15;
    const int lg = l >> 4;

    // stationary W_hh fragments + n-gate bias
    bf16x8 wf[3][2][4];
    float bhn[2];
    #pragma unroll
    for (int u = 0; u < 2; ++u) {
        const int c = 32*w + 16*u + ln;
        bhn[u] = b_hh[2*H + c];
        #pragma unroll
        for (int g = 0; g < 3; ++g) {
            const int crow = g*H + c;
            #pragma unroll
            for (int kt = 0; kt < 4; ++kt)
                wf[g][u][kt] = load8_cvt(W_hh + (size_t)crow * H + kt*32 + lg*8);
        }
    }

    const int sr  = tid >> 4;
    const int seg = tid & 15;

    for (int it = blockIdx.x; it < ntiles; it += gridDim.x) {
        const int lb0 = it * 16;                      // chunk-local row base
        __syncthreads();                              // hbf reuse safe

        // stage h0 (bf16 -> LDS) ; coalesced 8-float load per thread
        {
            const int b = base + lb0 + sr;
            const int n = b & (N_AG - 1);
            const float* src = local_embed + (size_t)n * H + seg*8;
            const float4 a = ((const float4*)src)[0];
            const float4 c = ((const float4*)src)[1];
            short tmp[8];
            tmp[0]=f2b(a.x); tmp[1]=f2b(a.y); tmp[2]=f2b(a.z); tmp[3]=f2b(a.w);
            tmp[4]=f2b(c.x); tmp[5]=f2b(c.y); tmp[6]=f2b(c.z); tmp[7]=f2b(c.w);
            *(uint4*)&hbf[sr][seg*8] = *(uint4*)tmp;
        }

        // h0 master copy (f32) for this thread's owned channels
        float h_reg[2][4];
        #pragma unroll
        for (int u = 0; u < 2; ++u) {
            const int j = 32*w + 16*u + ln;
            #pragma unroll
            for (int rg = 0; rg < 4; ++rg) {
                const int b = base + lb0 + lg*4 + rg;
                const int n = b & (N_AG - 1);
                h_reg[u][rg] = local_embed[(size_t)n * H + j];
            }
        }

        // gx for this tile (bias prefolded)
        float gx[3][2][4];
        #pragma unroll
        for (int g = 0; g < 3; ++g)
            #pragma unroll
            for (int u = 0; u < 2; ++u) {
                const int ch = g*128 + 32*w + 16*u + ln;
                #pragma unroll
                for (int rg = 0; rg < 4; ++rg)
                    gx[g][u][rg] = gx_ws[(size_t)(lb0 + lg*4 + rg) * 384 + ch];
            }
        __syncthreads();                              // h0 staged

        for (int t = 0; t < T_STEPS; ++t) {
            bf16x8 af[4];
            #pragma unroll
            for (int kt = 0; kt < 4; ++kt)
                af[kt] = *(const bf16x8*)&hbf[ln][kt*32 + lg*8];

            f32x4 ga[3][2];
            #pragma unroll
            for (int g = 0; g < 3; ++g)
                #pragma unroll
                for (int u = 0; u < 2; ++u) ga[g][u] = (f32x4)(0.f);
            #pragma unroll
            for (int kt = 0; kt < 4; ++kt)
                #pragma unroll
                for (int g = 0; g < 3; ++g)
                    #pragma unroll
                    for (int u = 0; u < 2; ++u)
                        ga[g][u] = MFMA16x16x32(af[kt], wf[g][u][kt], ga[g][u]);

            unsigned short hb[2][4];
            #pragma unroll
            for (int u = 0; u < 2; ++u) {
                #pragma unroll
                for (int rg = 0; rg < 4; ++rg) {
                    const float rr = fast_sigm(gx[0][u][rg] + ga[0][u][rg]);
                    const float zz = fast_sigm(gx[1][u][rg] + ga[1][u][rg]);
                    const float nn = fast_tanh(gx[2][u][rg] + rr * (ga[2][u][rg] + bhn[u]));
                    const float h  = (1.f - zz) * nn + zz * h_reg[u][rg];
                    h_reg[u][rg] = h;
                    hb[u][rg] = (unsigned short)f2b(h);
                }
            }
            __syncthreads();                          // af reads done
            #pragma unroll
            for (int u = 0; u < 2; ++u) {
                const int j = 32*w + 16*u + ln;
                #pragma unroll
                for (int rg = 0; rg < 4; ++rg)
                    hbf[lg*4 + rg][j] = (short)hb[u][rg];
            }
            __syncthreads();                          // h(t+1) visible

            const uint4 hv = *(const uint4*)&hbf[sr][seg*8];
            *(uint4*)(hist + (size_t)(lb0 + sr) * (T_STEPS * H) + t * H + seg*8) = hv;
        }
    }
}

// ===========================================================================
// Kernel B: loc/scale heads — weight-stationary persistent (1024 blocks).
// ===========================================================================
__global__ __launch_bounds__(256, 3) void heads_kernel(
    const unsigned short* __restrict__ hist, int base, int ntiles,
    const float* __restrict__ loc1_w, const float* __restrict__ loc1_b,
    const float* __restrict__ loc_ln_g, const float* __restrict__ loc_ln_b,
    const float* __restrict__ loc2_w, const float* __restrict__ loc2_b,
    const float* __restrict__ sc1_w, const float* __restrict__ sc1_b,
    const float* __restrict__ sc_ln_g, const float* __restrict__ sc_ln_b,
    const float* __restrict__ sc2_w, const float* __restrict__ sc2_b,
    float* __restrict__ traj)
{
    __shared__ short habf[32][136];
    __shared__ float red[2][32][4];
    __shared__ float red2[2][32][2][2];

    const int tid = threadIdx.x;
    const int w  = tid >> 6;
    const int l  = tid & 63;
    const int ln = l & 15;
    const int lg = l >> 4;
    const int head = w >> 1;
    const int wp = w & 1;

    const float* __restrict__ W1  = head ? sc1_w   : loc1_w;
    const float* __restrict__ B1v = head ? sc1_b   : loc1_b;
    const float* __restrict__ Gv  = head ? sc_ln_g : loc_ln_g;
    const float* __restrict__ Bv  = head ? sc_ln_b : loc_ln_b;
    const float* __restrict__ W2  = head ? sc2_w   : loc2_w;
    const float* __restrict__ B2v = head ? sc2_b   : loc2_b;

    bf16x8 wf[4][4];
    float bias1[4], lng[4], lnb[4], w2a[4], w2b[4];
    #pragma unroll
    for (int nt = 0; nt < 4; ++nt) {
        const int c = 64*wp + 16*nt + ln;
        #pragma unroll
        for (int kt = 0; kt < 4; ++kt)
            wf[nt][kt] = load8_cvt(W1 + (size_t)c * H + kt*32 + lg*8);
        bias1[nt] = B1v[c]; lng[nt] = Gv[c]; lnb[nt] = Bv[c];
        w2a[nt] = W2[c];    w2b[nt] = W2[H + c];
    }
    const float b2_0 = B2v[0], b2_1 = B2v[1];

    const int s_r  = tid >> 4;
    const int s_sg = tid & 15;

    uint4 ld0, ld1;
    if (blockIdx.x < ntiles) {
        const size_t rb = (size_t)blockIdx.x * 32;
        ld0 = *(const uint4*)(hist + (rb + s_r)      * H + s_sg*8);
        ld1 = *(const uint4*)(hist + (rb + s_r + 16) * H + s_sg*8);
    }

    for (int it = blockIdx.x; it < ntiles; it += gridDim.x) {
        __syncthreads();
        *(uint4*)&habf[s_r][s_sg*8]      = ld0;
        *(uint4*)&habf[s_r + 16][s_sg*8] = ld1;
        __syncthreads();

        const int nxt = it + gridDim.x;
        if (nxt < ntiles) {
            const size_t rb = (size_t)nxt * 32;
            ld0 = *(const uint4*)(hist + (rb + s_r)      * H + s_sg*8);
            ld1 = *(const uint4*)(hist + (rb + s_r + 16) * H + s_sg*8);
        }

        f32x4 acc[2][4];
        #pragma unroll
        for (int m = 0; m < 2; ++m) {
            #pragma unroll
            for (int nt = 0; nt < 4; ++nt) acc[m][nt] = (f32x4)(0.f);
            bf16x8 af[4];
            #pragma unroll
            for (int kt = 0; kt < 4; ++kt)
                af[kt] = *(const bf16x8*)&habf[m*16 + ln][kt*32 + lg*8];
            #pragma unroll
            for (int kt = 0; kt < 4; ++kt)
                #pragma unroll
                for (int nt = 0; nt < 4; ++nt)
                    acc[m][nt] = MFMA16x16x32(af[kt], wf[nt][kt], acc[m][nt]);
        }

        #pragma unroll
        for (int m = 0; m < 2; ++m)
            #pragma unroll
            for (int rg = 0; rg < 4; ++rg) {
                float s = 0.f, q = 0.f;
                #pragma unroll
                for (int nt = 0; nt < 4; ++nt) {
                    const float a = acc[m][nt][rg] + bias1[nt];
                    acc[m][nt][rg] = a;
                    s += a; q += a*a;
                }
                #pragma unroll
                for (int off = 1; off < 16; off <<= 1) {
                    s += __shfl_xor(s, off);
                    q += __shfl_xor(q, off);
                }
                if (ln == 0) {
                    const int row = m*16 + lg*4 + rg;
                    red[head][row][wp*2+0] = s;
                    red[head][row][wp*2+1] = q;
                }
            }
        __syncthreads();

        #pragma unroll
        for (int m = 0; m < 2; ++m)
            #pragma unroll
            for (int rg = 0; rg < 4; ++rg) {
                const int row = m*16 + lg*4 + rg;
                const float4 rv = *(const float4*)&red[head][row][0];
                const float S = rv.x + rv.z, Q = rv.y + rv.w;
                const float mu = S * (1.f/H);
                const float var = Q * (1.f/H) - mu*mu;
                const float rs = rsqrtf(var + LN_EPS);
                float p0 = 0.f, p1 = 0.f;
                #pragma unroll
                for (int nt = 0; nt < 4; ++nt) {
                    float v = (acc[m][nt][rg] - mu) * rs * lng[nt] + lnb[nt];
                    v = fmaxf(v, 0.f);
                    p0 += v * w2a[nt];
                    p1 += v * w2b[nt];
                }
                #pragma unroll
                for (int off = 1; off < 16; off <<= 1) {
                    p0 += __shfl_xor(p0, off);
                    p1 += __shfl_xor(p1, off);
                }
                if (ln == 0) {
                    red2[head][row][wp][0] = p0;
                    red2[head][row][wp][1] = p1;
                }
            }
        __syncthreads();

        if (wp == 0 && ln == 0) {
            const int flat0 = it * 32;
            #pragma unroll
            for (int m = 0; m < 2; ++m)
                #pragma unroll
                for (int rg = 0; rg < 4; ++rg) {
                    const int row = m*16 + lg*4 + rg;
                    const int flat = flat0 + row;
                    const int lb = flat / T_STEPS;
                    const int t = flat - lb * T_STEPS;
                    const int b = base + lb;
                    #pragma unroll
                    for (int o = 0; o < 2; ++o) {
                        float val = red2[head][row][0][o] + red2[head][row][1][o]
                                  + (o ? b2_1 : b2_0);
                        if (head) val = (val > 0.f ? val : expm1f(val)) + 1.0f + MIN_SCALE;
                        traj[((size_t)b * T_STEPS + t) * 4 + head*2 + o] = val;
                    }
                }
        }
    }
}

// ===========================================================================
// Kernel C: pi head — weight-stationary persistent (768 blocks).
// ===========================================================================
__global__ __launch_bounds__(256, 2) void pi_persist_kernel(
    const float* __restrict__ local_embed, const float* __restrict__ global_embed,
    const float* __restrict__ pi1_w, const float* __restrict__ pi1_b,
    const float* __restrict__ ln1_g, const float* __restrict__ ln1_b,
    const float* __restrict__ pi2_w, const float* __restrict__ pi2_b,
    const float* __restrict__ ln2_g, const float* __restrict__ ln2_b,
    const float* __restrict__ pi3_w, const float* __restrict__ pi3_b,
    float* __restrict__ pi_out)
{
    __shared__ short inbf[32][264];
    __shared__ short h1bf[32][136];
    __shared__ float redL[4][32][2];
    __shared__ float red3[4][32];

    const int tid = threadIdx.x;
    const int w  = tid >> 6;
    const int l  = tid & 63;
    const int ln = l & 15;
    const int lg = l >> 4;

    bf16x8 wf1[2][8];
    bf16x8 wf2[2][4];
    float b1[2], g1[2], bb1[2], b2[2], g2[2], bb2[2], w3[2];
    #pragma unroll
    for (int nt = 0; nt < 2; ++nt) {
        const int c = 32*w + 16*nt + ln;
        #pragma unroll
        for (int kt = 0; kt < 8; ++kt)
            wf1[nt][kt] = load8_cvt(pi1_w + (size_t)c * (2*H) + kt*32 + lg*8);
        #pragma unroll
        for (int kt = 0; kt < 4; ++kt)
            wf2[nt][kt] = load8_cvt(pi2_w + (size_t)c * H + kt*32 + lg*8);
        b1[nt] = pi1_b[c]; g1[nt] = ln1_g[c]; bb1[nt] = ln1_b[c];
        b2[nt] = pi2_b[c]; g2[nt] = ln2_g[c]; bb2[nt] = ln2_b[c];
        w3[nt] = pi3_w[c];
    }
    const float b3 = pi3_b[0];

    const int ntiles = B_TOT / 32;

    for (int it = blockIdx.x; it < ntiles; it += gridDim.x) {
        const int r0 = it * 32;
        {
            const int r   = tid >> 3;
            const int seg = tid & 7;
            const int b = r0 + r;
            const int n = b & (N_AG - 1);
            const float* src = (seg < 4) ? (local_embed + (size_t)n * H + seg * 32)
                                         : (global_embed + (size_t)b * I_DIM + (seg - 4) * 32);
            short tmp[32];
            #pragma unroll
            for (int i = 0; i < 8; ++i) {
                const float4 v = ((const float4*)src)[i];
                tmp[i*4+0]=f2b(v.x); tmp[i*4+1]=f2b(v.y); tmp[i*4+2]=f2b(v.z); tmp[i*4+3]=f2b(v.w);
            }
            #pragma unroll
            for (int i = 0; i < 4; ++i)
                *(uint4*)&inbf[r][seg*32 + i*8] = *(uint4*)&tmp[i*8];
        }
        __syncthreads();

        f32x4 acc1[2][2];
        #pragma unroll
        for (int m = 0; m < 2; ++m) {
            #pragma unroll
            for (int nt = 0; nt < 2; ++nt) acc1[m][nt] = (f32x4)(0.f);
            bf16x8 af[8];
            #pragma unroll
            for (int kt = 0; kt < 8; ++kt)
                af[kt] = *(const bf16x8*)&inbf[m*16 + ln][kt*32 + lg*8];
            #pragma unroll
            for (int kt = 0; kt < 8; ++kt)
                #pragma unroll
                for (int nt = 0; nt < 2; ++nt)
                    acc1[m][nt] = MFMA16x16x32(af[kt], wf1[nt][kt], acc1[m][nt]);
        }

        #pragma unroll
        for (int m = 0; m < 2; ++m)
            #pragma unroll
            for (int rg = 0; rg < 4; ++rg) {
                float s = 0.f, q = 0.f;
                #pragma unroll
                for (int nt = 0; nt < 2; ++nt) {
                    const float a = acc1[m][nt][rg] + b1[nt];
                    acc1[m][nt][rg] = a;
                    s += a; q += a*a;
                }
                #pragma unroll
                for (int off = 1; off < 16; off <<= 1) {
                    s += __shfl_xor(s, off);
                    q += __shfl_xor(q, off);
                }
                if (ln == 0) {
                    const int row = m*16 + lg*4 + rg;
                    redL[w][row][0] = s;
                    redL[w][row][1] = q;
                }
            }
        __syncthreads();

        #pragma unroll
        for (int m = 0; m < 2; ++m)
            #pragma unroll
            for (int rg = 0; rg < 4; ++rg) {
                const int row = m*16 + lg*4 + rg;
                const float S = redL[0][row][0] + redL[1][row][0] + redL[2][row][0] + redL[3][row][0];
                const float Q = redL[0][row][1] + redL[1][row][1] + redL[2][row][1] + redL[3][row][1];
                const float mu = S * (1.f/H);
                const float var = Q * (1.f/H) - mu*mu;
                const float rs = rsqrtf(var + LN_EPS);
                #pragma unroll
                for (int nt = 0; nt < 2; ++nt) {
                    const float v = fmaxf((acc1[m][nt][rg] - mu) * rs * g1[nt] + bb1[nt], 0.f);
                    h1bf[row][32*w + 16*nt + ln] = f2b(v);
                }
            }
        __syncthreads();

        f32x4 acc2[2][2];
        #pragma unroll
        for (int m = 0; m < 2; ++m) {
            #pragma unroll
            for (int nt = 0; nt < 2; ++nt) acc2[m][nt] = (f32x4)(0.f);
            bf16x8 af[4];
            #pragma unroll
            for (int kt = 0; kt < 4; ++kt)
                af[kt] = *(const bf16x8*)&h1bf[m*16 + ln][kt*32 + lg*8];
            #pragma unroll
            for (int kt = 0; kt < 4; ++kt)
                #pragma unroll
                for (int nt = 0; nt < 2; ++nt)
                    acc2[m][nt] = MFMA16x16x32(af[kt], wf2[nt][kt], acc2[m][nt]);
        }

        #pragma unroll
        for (int m = 0; m < 2; ++m)
            #pragma unroll
            for (int rg = 0; rg < 4; ++rg) {
                float s = 0.f, q = 0.f;
                #pragma unroll
                for (int nt = 0; nt < 2; ++nt) {
                    const float a = acc2[m][nt][rg] + b2[nt];
                    acc2[m][nt][rg] = a;
                    s += a; q += a*a;
                }
                #pragma unroll
                for (int off = 1; off < 16; off <<= 1) {
                    s += __shfl_xor(s, off);
                    q += __shfl_xor(q, off);
                }
                if (ln == 0) {
                    const int row = m*16 + lg*4 + rg;
                    redL[w][row][0] = s;
                    redL[w][row][1] = q;
                }
            }
        __syncthreads();

        #pragma unroll
        for (int m = 0; m < 2; ++m)
            #pragma unroll
            for (int rg = 0; rg < 4; ++rg) {
                const int row = m*16 + lg*4 + rg;
                const float S = redL[0][row][0] + redL[1][row][0] + redL[2][row][0] + redL[3][row][0];
                const float Q = redL[0][row][1] + redL[1][row][1] + redL[2][row][1] + redL[3][row][1];
                const float mu = S * (1.f/H);
                const float var = Q * (1.f/H) - mu*mu;
                const float rs = rsqrtf(var + LN_EPS);
                float p = 0.f;
                #pragma unroll
                for (int nt = 0; nt < 2; ++nt) {
                    const float v = fmaxf((acc2[m][nt][rg] - mu) * rs * g2[nt] + bb2[nt], 0.f);
                    p += v * w3[nt];
                }
                #pragma unroll
                for (int off = 1; off < 16; off <<= 1) p += __shfl_xor(p, off);
                if (ln == 0) red3[w][row] = p;
            }
        __syncthreads();

        if (tid < 32) {
            const int row = tid;
            const float p = red3[0][row] + red3[1][row] + red3[2][row] + red3[3][row] + b3;
            const int b = r0 + row;
            const int n = b & (N_AG - 1);
            const int m = b >> 13;
            pi_out[(size_t)n * M_MODES + m] = p;
        }
        __syncthreads();
    }
}

extern "C" void kernel_launch(void* const* d_in, const int* in_sizes, int n_in,
                              void* d_out, int out_size, void* d_ws, size_t ws_size,
                              hipStream_t stream) {
    (void)in_sizes; (void)n_in; (void)out_size;
    const float* local_embed  = (const float*)d_in[0];
    const float* global_embed = (const float*)d_in[1];
    const float* W_ih   = (const float*)d_in[2];
    const float* W_hh   = (const float*)d_in[3];
    const float* b_ih   = (const float*)d_in[4];
    const float* b_hh   = (const float*)d_in[5];
    const float* loc1_w = (const float*)d_in[6];
    const float* loc1_b = (const float*)d_in[7];
    const float* loc_ln_g = (const float*)d_in[8];
    const float* loc_ln_b = (const float*)d_in[9];
    const float* loc2_w = (const float*)d_in[10];
    const float* loc2_b = (const float*)d_in[11];
    const float* sc1_w  = (const float*)d_in[12];
    const float* sc1_b  = (const float*)d_in[13];
    const float* sc_ln_g = (const float*)d_in[14];
    const float* sc_ln_b = (const float*)d_in[15];
    const float* sc2_w  = (const float*)d_in[16];
    const float* sc2_b  = (const float*)d_in[17];
    const float* pi1_w  = (const float*)d_in[18];
    const float* pi1_b  = (const float*)d_in[19];
    const float* pi_ln1_g = (const float*)d_in[20];
    const float* pi_ln1_b = (const float*)d_in[21];
    const float* pi2_w  = (const float*)d_in[22];
    const float* pi2_b  = (const float*)d_in[23];
    const float* pi_ln2_g = (const float*)d_in[24];
    const float* pi_ln2_b = (const float*)d_in[25];
    const float* pi3_w  = (const float*)d_in[26];
    const float* pi3_b  = (const float*)d_in[27];

    float* traj = (float*)d_out;
    float* pi_out = traj + (size_t)B_TOT * T_STEPS * 4;

    pi_persist_kernel<<<768, 256, 0, stream>>>(
        local_embed, global_embed, pi1_w, pi1_b, pi_ln1_g, pi_ln1_b,
        pi2_w, pi2_b, pi_ln2_g, pi_ln2_b, pi3_w, pi3_b, pi_out);

    // workspace layout per chunk of Rc rows:
    //   gx  : Rc * 384 f32  (1536 B/row)
    //   hist: Rc * 30 * 128 bf16 (7680 B/row)
    const size_t row_bytes = 384 * sizeof(float) + (size_t)T_STEPS * H * sizeof(unsigned short);
    long long rc = (long long)(ws_size / row_bytes);
    int Rc = rc > B_TOT ? B_TOT : (int)rc;
    Rc &= ~15;

    if (Rc >= 16) {
        float* gx_ws = (float*)d_ws;
        unsigned short* hist = (unsigned short*)(gx_ws + (size_t)Rc * 384);

        for (int basep = 0; basep < B_TOT; basep += Rc) {
            const int rows = (B_TOT - basep < Rc) ? (B_TOT - basep) : Rc;
            const int tiles = rows / 16;

            gx_kernel<<<(tiles < 512 ? tiles : 512), 256, 0, stream>>>(
                global_embed, W_ih, b_ih, b_hh, basep, tiles, gx_ws);

            gru_rec_kernel<<<(tiles < 512 ? tiles : 512), 256, 0, stream>>>(
                local_embed, gx_ws, W_hh, b_hh, basep, tiles, hist);

            const int htiles = (rows * T_STEPS) / 32;
            heads_kernel<<<(htiles < 1024 ? htiles : 1024), 256, 0, stream>>>(
                hist, basep, htiles,
                loc1_w, loc1_b, loc_ln_g, loc_ln_b, loc2_w, loc2_b,
                sc1_w, sc1_b, sc_ln_g, sc_ln_b, sc2_w, sc2_b, traj);
        }
    }
}

// Round 7
// 750.324 us; speedup vs baseline: 2.1205x; 1.3534x over previous
//
#include <hip/hip_runtime.h>
#include <math.h>

#define H 128
#define I_DIM 128
#define T_STEPS 30
#define M_MODES 6
#define N_AG 8192
#define B_TOT (M_MODES * N_AG)   /* 49152 */
#define LN_EPS 1e-5f
#define MIN_SCALE 0.001f

typedef short bf16x8 __attribute__((ext_vector_type(8)));
typedef float f32x4 __attribute__((ext_vector_type(4)));

#define MFMA16x16x32(A, B, C) __builtin_amdgcn_mfma_f32_16x16x32_bf16(A, B, C, 0, 0, 0)

__device__ __forceinline__ short f2b(float f) {
    union { float f; unsigned u; } v; v.f = f;
    return (short)((v.u + 0x7FFFu + ((v.u >> 16) & 1u)) >> 16);
}

__device__ __forceinline__ bf16x8 load8_cvt(const float* __restrict__ p) {
    const float4 a = ((const float4*)p)[0];
    const float4 b = ((const float4*)p)[1];
    bf16x8 r;
    r[0]=f2b(a.x); r[1]=f2b(a.y); r[2]=f2b(a.z); r[3]=f2b(a.w);
    r[4]=f2b(b.x); r[5]=f2b(b.y); r[6]=f2b(b.z); r[7]=f2b(b.w);
    return r;
}

__device__ __forceinline__ float fast_sigm(float x) {
    return __builtin_amdgcn_rcpf(1.f + __expf(-x));
}
__device__ __forceinline__ float fast_tanh(float x) {
    return 1.f - 2.f * __builtin_amdgcn_rcpf(1.f + __expf(2.f * x));
}

// ===========================================================================
// Kernel 0: gx = x @ W_ih^T + b_ih (+ b_hh folded for r,z gates).
// Output TRANSPOSED: gx_ws[ch][row], ch in [0,384), stride Rc.
// ===========================================================================
__global__ __launch_bounds__(256, 2) void gx_kernel(
    const float* __restrict__ global_embed,
    const float* __restrict__ W_ih, const float* __restrict__ b_ih,
    const float* __restrict__ b_hh,
    int base, int ntiles, int Rc, float* __restrict__ gx_ws)
{
    __shared__ short xbuf[16][136];

    const int tid = threadIdx.x;
    const int w  = tid >> 6;
    const int l  = tid & 63;
    const int ln = l & 15;
    const int lg = l >> 4;

    bf16x8 wf[6][4];
    float bias[6];
    #pragma unroll
    for (int nt = 0; nt < 6; ++nt) {
        const int ch = 96*w + 16*nt + ln;
        #pragma unroll
        for (int kt = 0; kt < 4; ++kt)
            wf[nt][kt] = load8_cvt(W_ih + (size_t)ch * I_DIM + kt*32 + lg*8);
        bias[nt] = b_ih[ch] + (ch < 2*H ? b_hh[ch] : 0.f);
    }

    const int s_r = tid >> 4, s_sg = tid & 15;

    for (int it = blockIdx.x; it < ntiles; it += gridDim.x) {
        const int r0 = it * 16;
        __syncthreads();
        {
            const float* src = global_embed + (size_t)(base + r0 + s_r) * I_DIM + s_sg*8;
            const float4 a = ((const float4*)src)[0];
            const float4 c = ((const float4*)src)[1];
            short tmp[8];
            tmp[0]=f2b(a.x); tmp[1]=f2b(a.y); tmp[2]=f2b(a.z); tmp[3]=f2b(a.w);
            tmp[4]=f2b(c.x); tmp[5]=f2b(c.y); tmp[6]=f2b(c.z); tmp[7]=f2b(c.w);
            *(uint4*)&xbuf[s_r][s_sg*8] = *(uint4*)tmp;
        }
        __syncthreads();

        bf16x8 af[4];
        #pragma unroll
        for (int kt = 0; kt < 4; ++kt)
            af[kt] = *(const bf16x8*)&xbuf[ln][kt*32 + lg*8];

        f32x4 acc[6];
        #pragma unroll
        for (int nt = 0; nt < 6; ++nt) acc[nt] = (f32x4)(0.f);
        #pragma unroll
        for (int kt = 0; kt < 4; ++kt)
            #pragma unroll
            for (int nt = 0; nt < 6; ++nt)
                acc[nt] = MFMA16x16x32(af[kt], wf[nt][kt], acc[nt]);

        #pragma unroll
        for (int nt = 0; nt < 6; ++nt) {
            const f32x4 v = acc[nt] + (f32x4)(bias[nt]);
            *(f32x4*)(gx_ws + (size_t)(96*w + 16*nt + ln) * Rc + r0 + lg*4) = v;
        }
    }
}

// ===========================================================================
// Kernel A: GRU recurrence, persistent weight-stationary, single barrier per
// step via double-buffered h in LDS. gx read as float4 (transposed layout).
// ===========================================================================
__global__ __launch_bounds__(256, 2) void gru_rec_kernel(
    const float* __restrict__ local_embed, const float* __restrict__ gx_ws,
    const float* __restrict__ W_hh, const float* __restrict__ b_hh,
    int base, int ntiles, int Rc, unsigned short* __restrict__ hist)
{
    __shared__ short hb0[16][136];
    __shared__ short hb1[16][136];

    const int tid = threadIdx.x;
    const int w  = tid >> 6;
    const int l  = tid & 63;
    const int ln = l & 15;
    const int lg = l >> 4;

    bf16x8 wf[3][2][4];
    float bhn[2];
    #pragma unroll
    for (int u = 0; u < 2; ++u) {
        const int c = 32*w + 16*u + ln;
        bhn[u] = b_hh[2*H + c];
        #pragma unroll
        for (int g = 0; g < 3; ++g) {
            const int crow = g*H + c;
            #pragma unroll
            for (int kt = 0; kt < 4; ++kt)
                wf[g][u][kt] = load8_cvt(W_hh + (size_t)crow * H + kt*32 + lg*8);
        }
    }

    const int sr  = tid >> 4;
    const int seg = tid & 15;

    for (int it = blockIdx.x; it < ntiles; it += gridDim.x) {
        const int lb0 = it * 16;
        __syncthreads();                              // prev tile reads done

        // stage h0 -> hb0 (bf16), coalesced
        {
            const int b = base + lb0 + sr;
            const int n = b & (N_AG - 1);
            const float* src = local_embed + (size_t)n * H + seg*8;
            const float4 a = ((const float4*)src)[0];
            const float4 c = ((const float4*)src)[1];
            short tmp[8];
            tmp[0]=f2b(a.x); tmp[1]=f2b(a.y); tmp[2]=f2b(a.z); tmp[3]=f2b(a.w);
            tmp[4]=f2b(c.x); tmp[5]=f2b(c.y); tmp[6]=f2b(c.z); tmp[7]=f2b(c.w);
            *(uint4*)&hb0[sr][seg*8] = *(uint4*)tmp;
        }

        // h0 master copy (f32) for owned channels
        float h_reg[2][4];
        #pragma unroll
        for (int u = 0; u < 2; ++u) {
            const int j = 32*w + 16*u + ln;
            #pragma unroll
            for (int rg = 0; rg < 4; ++rg) {
                const int b = base + lb0 + lg*4 + rg;
                const int n = b & (N_AG - 1);
                h_reg[u][rg] = local_embed[(size_t)n * H + j];
            }
        }

        // gx (transposed layout -> float4 loads)
        float gx[3][2][4];
        #pragma unroll
        for (int g = 0; g < 3; ++g)
            #pragma unroll
            for (int u = 0; u < 2; ++u) {
                const int ch = g*128 + 32*w + 16*u + ln;
                const f32x4 v = *(const f32x4*)(gx_ws + (size_t)ch * Rc + lb0 + lg*4);
                #pragma unroll
                for (int rg = 0; rg < 4; ++rg) gx[g][u][rg] = v[rg];
            }
        __syncthreads();                              // h0 staged

        int cur = 0;
        for (int t = 0; t < T_STEPS; ++t) {
            const short* hcur = cur ? &hb1[0][0] : &hb0[0][0];
            short*       hnxt = cur ? &hb0[0][0] : &hb1[0][0];

            bf16x8 af[4];
            #pragma unroll
            for (int kt = 0; kt < 4; ++kt)
                af[kt] = *(const bf16x8*)&hcur[ln*136 + kt*32 + lg*8];

            f32x4 ga[3][2];
            #pragma unroll
            for (int g = 0; g < 3; ++g)
                #pragma unroll
                for (int u = 0; u < 2; ++u) ga[g][u] = (f32x4)(0.f);
            #pragma unroll
            for (int kt = 0; kt < 4; ++kt)
                #pragma unroll
                for (int g = 0; g < 3; ++g)
                    #pragma unroll
                    for (int u = 0; u < 2; ++u)
                        ga[g][u] = MFMA16x16x32(af[kt], wf[g][u][kt], ga[g][u]);

            #pragma unroll
            for (int u = 0; u < 2; ++u) {
                const int j = 32*w + 16*u + ln;
                #pragma unroll
                for (int rg = 0; rg < 4; ++rg) {
                    const float rr = fast_sigm(gx[0][u][rg] + ga[0][u][rg]);
                    const float zz = fast_sigm(gx[1][u][rg] + ga[1][u][rg]);
                    const float nn = fast_tanh(gx[2][u][rg] + rr * (ga[2][u][rg] + bhn[u]));
                    const float h  = (1.f - zz) * nn + zz * h_reg[u][rg];
                    h_reg[u][rg] = h;
                    hnxt[(lg*4 + rg)*136 + j] = f2b(h);
                }
            }
            __syncthreads();                          // h(t+1) visible; reads of hcur done

            const uint4 hv = *(const uint4*)&hnxt[sr*136 + seg*8];
            *(uint4*)(hist + (size_t)(lb0 + sr) * (T_STEPS * H) + t * H + seg*8) = hv;
            cur ^= 1;
        }
    }
}

// ===========================================================================
// Kernel B: loc/scale heads — wave-owns-full-head. 4 waves/block:
// wave w -> head (w&1), rows (w>>1)*16 of the 32-row tile. LN + linear-2
// fully wave-local (no cross-wave LDS reductions, no epilogue barriers).
// ===========================================================================
__global__ __launch_bounds__(256, 2) void heads_kernel(
    const unsigned short* __restrict__ hist, int base, int ntiles,
    const float* __restrict__ loc1_w, const float* __restrict__ loc1_b,
    const float* __restrict__ loc_ln_g, const float* __restrict__ loc_ln_b,
    const float* __restrict__ loc2_w, const float* __restrict__ loc2_b,
    const float* __restrict__ sc1_w, const float* __restrict__ sc1_b,
    const float* __restrict__ sc_ln_g, const float* __restrict__ sc_ln_b,
    const float* __restrict__ sc2_w, const float* __restrict__ sc2_b,
    float* __restrict__ traj)
{
    __shared__ short habf[32][136];

    const int tid = threadIdx.x;
    const int w  = tid >> 6;
    const int l  = tid & 63;
    const int ln = l & 15;
    const int lg = l >> 4;
    const int hd   = w & 1;                // 0 = loc, 1 = sc
    const int mrow = (w >> 1) * 16;        // row offset within tile

    const float* __restrict__ W1  = hd ? sc1_w   : loc1_w;
    const float* __restrict__ B1v = hd ? sc1_b   : loc1_b;
    const float* __restrict__ Gv  = hd ? sc_ln_g : loc_ln_g;
    const float* __restrict__ Bv  = hd ? sc_ln_b : loc_ln_b;
    const float* __restrict__ W2  = hd ? sc2_w   : loc2_w;
    const float* __restrict__ B2v = hd ? sc2_b   : loc2_b;

    // full head: 8 col-fragments (128 channels), stationary
    bf16x8 wf[8][4];
    float bias1[8], lng[8], lnb[8], w2a[8], w2b[8];
    #pragma unroll
    for (int nt = 0; nt < 8; ++nt) {
        const int c = 16*nt + ln;
        #pragma unroll
        for (int kt = 0; kt < 4; ++kt)
            wf[nt][kt] = load8_cvt(W1 + (size_t)c * H + kt*32 + lg*8);
        bias1[nt] = B1v[c]; lng[nt] = Gv[c]; lnb[nt] = Bv[c];
        w2a[nt] = W2[c];    w2b[nt] = W2[H + c];
    }
    const float b2_0 = B2v[0], b2_1 = B2v[1];

    const int s_r  = tid >> 4;
    const int s_sg = tid & 15;

    uint4 ld0, ld1;
    {
        const size_t rb = (size_t)blockIdx.x * 32;
        ld0 = *(const uint4*)(hist + (rb + s_r)      * H + s_sg*8);
        ld1 = *(const uint4*)(hist + (rb + s_r + 16) * H + s_sg*8);
    }

    for (int it = blockIdx.x; it < ntiles; it += gridDim.x) {
        __syncthreads();                    // prior tile's LDS reads done
        *(uint4*)&habf[s_r][s_sg*8]      = ld0;
        *(uint4*)&habf[s_r + 16][s_sg*8] = ld1;
        __syncthreads();                    // tile staged

        const int nxt = it + gridDim.x;
        if (nxt < ntiles) {
            const size_t rb = (size_t)nxt * 32;
            ld0 = *(const uint4*)(hist + (rb + s_r)      * H + s_sg*8);
            ld1 = *(const uint4*)(hist + (rb + s_r + 16) * H + s_sg*8);
        }

        // GEMM: 16 rows x 128 channels per wave
        bf16x8 af[4];
        #pragma unroll
        for (int kt = 0; kt < 4; ++kt)
            af[kt] = *(const bf16x8*)&habf[mrow + ln][kt*32 + lg*8];
        f32x4 acc[8];
        #pragma unroll
        for (int nt = 0; nt < 8; ++nt) acc[nt] = (f32x4)(0.f);
        #pragma unroll
        for (int kt = 0; kt < 4; ++kt)
            #pragma unroll
            for (int nt = 0; nt < 8; ++nt)
                acc[nt] = MFMA16x16x32(af[kt], wf[nt][kt], acc[nt]);

        // wave-local epilogue per row-group
        #pragma unroll
        for (int rg = 0; rg < 4; ++rg) {
            float s = 0.f, q = 0.f;
            #pragma unroll
            for (int nt = 0; nt < 8; ++nt) {
                const float a = acc[nt][rg] + bias1[nt];
                acc[nt][rg] = a;
                s += a; q += a*a;
            }
            #pragma unroll
            for (int off = 1; off < 16; off <<= 1) {
                s += __shfl_xor(s, off);
                q += __shfl_xor(q, off);
            }
            const float mu = s * (1.f/H);
            const float var = q * (1.f/H) - mu*mu;
            const float rs = rsqrtf(var + LN_EPS);
            float p0 = 0.f, p1 = 0.f;
            #pragma unroll
            for (int nt = 0; nt < 8; ++nt) {
                float v = (acc[nt][rg] - mu) * rs * lng[nt] + lnb[nt];
                v = fmaxf(v, 0.f);
                p0 += v * w2a[nt];
                p1 += v * w2b[nt];
            }
            #pragma unroll
            for (int off = 1; off < 16; off <<= 1) {
                p0 += __shfl_xor(p0, off);
                p1 += __shfl_xor(p1, off);
            }
            if (ln == 0) {
                const int row = mrow + lg*4 + rg;
                const int flat = it * 32 + row;
                const int lb = flat / T_STEPS;
                const int t = flat - lb * T_STEPS;
                const int b = base + lb;
                float v0 = p0 + b2_0;
                float v1 = p1 + b2_1;
                if (hd) {
                    v0 = (v0 > 0.f ? v0 : expm1f(v0)) + 1.0f + MIN_SCALE;
                    v1 = (v1 > 0.f ? v1 : expm1f(v1)) + 1.0f + MIN_SCALE;
                }
                *(float2*)(traj + ((size_t)b * T_STEPS + t) * 4 + hd*2) = make_float2(v0, v1);
            }
        }
    }
}

// ===========================================================================
// Kernel C: pi head — weight-stationary persistent (768 blocks). Unchanged.
// ===========================================================================
__global__ __launch_bounds__(256, 2) void pi_persist_kernel(
    const float* __restrict__ local_embed, const float* __restrict__ global_embed,
    const float* __restrict__ pi1_w, const float* __restrict__ pi1_b,
    const float* __restrict__ ln1_g, const float* __restrict__ ln1_b,
    const float* __restrict__ pi2_w, const float* __restrict__ pi2_b,
    const float* __restrict__ ln2_g, const float* __restrict__ ln2_b,
    const float* __restrict__ pi3_w, const float* __restrict__ pi3_b,
    float* __restrict__ pi_out)
{
    __shared__ short inbf[32][264];
    __shared__ short h1bf[32][136];
    __shared__ float redL[4][32][2];
    __shared__ float red3[4][32];

    const int tid = threadIdx.x;
    const int w  = tid >> 6;
    const int l  = tid & 63;
    const int ln = l & 15;
    const int lg = l >> 4;

    bf16x8 wf1[2][8];
    bf16x8 wf2[2][4];
    float b1[2], g1[2], bb1[2], b2[2], g2[2], bb2[2], w3[2];
    #pragma unroll
    for (int nt = 0; nt < 2; ++nt) {
        const int c = 32*w + 16*nt + ln;
        #pragma unroll
        for (int kt = 0; kt < 8; ++kt)
            wf1[nt][kt] = load8_cvt(pi1_w + (size_t)c * (2*H) + kt*32 + lg*8);
        #pragma unroll
        for (int kt = 0; kt < 4; ++kt)
            wf2[nt][kt] = load8_cvt(pi2_w + (size_t)c * H + kt*32 + lg*8);
        b1[nt] = pi1_b[c]; g1[nt] = ln1_g[c]; bb1[nt] = ln1_b[c];
        b2[nt] = pi2_b[c]; g2[nt] = ln2_g[c]; bb2[nt] = ln2_b[c];
        w3[nt] = pi3_w[c];
    }
    const float b3 = pi3_b[0];

    const int ntiles = B_TOT / 32;

    for (int it = blockIdx.x; it < ntiles; it += gridDim.x) {
        const int r0 = it * 32;
        {
            const int r   = tid >> 3;
            const int seg = tid & 7;
            const int b = r0 + r;
            const int n = b & (N_AG - 1);
            const float* src = (seg < 4) ? (local_embed + (size_t)n * H + seg * 32)
                                         : (global_embed + (size_t)b * I_DIM + (seg - 4) * 32);
            short tmp[32];
            #pragma unroll
            for (int i = 0; i < 8; ++i) {
                const float4 v = ((const float4*)src)[i];
                tmp[i*4+0]=f2b(v.x); tmp[i*4+1]=f2b(v.y); tmp[i*4+2]=f2b(v.z); tmp[i*4+3]=f2b(v.w);
            }
            #pragma unroll
            for (int i = 0; i < 4; ++i)
                *(uint4*)&inbf[r][seg*32 + i*8] = *(uint4*)&tmp[i*8];
        }
        __syncthreads();

        f32x4 acc1[2][2];
        #pragma unroll
        for (int m = 0; m < 2; ++m) {
            #pragma unroll
            for (int nt = 0; nt < 2; ++nt) acc1[m][nt] = (f32x4)(0.f);
            bf16x8 af[8];
            #pragma unroll
            for (int kt = 0; kt < 8; ++kt)
                af[kt] = *(const bf16x8*)&inbf[m*16 + ln][kt*32 + lg*8];
            #pragma unroll
            for (int kt = 0; kt < 8; ++kt)
                #pragma unroll
                for (int nt = 0; nt < 2; ++nt)
                    acc1[m][nt] = MFMA16x16x32(af[kt], wf1[nt][kt], acc1[m][nt]);
        }

        #pragma unroll
        for (int m = 0; m < 2; ++m)
            #pragma unroll
            for (int rg = 0; rg < 4; ++rg) {
                float s = 0.f, q = 0.f;
                #pragma unroll
                for (int nt = 0; nt < 2; ++nt) {
                    const float a = acc1[m][nt][rg] + b1[nt];
                    acc1[m][nt][rg] = a;
                    s += a; q += a*a;
                }
                #pragma unroll
                for (int off = 1; off < 16; off <<= 1) {
                    s += __shfl_xor(s, off);
                    q += __shfl_xor(q, off);
                }
                if (ln == 0) {
                    const int row = m*16 + lg*4 + rg;
                    redL[w][row][0] = s;
                    redL[w][row][1] = q;
                }
            }
        __syncthreads();

        #pragma unroll
        for (int m = 0; m < 2; ++m)
            #pragma unroll
            for (int rg = 0; rg < 4; ++rg) {
                const int row = m*16 + lg*4 + rg;
                const float S = redL[0][row][0] + redL[1][row][0] + redL[2][row][0] + redL[3][row][0];
                const float Q = redL[0][row][1] + redL[1][row][1] + redL[2][row][1] + redL[3][row][1];
                const float mu = S * (1.f/H);
                const float var = Q * (1.f/H) - mu*mu;
                const float rs = rsqrtf(var + LN_EPS);
                #pragma unroll
                for (int nt = 0; nt < 2; ++nt) {
                    const float v = fmaxf((acc1[m][nt][rg] - mu) * rs * g1[nt] + bb1[nt], 0.f);
                    h1bf[row][32*w + 16*nt + ln] = f2b(v);
                }
            }
        __syncthreads();

        f32x4 acc2[2][2];
        #pragma unroll
        for (int m = 0; m < 2; ++m) {
            #pragma unroll
            for (int nt = 0; nt < 2; ++nt) acc2[m][nt] = (f32x4)(0.f);
            bf16x8 af[4];
            #pragma unroll
            for (int kt = 0; kt < 4; ++kt)
                af[kt] = *(const bf16x8*)&h1bf[m*16 + ln][kt*32 + lg*8];
            #pragma unroll
            for (int kt = 0; kt < 4; ++kt)
                #pragma unroll
                for (int nt = 0; nt < 2; ++nt)
                    acc2[m][nt] = MFMA16x16x32(af[kt], wf2[nt][kt], acc2[m][nt]);
        }

        #pragma unroll
        for (int m = 0; m < 2; ++m)
            #pragma unroll
            for (int rg = 0; rg < 4; ++rg) {
                float s = 0.f, q = 0.f;
                #pragma unroll
                for (int nt = 0; nt < 2; ++nt) {
                    const float a = acc2[m][nt][rg] + b2[nt];
                    acc2[m][nt][rg] = a;
                    s += a; q += a*a;
                }
                #pragma unroll
                for (int off = 1; off < 16; off <<= 1) {
                    s += __shfl_xor(s, off);
                    q += __shfl_xor(q, off);
                }
                if (ln == 0) {
                    const int row = m*16 + lg*4 + rg;
                    redL[w][row][0] = s;
                    redL[w][row][1] = q;
                }
            }
        __syncthreads();

        #pragma unroll
        for (int m = 0; m < 2; ++m)
            #pragma unroll
            for (int rg = 0; rg < 4; ++rg) {
                const int row = m*16 + lg*4 + rg;
                const float S = redL[0][row][0] + redL[1][row][0] + redL[2][row][0] + redL[3][row][0];
                const float Q = redL[0][row][1] + redL[1][row][1] + redL[2][row][1] + redL[3][row][1];
                const float mu = S * (1.f/H);
                const float var = Q * (1.f/H) - mu*mu;
                const float rs = rsqrtf(var + LN_EPS);
                float p = 0.f;
                #pragma unroll
                for (int nt = 0; nt < 2; ++nt) {
                    const float v = fmaxf((acc2[m][nt][rg] - mu) * rs * g2[nt] + bb2[nt], 0.f);
                    p += v * w3[nt];
                }
                #pragma unroll
                for (int off = 1; off < 16; off <<= 1) p += __shfl_xor(p, off);
                if (ln == 0) red3[w][row] = p;
            }
        __syncthreads();

        if (tid < 32) {
            const int row = tid;
            const float p = red3[0][row] + red3[1][row] + red3[2][row] + red3[3][row] + b3;
            const int b = r0 + row;
            const int n = b & (N_AG - 1);
            const int m = b >> 13;
            pi_out[(size_t)n * M_MODES + m] = p;
        }
        __syncthreads();
    }
}

extern "C" void kernel_launch(void* const* d_in, const int* in_sizes, int n_in,
                              void* d_out, int out_size, void* d_ws, size_t ws_size,
                              hipStream_t stream) {
    (void)in_sizes; (void)n_in; (void)out_size;
    const float* local_embed  = (const float*)d_in[0];
    const float* global_embed = (const float*)d_in[1];
    const float* W_ih   = (const float*)d_in[2];
    const float* W_hh   = (const float*)d_in[3];
    const float* b_ih   = (const float*)d_in[4];
    const float* b_hh   = (const float*)d_in[5];
    const float* loc1_w = (const float*)d_in[6];
    const float* loc1_b = (const float*)d_in[7];
    const float* loc_ln_g = (const float*)d_in[8];
    const float* loc_ln_b = (const float*)d_in[9];
    const float* loc2_w = (const float*)d_in[10];
    const float* loc2_b = (const float*)d_in[11];
    const float* sc1_w  = (const float*)d_in[12];
    const float* sc1_b  = (const float*)d_in[13];
    const float* sc_ln_g = (const float*)d_in[14];
    const float* sc_ln_b = (const float*)d_in[15];
    const float* sc2_w  = (const float*)d_in[16];
    const float* sc2_b  = (const float*)d_in[17];
    const float* pi1_w  = (const float*)d_in[18];
    const float* pi1_b  = (const float*)d_in[19];
    const float* pi_ln1_g = (const float*)d_in[20];
    const float* pi_ln1_b = (const float*)d_in[21];
    const float* pi2_w  = (const float*)d_in[22];
    const float* pi2_b  = (const float*)d_in[23];
    const float* pi_ln2_g = (const float*)d_in[24];
    const float* pi_ln2_b = (const float*)d_in[25];
    const float* pi3_w  = (const float*)d_in[26];
    const float* pi3_b  = (const float*)d_in[27];

    float* traj = (float*)d_out;
    float* pi_out = traj + (size_t)B_TOT * T_STEPS * 4;

    pi_persist_kernel<<<768, 256, 0, stream>>>(
        local_embed, global_embed, pi1_w, pi1_b, pi_ln1_g, pi_ln1_b,
        pi2_w, pi2_b, pi_ln2_g, pi_ln2_b, pi3_w, pi3_b, pi_out);

    // workspace per chunk of Rc rows: gx (transposed [384][Rc] f32) + hist
    const size_t row_bytes = 384 * sizeof(float) + (size_t)T_STEPS * H * sizeof(unsigned short);
    long long rc = (long long)(ws_size / row_bytes);
    int Rc = rc > B_TOT ? B_TOT : (int)rc;
    Rc &= ~15;

    if (Rc >= 16) {
        float* gx_ws = (float*)d_ws;
        unsigned short* hist = (unsigned short*)(gx_ws + (size_t)Rc * 384);

        for (int basep = 0; basep < B_TOT; basep += Rc) {
            const int rows = (B_TOT - basep < Rc) ? (B_TOT - basep) : Rc;
            const int tiles = rows / 16;

            gx_kernel<<<(tiles < 512 ? tiles : 512), 256, 0, stream>>>(
                global_embed, W_ih, b_ih, b_hh, basep, tiles, Rc, gx_ws);

            gru_rec_kernel<<<(tiles < 512 ? tiles : 512), 256, 0, stream>>>(
                local_embed, gx_ws, W_hh, b_hh, basep, tiles, Rc, hist);

            const int htiles = (rows * T_STEPS) / 32;
            heads_kernel<<<(htiles < 1024 ? htiles : 1024), 256, 0, stream>>>(
                hist, basep, htiles,
                loc1_w, loc1_b, loc_ln_g, loc_ln_b, loc2_w, loc2_b,
                sc1_w, sc1_b, sc_ln_g, sc_ln_b, sc2_w, sc2_b, traj);
        }
    }
}

// Round 8
// 738.570 us; speedup vs baseline: 2.1543x; 1.0159x over previous
//
#include <hip/hip_runtime.h>
#include <math.h>

#define H 128
#define I_DIM 128
#define T_STEPS 30
#define M_MODES 6
#define N_AG 8192
#define B_TOT (M_MODES * N_AG)   /* 49152 */
#define LN_EPS 1e-5f
#define MIN_SCALE 0.001f

typedef short bf16x8 __attribute__((ext_vector_type(8)));
typedef float f32x4 __attribute__((ext_vector_type(4)));

#define MFMA16x16x32(A, B, C) __builtin_amdgcn_mfma_f32_16x16x32_bf16(A, B, C, 0, 0, 0)

__device__ __forceinline__ short f2b(float f) {
    union { float f; unsigned u; } v; v.f = f;
    return (short)((v.u + 0x7FFFu + ((v.u >> 16) & 1u)) >> 16);
}

__device__ __forceinline__ bf16x8 load8_cvt(const float* __restrict__ p) {
    const float4 a = ((const float4*)p)[0];
    const float4 b = ((const float4*)p)[1];
    bf16x8 r;
    r[0]=f2b(a.x); r[1]=f2b(a.y); r[2]=f2b(a.z); r[3]=f2b(a.w);
    r[4]=f2b(b.x); r[5]=f2b(b.y); r[6]=f2b(b.z); r[7]=f2b(b.w);
    return r;
}

__device__ __forceinline__ float fast_sigm(float x) {
    return __builtin_amdgcn_rcpf(1.f + __expf(-x));
}
__device__ __forceinline__ float fast_tanh(float x) {
    return 1.f - 2.f * __builtin_amdgcn_rcpf(1.f + __expf(2.f * x));
}

// ===========================================================================
// Kernel 0: gx = x @ W_ih^T + b_ih (+ b_hh folded for r,z gates).
// Output TRANSPOSED: gx_ws[ch][row], ch in [0,384), stride Rc.
// ===========================================================================
__global__ __launch_bounds__(256, 2) void gx_kernel(
    const float* __restrict__ global_embed,
    const float* __restrict__ W_ih, const float* __restrict__ b_ih,
    const float* __restrict__ b_hh,
    int base, int ntiles, int Rc, float* __restrict__ gx_ws)
{
    __shared__ short xbuf[16][136];

    const int tid = threadIdx.x;
    const int w  = tid >> 6;
    const int l  = tid & 63;
    const int ln = l & 15;
    const int lg = l >> 4;

    bf16x8 wf[6][4];
    float bias[6];
    #pragma unroll
    for (int nt = 0; nt < 6; ++nt) {
        const int ch = 96*w + 16*nt + ln;
        #pragma unroll
        for (int kt = 0; kt < 4; ++kt)
            wf[nt][kt] = load8_cvt(W_ih + (size_t)ch * I_DIM + kt*32 + lg*8);
        bias[nt] = b_ih[ch] + (ch < 2*H ? b_hh[ch] : 0.f);
    }

    const int s_r = tid >> 4, s_sg = tid & 15;

    for (int it = blockIdx.x; it < ntiles; it += gridDim.x) {
        const int r0 = it * 16;
        __syncthreads();
        {
            const float* src = global_embed + (size_t)(base + r0 + s_r) * I_DIM + s_sg*8;
            const float4 a = ((const float4*)src)[0];
            const float4 c = ((const float4*)src)[1];
            short tmp[8];
            tmp[0]=f2b(a.x); tmp[1]=f2b(a.y); tmp[2]=f2b(a.z); tmp[3]=f2b(a.w);
            tmp[4]=f2b(c.x); tmp[5]=f2b(c.y); tmp[6]=f2b(c.z); tmp[7]=f2b(c.w);
            *(uint4*)&xbuf[s_r][s_sg*8] = *(uint4*)tmp;
        }
        __syncthreads();

        bf16x8 af[4];
        #pragma unroll
        for (int kt = 0; kt < 4; ++kt)
            af[kt] = *(const bf16x8*)&xbuf[ln][kt*32 + lg*8];

        f32x4 acc[6];
        #pragma unroll
        for (int nt = 0; nt < 6; ++nt) acc[nt] = (f32x4)(0.f);
        #pragma unroll
        for (int kt = 0; kt < 4; ++kt)
            #pragma unroll
            for (int nt = 0; nt < 6; ++nt)
                acc[nt] = MFMA16x16x32(af[kt], wf[nt][kt], acc[nt]);

        #pragma unroll
        for (int nt = 0; nt < 6; ++nt) {
            const f32x4 v = acc[nt] + (f32x4)(bias[nt]);
            *(f32x4*)(gx_ws + (size_t)(96*w + 16*nt + ln) * Rc + r0 + lg*4) = v;
        }
    }
}

// ===========================================================================
// Kernel A: GRU recurrence — 32 rows/block (two 16-row groups), persistent
// weight-stationary, single barrier per step, double-buffered h.
// ===========================================================================
__global__ __launch_bounds__(256, 2) void gru_rec_kernel(
    const float* __restrict__ local_embed, const float* __restrict__ gx_ws,
    const float* __restrict__ W_hh, const float* __restrict__ b_hh,
    int base, int ntiles, int Rc, unsigned short* __restrict__ hist)
{
    __shared__ short hb0[32][136];
    __shared__ short hb1[32][136];

    const int tid = threadIdx.x;
    const int w  = tid >> 6;
    const int l  = tid & 63;
    const int ln = l & 15;
    const int lg = l >> 4;

    bf16x8 wf[3][2][4];
    float bhn[2];
    #pragma unroll
    for (int u = 0; u < 2; ++u) {
        const int c = 32*w + 16*u + ln;
        bhn[u] = b_hh[2*H + c];
        #pragma unroll
        for (int g = 0; g < 3; ++g) {
            const int crow = g*H + c;
            #pragma unroll
            for (int kt = 0; kt < 4; ++kt)
                wf[g][u][kt] = load8_cvt(W_hh + (size_t)crow * H + kt*32 + lg*8);
        }
    }

    const int sr  = tid >> 4;      // 0..15
    const int seg = tid & 15;

    for (int it = blockIdx.x; it < ntiles; it += gridDim.x) {
        const int lb0 = it * 32;
        __syncthreads();                              // prev tile reads done

        // stage h0 -> hb0 (bf16): rows sr and sr+16
        #pragma unroll
        for (int rr2 = 0; rr2 < 2; ++rr2) {
            const int r = sr + rr2*16;
            const int b = base + lb0 + r;
            const int n = b & (N_AG - 1);
            const float* src = local_embed + (size_t)n * H + seg*8;
            const float4 a = ((const float4*)src)[0];
            const float4 c = ((const float4*)src)[1];
            short tmp[8];
            tmp[0]=f2b(a.x); tmp[1]=f2b(a.y); tmp[2]=f2b(a.z); tmp[3]=f2b(a.w);
            tmp[4]=f2b(c.x); tmp[5]=f2b(c.y); tmp[6]=f2b(c.z); tmp[7]=f2b(c.w);
            *(uint4*)&hb0[r][seg*8] = *(uint4*)tmp;
        }

        // h0 master copies (f32) for owned channels, both row groups
        float h_reg[2][2][4];
        #pragma unroll
        for (int grp = 0; grp < 2; ++grp)
            #pragma unroll
            for (int u = 0; u < 2; ++u) {
                const int j = 32*w + 16*u + ln;
                #pragma unroll
                for (int rg = 0; rg < 4; ++rg) {
                    const int b = base + lb0 + grp*16 + lg*4 + rg;
                    const int n = b & (N_AG - 1);
                    h_reg[grp][u][rg] = local_embed[(size_t)n * H + j];
                }
            }

        // gx (transposed layout -> float4 loads), both row groups
        float gx[2][3][2][4];
        #pragma unroll
        for (int grp = 0; grp < 2; ++grp)
            #pragma unroll
            for (int g = 0; g < 3; ++g)
                #pragma unroll
                for (int u = 0; u < 2; ++u) {
                    const int ch = g*128 + 32*w + 16*u + ln;
                    const f32x4 v = *(const f32x4*)(gx_ws + (size_t)ch * Rc + lb0 + grp*16 + lg*4);
                    #pragma unroll
                    for (int rg = 0; rg < 4; ++rg) gx[grp][g][u][rg] = v[rg];
                }
        __syncthreads();                              // h0 staged

        int cur = 0;
        for (int t = 0; t < T_STEPS; ++t) {
            const short* hcur = cur ? &hb1[0][0] : &hb0[0][0];
            short*       hnxt = cur ? &hb0[0][0] : &hb1[0][0];

            #pragma unroll
            for (int grp = 0; grp < 2; ++grp) {
                bf16x8 af[4];
                #pragma unroll
                for (int kt = 0; kt < 4; ++kt)
                    af[kt] = *(const bf16x8*)&hcur[(grp*16 + ln)*136 + kt*32 + lg*8];

                f32x4 ga[3][2];
                #pragma unroll
                for (int g = 0; g < 3; ++g)
                    #pragma unroll
                    for (int u = 0; u < 2; ++u) ga[g][u] = (f32x4)(0.f);
                #pragma unroll
                for (int kt = 0; kt < 4; ++kt)
                    #pragma unroll
                    for (int g = 0; g < 3; ++g)
                        #pragma unroll
                        for (int u = 0; u < 2; ++u)
                            ga[g][u] = MFMA16x16x32(af[kt], wf[g][u][kt], ga[g][u]);

                #pragma unroll
                for (int u = 0; u < 2; ++u) {
                    const int j = 32*w + 16*u + ln;
                    #pragma unroll
                    for (int rg = 0; rg < 4; ++rg) {
                        const float rr = fast_sigm(gx[grp][0][u][rg] + ga[0][u][rg]);
                        const float zz = fast_sigm(gx[grp][1][u][rg] + ga[1][u][rg]);
                        const float nn = fast_tanh(gx[grp][2][u][rg] + rr * (ga[2][u][rg] + bhn[u]));
                        const float h  = (1.f - zz) * nn + zz * h_reg[grp][u][rg];
                        h_reg[grp][u][rg] = h;
                        hnxt[(grp*16 + lg*4 + rg)*136 + j] = f2b(h);
                    }
                }
            }
            __syncthreads();                          // h(t+1) visible

            #pragma unroll
            for (int rr2 = 0; rr2 < 2; ++rr2) {
                const int r = sr + rr2*16;
                const uint4 hv = *(const uint4*)&hnxt[r*136 + seg*8];
                *(uint4*)(hist + (size_t)(lb0 + r) * (T_STEPS * H) + t * H + seg*8) = hv;
            }
            cur ^= 1;
        }
    }
}

// ===========================================================================
// Kernel B: loc/scale heads — barrier-free, LDS-free, wave-autonomous.
// Wave-task = (16-row tile, head). A-fragments loaded directly from global
// hist (coalesced dwordx4 per 16-lane group). Weights stationary per wave.
// ===========================================================================
__global__ __launch_bounds__(256, 2) void heads_kernel(
    const unsigned short* __restrict__ hist, int base, int ntiles16,
    const float* __restrict__ loc1_w, const float* __restrict__ loc1_b,
    const float* __restrict__ loc_ln_g, const float* __restrict__ loc_ln_b,
    const float* __restrict__ loc2_w, const float* __restrict__ loc2_b,
    const float* __restrict__ sc1_w, const float* __restrict__ sc1_b,
    const float* __restrict__ sc_ln_g, const float* __restrict__ sc_ln_b,
    const float* __restrict__ sc2_w, const float* __restrict__ sc2_b,
    float* __restrict__ traj)
{
    const int tid = threadIdx.x;
    const int w  = tid >> 6;
    const int l  = tid & 63;
    const int ln = l & 15;
    const int lg = l >> 4;

    const int gw = blockIdx.x * 4 + w;     // global wave id
    const int hd = gw & 1;                 // 0 = loc, 1 = sc
    const int wstride = gridDim.x * 2;     // tile stride per head

    const float* __restrict__ W1  = hd ? sc1_w   : loc1_w;
    const float* __restrict__ B1v = hd ? sc1_b   : loc1_b;
    const float* __restrict__ Gv  = hd ? sc_ln_g : loc_ln_g;
    const float* __restrict__ Bv  = hd ? sc_ln_b : loc_ln_b;
    const float* __restrict__ W2  = hd ? sc2_w   : loc2_w;
    const float* __restrict__ B2v = hd ? sc2_b   : loc2_b;

    // full head: 8 col-fragments (128 channels), stationary
    bf16x8 wf[8][4];
    float bias1[8], lng[8], lnb[8], w2a[8], w2b[8];
    #pragma unroll
    for (int nt = 0; nt < 8; ++nt) {
        const int c = 16*nt + ln;
        #pragma unroll
        for (int kt = 0; kt < 4; ++kt)
            wf[nt][kt] = load8_cvt(W1 + (size_t)c * H + kt*32 + lg*8);
        bias1[nt] = B1v[c]; lng[nt] = Gv[c]; lnb[nt] = Bv[c];
        w2a[nt] = W2[c];    w2b[nt] = W2[H + c];
    }
    const float b2_0 = B2v[0], b2_1 = B2v[1];

    for (int tile = gw >> 1; tile < ntiles16; tile += wstride) {
        // A-fragments: direct global loads (row = tile*16 + ln)
        const unsigned short* rowp = hist + (size_t)(tile * 16 + ln) * H;
        bf16x8 af[4];
        #pragma unroll
        for (int kt = 0; kt < 4; ++kt)
            af[kt] = *(const bf16x8*)(rowp + kt*32 + lg*8);

        f32x4 acc[8];
        #pragma unroll
        for (int nt = 0; nt < 8; ++nt) acc[nt] = (f32x4)(0.f);
        #pragma unroll
        for (int kt = 0; kt < 4; ++kt)
            #pragma unroll
            for (int nt = 0; nt < 8; ++nt)
                acc[nt] = MFMA16x16x32(af[kt], wf[nt][kt], acc[nt]);

        // wave-local epilogue per row-group
        #pragma unroll
        for (int rg = 0; rg < 4; ++rg) {
            float s = 0.f, q = 0.f;
            #pragma unroll
            for (int nt = 0; nt < 8; ++nt) {
                const float a = acc[nt][rg] + bias1[nt];
                acc[nt][rg] = a;
                s += a; q += a*a;
            }
            #pragma unroll
            for (int off = 1; off < 16; off <<= 1) {
                s += __shfl_xor(s, off);
                q += __shfl_xor(q, off);
            }
            const float mu = s * (1.f/H);
            const float var = q * (1.f/H) - mu*mu;
            const float rs = rsqrtf(var + LN_EPS);
            float p0 = 0.f, p1 = 0.f;
            #pragma unroll
            for (int nt = 0; nt < 8; ++nt) {
                float v = (acc[nt][rg] - mu) * rs * lng[nt] + lnb[nt];
                v = fmaxf(v, 0.f);
                p0 += v * w2a[nt];
                p1 += v * w2b[nt];
            }
            #pragma unroll
            for (int off = 1; off < 16; off <<= 1) {
                p0 += __shfl_xor(p0, off);
                p1 += __shfl_xor(p1, off);
            }
            if (ln == 0) {
                const int flat = tile * 16 + lg*4 + rg;
                const int lb = flat / T_STEPS;
                const int t = flat - lb * T_STEPS;
                const int b = base + lb;
                float v0 = p0 + b2_0;
                float v1 = p1 + b2_1;
                if (hd) {
                    v0 = (v0 > 0.f ? v0 : expm1f(v0)) + 1.0f + MIN_SCALE;
                    v1 = (v1 > 0.f ? v1 : expm1f(v1)) + 1.0f + MIN_SCALE;
                }
                *(float2*)(traj + ((size_t)b * T_STEPS + t) * 4 + hd*2) = make_float2(v0, v1);
            }
        }
    }
}

// ===========================================================================
// Kernel C: pi head — weight-stationary persistent (768 blocks). Unchanged.
// ===========================================================================
__global__ __launch_bounds__(256, 2) void pi_persist_kernel(
    const float* __restrict__ local_embed, const float* __restrict__ global_embed,
    const float* __restrict__ pi1_w, const float* __restrict__ pi1_b,
    const float* __restrict__ ln1_g, const float* __restrict__ ln1_b,
    const float* __restrict__ pi2_w, const float* __restrict__ pi2_b,
    const float* __restrict__ ln2_g, const float* __restrict__ ln2_b,
    const float* __restrict__ pi3_w, const float* __restrict__ pi3_b,
    float* __restrict__ pi_out)
{
    __shared__ short inbf[32][264];
    __shared__ short h1bf[32][136];
    __shared__ float redL[4][32][2];
    __shared__ float red3[4][32];

    const int tid = threadIdx.x;
    const int w  = tid >> 6;
    const int l  = tid & 63;
    const int ln = l & 15;
    const int lg = l >> 4;

    bf16x8 wf1[2][8];
    bf16x8 wf2[2][4];
    float b1[2], g1[2], bb1[2], b2[2], g2[2], bb2[2], w3[2];
    #pragma unroll
    for (int nt = 0; nt < 2; ++nt) {
        const int c = 32*w + 16*nt + ln;
        #pragma unroll
        for (int kt = 0; kt < 8; ++kt)
            wf1[nt][kt] = load8_cvt(pi1_w + (size_t)c * (2*H) + kt*32 + lg*8);
        #pragma unroll
        for (int kt = 0; kt < 4; ++kt)
            wf2[nt][kt] = load8_cvt(pi2_w + (size_t)c * H + kt*32 + lg*8);
        b1[nt] = pi1_b[c]; g1[nt] = ln1_g[c]; bb1[nt] = ln1_b[c];
        b2[nt] = pi2_b[c]; g2[nt] = ln2_g[c]; bb2[nt] = ln2_b[c];
        w3[nt] = pi3_w[c];
    }
    const float b3 = pi3_b[0];

    const int ntiles = B_TOT / 32;

    for (int it = blockIdx.x; it < ntiles; it += gridDim.x) {
        const int r0 = it * 32;
        {
            const int r   = tid >> 3;
            const int seg = tid & 7;
            const int b = r0 + r;
            const int n = b & (N_AG - 1);
            const float* src = (seg < 4) ? (local_embed + (size_t)n * H + seg * 32)
                                         : (global_embed + (size_t)b * I_DIM + (seg - 4) * 32);
            short tmp[32];
            #pragma unroll
            for (int i = 0; i < 8; ++i) {
                const float4 v = ((const float4*)src)[i];
                tmp[i*4+0]=f2b(v.x); tmp[i*4+1]=f2b(v.y); tmp[i*4+2]=f2b(v.z); tmp[i*4+3]=f2b(v.w);
            }
            #pragma unroll
            for (int i = 0; i < 4; ++i)
                *(uint4*)&inbf[r][seg*32 + i*8] = *(uint4*)&tmp[i*8];
        }
        __syncthreads();

        f32x4 acc1[2][2];
        #pragma unroll
        for (int m = 0; m < 2; ++m) {
            #pragma unroll
            for (int nt = 0; nt < 2; ++nt) acc1[m][nt] = (f32x4)(0.f);
            bf16x8 af[8];
            #pragma unroll
            for (int kt = 0; kt < 8; ++kt)
                af[kt] = *(const bf16x8*)&inbf[m*16 + ln][kt*32 + lg*8];
            #pragma unroll
            for (int kt = 0; kt < 8; ++kt)
                #pragma unroll
                for (int nt = 0; nt < 2; ++nt)
                    acc1[m][nt] = MFMA16x16x32(af[kt], wf1[nt][kt], acc1[m][nt]);
        }

        #pragma unroll
        for (int m = 0; m < 2; ++m)
            #pragma unroll
            for (int rg = 0; rg < 4; ++rg) {
                float s = 0.f, q = 0.f;
                #pragma unroll
                for (int nt = 0; nt < 2; ++nt) {
                    const float a = acc1[m][nt][rg] + b1[nt];
                    acc1[m][nt][rg] = a;
                    s += a; q += a*a;
                }
                #pragma unroll
                for (int off = 1; off < 16; off <<= 1) {
                    s += __shfl_xor(s, off);
                    q += __shfl_xor(q, off);
                }
                if (ln == 0) {
                    const int row = m*16 + lg*4 + rg;
                    redL[w][row][0] = s;
                    redL[w][row][1] = q;
                }
            }
        __syncthreads();

        #pragma unroll
        for (int m = 0; m < 2; ++m)
            #pragma unroll
            for (int rg = 0; rg < 4; ++rg) {
                const int row = m*16 + lg*4 + rg;
                const float S = redL[0][row][0] + redL[1][row][0] + redL[2][row][0] + redL[3][row][0];
                const float Q = redL[0][row][1] + redL[1][row][1] + redL[2][row][1] + redL[3][row][1];
                const float mu = S * (1.f/H);
                const float var = Q * (1.f/H) - mu*mu;
                const float rs = rsqrtf(var + LN_EPS);
                #pragma unroll
                for (int nt = 0; nt < 2; ++nt) {
                    const float v = fmaxf((acc1[m][nt][rg] - mu) * rs * g1[nt] + bb1[nt], 0.f);
                    h1bf[row][32*w + 16*nt + ln] = f2b(v);
                }
            }
        __syncthreads();

        f32x4 acc2[2][2];
        #pragma unroll
        for (int m = 0; m < 2; ++m) {
            #pragma unroll
            for (int nt = 0; nt < 2; ++nt) acc2[m][nt] = (f32x4)(0.f);
            bf16x8 af[4];
            #pragma unroll
            for (int kt = 0; kt < 4; ++kt)
                af[kt] = *(const bf16x8*)&h1bf[m*16 + ln][kt*32 + lg*8];
            #pragma unroll
            for (int kt = 0; kt < 4; ++kt)
                #pragma unroll
                for (int nt = 0; nt < 2; ++nt)
                    acc2[m][nt] = MFMA16x16x32(af[kt], wf2[nt][kt], acc2[m][nt]);
        }

        #pragma unroll
        for (int m = 0; m < 2; ++m)
            #pragma unroll
            for (int rg = 0; rg < 4; ++rg) {
                float s = 0.f, q = 0.f;
                #pragma unroll
                for (int nt = 0; nt < 2; ++nt) {
                    const float a = acc2[m][nt][rg] + b2[nt];
                    acc2[m][nt][rg] = a;
                    s += a; q += a*a;
                }
                #pragma unroll
                for (int off = 1; off < 16; off <<= 1) {
                    s += __shfl_xor(s, off);
                    q += __shfl_xor(q, off);
                }
                if (ln == 0) {
                    const int row = m*16 + lg*4 + rg;
                    redL[w][row][0] = s;
                    redL[w][row][1] = q;
                }
            }
        __syncthreads();

        #pragma unroll
        for (int m = 0; m < 2; ++m)
            #pragma unroll
            for (int rg = 0; rg < 4; ++rg) {
                const int row = m*16 + lg*4 + rg;
                const float S = redL[0][row][0] + redL[1][row][0] + redL[2][row][0] + redL[3][row][0];
                const float Q = redL[0][row][1] + redL[1][row][1] + redL[2][row][1] + redL[3][row][1];
                const float mu = S * (1.f/H);
                const float var = Q * (1.f/H) - mu*mu;
                const float rs = rsqrtf(var + LN_EPS);
                float p = 0.f;
                #pragma unroll
                for (int nt = 0; nt < 2; ++nt) {
                    const float v = fmaxf((acc2[m][nt][rg] - mu) * rs * g2[nt] + bb2[nt], 0.f);
                    p += v * w3[nt];
                }
                #pragma unroll
                for (int off = 1; off < 16; off <<= 1) p += __shfl_xor(p, off);
                if (ln == 0) red3[w][row] = p;
            }
        __syncthreads();

        if (tid < 32) {
            const int row = tid;
            const float p = red3[0][row] + red3[1][row] + red3[2][row] + red3[3][row] + b3;
            const int b = r0 + row;
            const int n = b & (N_AG - 1);
            const int m = b >> 13;
            pi_out[(size_t)n * M_MODES + m] = p;
        }
        __syncthreads();
    }
}

extern "C" void kernel_launch(void* const* d_in, const int* in_sizes, int n_in,
                              void* d_out, int out_size, void* d_ws, size_t ws_size,
                              hipStream_t stream) {
    (void)in_sizes; (void)n_in; (void)out_size;
    const float* local_embed  = (const float*)d_in[0];
    const float* global_embed = (const float*)d_in[1];
    const float* W_ih   = (const float*)d_in[2];
    const float* W_hh   = (const float*)d_in[3];
    const float* b_ih   = (const float*)d_in[4];
    const float* b_hh   = (const float*)d_in[5];
    const float* loc1_w = (const float*)d_in[6];
    const float* loc1_b = (const float*)d_in[7];
    const float* loc_ln_g = (const float*)d_in[8];
    const float* loc_ln_b = (const float*)d_in[9];
    const float* loc2_w = (const float*)d_in[10];
    const float* loc2_b = (const float*)d_in[11];
    const float* sc1_w  = (const float*)d_in[12];
    const float* sc1_b  = (const float*)d_in[13];
    const float* sc_ln_g = (const float*)d_in[14];
    const float* sc_ln_b = (const float*)d_in[15];
    const float* sc2_w  = (const float*)d_in[16];
    const float* sc2_b  = (const float*)d_in[17];
    const float* pi1_w  = (const float*)d_in[18];
    const float* pi1_b  = (const float*)d_in[19];
    const float* pi_ln1_g = (const float*)d_in[20];
    const float* pi_ln1_b = (const float*)d_in[21];
    const float* pi2_w  = (const float*)d_in[22];
    const float* pi2_b  = (const float*)d_in[23];
    const float* pi_ln2_g = (const float*)d_in[24];
    const float* pi_ln2_b = (const float*)d_in[25];
    const float* pi3_w  = (const float*)d_in[26];
    const float* pi3_b  = (const float*)d_in[27];

    float* traj = (float*)d_out;
    float* pi_out = traj + (size_t)B_TOT * T_STEPS * 4;

    pi_persist_kernel<<<768, 256, 0, stream>>>(
        local_embed, global_embed, pi1_w, pi1_b, pi_ln1_g, pi_ln1_b,
        pi2_w, pi2_b, pi_ln2_g, pi_ln2_b, pi3_w, pi3_b, pi_out);

    // workspace per chunk of Rc rows: gx (transposed [384][Rc] f32) + hist
    const size_t row_bytes = 384 * sizeof(float) + (size_t)T_STEPS * H * sizeof(unsigned short);
    long long rc = (long long)(ws_size / row_bytes);
    int Rc = rc > B_TOT ? B_TOT : (int)rc;
    Rc &= ~31;

    if (Rc >= 32) {
        float* gx_ws = (float*)d_ws;
        unsigned short* hist = (unsigned short*)(gx_ws + (size_t)Rc * 384);

        for (int basep = 0; basep < B_TOT; basep += Rc) {
            const int rows = (B_TOT - basep < Rc) ? (B_TOT - basep) : Rc;

            const int gxtiles = rows / 16;
            gx_kernel<<<(gxtiles < 512 ? gxtiles : 512), 256, 0, stream>>>(
                global_embed, W_ih, b_ih, b_hh, basep, gxtiles, Rc, gx_ws);

            const int rtiles = rows / 32;
            gru_rec_kernel<<<(rtiles < 512 ? rtiles : 512), 256, 0, stream>>>(
                local_embed, gx_ws, W_hh, b_hh, basep, rtiles, Rc, hist);

            const int htiles16 = (rows * T_STEPS) / 16;
            const int hblk = (htiles16 + 1) / 2 < 1024 ? (htiles16 + 1) / 2 : 1024;
            heads_kernel<<<hblk, 256, 0, stream>>>(
                hist, basep, htiles16,
                loc1_w, loc1_b, loc_ln_g, loc_ln_b, loc2_w, loc2_b,
                sc1_w, sc1_b, sc_ln_g, sc_ln_b, sc2_w, sc2_b, traj);
        }
    }
}

// Round 9
// 721.350 us; speedup vs baseline: 2.2057x; 1.0239x over previous
//
#include <hip/hip_runtime.h>
#include <math.h>

#define H 128
#define I_DIM 128
#define T_STEPS 30
#define M_MODES 6
#define N_AG 8192
#define B_TOT (M_MODES * N_AG)   /* 49152 */
#define LN_EPS 1e-5f
#define MIN_SCALE 0.001f

typedef short bf16x8 __attribute__((ext_vector_type(8)));
typedef float f32x4 __attribute__((ext_vector_type(4)));

#define MFMA16x16x32(A, B, C) __builtin_amdgcn_mfma_f32_16x16x32_bf16(A, B, C, 0, 0, 0)

__device__ __forceinline__ short f2b(float f) {
    union { float f; unsigned u; } v; v.f = f;
    return (short)((v.u + 0x7FFFu + ((v.u >> 16) & 1u)) >> 16);
}

__device__ __forceinline__ bf16x8 load8_cvt(const float* __restrict__ p) {
    const float4 a = ((const float4*)p)[0];
    const float4 b = ((const float4*)p)[1];
    bf16x8 r;
    r[0]=f2b(a.x); r[1]=f2b(a.y); r[2]=f2b(a.z); r[3]=f2b(a.w);
    r[4]=f2b(b.x); r[5]=f2b(b.y); r[6]=f2b(b.z); r[7]=f2b(b.w);
    return r;
}

__device__ __forceinline__ float fast_sigm(float x) {
    return __builtin_amdgcn_rcpf(1.f + __expf(-x));
}
__device__ __forceinline__ float fast_tanh(float x) {
    return 1.f - 2.f * __builtin_amdgcn_rcpf(1.f + __expf(2.f * x));
}

// 16-lane all-reduce sum via DPP (VALU pipe; no DS-pipe shuffles).
// quad_perm xor1, xor2, then row_ror 4, 8 — all lanes end with the group sum.
#define DPP_ADD(v, ctrl)                                                     \
    v += __builtin_bit_cast(float, __builtin_amdgcn_mov_dpp(                 \
             __builtin_bit_cast(int, v), ctrl, 0xF, 0xF, true))

__device__ __forceinline__ float red16(float v) {
    DPP_ADD(v, 0xB1);    // quad_perm [1,0,3,2]  (xor 1)
    DPP_ADD(v, 0x4E);    // quad_perm [2,3,0,1]  (xor 2)
    DPP_ADD(v, 0x124);   // row_ror:4
    DPP_ADD(v, 0x128);   // row_ror:8
    return v;
}

// ===========================================================================
// Kernel 0: gx = x @ W_ih^T + b_ih (+ b_hh folded for r,z gates).
// Output TRANSPOSED: gx_ws[ch][row], ch in [0,384), stride Rc.
// ===========================================================================
__global__ __launch_bounds__(256, 2) void gx_kernel(
    const float* __restrict__ global_embed,
    const float* __restrict__ W_ih, const float* __restrict__ b_ih,
    const float* __restrict__ b_hh,
    int base, int ntiles, int Rc, float* __restrict__ gx_ws)
{
    __shared__ short xbuf[16][136];

    const int tid = threadIdx.x;
    const int w  = tid >> 6;
    const int l  = tid & 63;
    const int ln = l & 15;
    const int lg = l >> 4;

    bf16x8 wf[6][4];
    float bias[6];
    #pragma unroll
    for (int nt = 0; nt < 6; ++nt) {
        const int ch = 96*w + 16*nt + ln;
        #pragma unroll
        for (int kt = 0; kt < 4; ++kt)
            wf[nt][kt] = load8_cvt(W_ih + (size_t)ch * I_DIM + kt*32 + lg*8);
        bias[nt] = b_ih[ch] + (ch < 2*H ? b_hh[ch] : 0.f);
    }

    const int s_r = tid >> 4, s_sg = tid & 15;

    for (int it = blockIdx.x; it < ntiles; it += gridDim.x) {
        const int r0 = it * 16;
        __syncthreads();
        {
            const float* src = global_embed + (size_t)(base + r0 + s_r) * I_DIM + s_sg*8;
            const float4 a = ((const float4*)src)[0];
            const float4 c = ((const float4*)src)[1];
            short tmp[8];
            tmp[0]=f2b(a.x); tmp[1]=f2b(a.y); tmp[2]=f2b(a.z); tmp[3]=f2b(a.w);
            tmp[4]=f2b(c.x); tmp[5]=f2b(c.y); tmp[6]=f2b(c.z); tmp[7]=f2b(c.w);
            *(uint4*)&xbuf[s_r][s_sg*8] = *(uint4*)tmp;
        }
        __syncthreads();

        bf16x8 af[4];
        #pragma unroll
        for (int kt = 0; kt < 4; ++kt)
            af[kt] = *(const bf16x8*)&xbuf[ln][kt*32 + lg*8];

        f32x4 acc[6];
        #pragma unroll
        for (int nt = 0; nt < 6; ++nt) acc[nt] = (f32x4)(0.f);
        #pragma unroll
        for (int kt = 0; kt < 4; ++kt)
            #pragma unroll
            for (int nt = 0; nt < 6; ++nt)
                acc[nt] = MFMA16x16x32(af[kt], wf[nt][kt], acc[nt]);

        #pragma unroll
        for (int nt = 0; nt < 6; ++nt) {
            const f32x4 v = acc[nt] + (f32x4)(bias[nt]);
            *(f32x4*)(gx_ws + (size_t)(96*w + 16*nt + ln) * Rc + r0 + lg*4) = v;
        }
    }
}

// ===========================================================================
// Kernel A: GRU recurrence — 32 rows/block, persistent weight-stationary,
// single barrier per step, double-buffered h. Unchanged from round 8.
// ===========================================================================
__global__ __launch_bounds__(256, 2) void gru_rec_kernel(
    const float* __restrict__ local_embed, const float* __restrict__ gx_ws,
    const float* __restrict__ W_hh, const float* __restrict__ b_hh,
    int base, int ntiles, int Rc, unsigned short* __restrict__ hist)
{
    __shared__ short hb0[32][136];
    __shared__ short hb1[32][136];

    const int tid = threadIdx.x;
    const int w  = tid >> 6;
    const int l  = tid & 63;
    const int ln = l & 15;
    const int lg = l >> 4;

    bf16x8 wf[3][2][4];
    float bhn[2];
    #pragma unroll
    for (int u = 0; u < 2; ++u) {
        const int c = 32*w + 16*u + ln;
        bhn[u] = b_hh[2*H + c];
        #pragma unroll
        for (int g = 0; g < 3; ++g) {
            const int crow = g*H + c;
            #pragma unroll
            for (int kt = 0; kt < 4; ++kt)
                wf[g][u][kt] = load8_cvt(W_hh + (size_t)crow * H + kt*32 + lg*8);
        }
    }

    const int sr  = tid >> 4;
    const int seg = tid & 15;

    for (int it = blockIdx.x; it < ntiles; it += gridDim.x) {
        const int lb0 = it * 32;
        __syncthreads();

        #pragma unroll
        for (int rr2 = 0; rr2 < 2; ++rr2) {
            const int r = sr + rr2*16;
            const int b = base + lb0 + r;
            const int n = b & (N_AG - 1);
            const float* src = local_embed + (size_t)n * H + seg*8;
            const float4 a = ((const float4*)src)[0];
            const float4 c = ((const float4*)src)[1];
            short tmp[8];
            tmp[0]=f2b(a.x); tmp[1]=f2b(a.y); tmp[2]=f2b(a.z); tmp[3]=f2b(a.w);
            tmp[4]=f2b(c.x); tmp[5]=f2b(c.y); tmp[6]=f2b(c.z); tmp[7]=f2b(c.w);
            *(uint4*)&hb0[r][seg*8] = *(uint4*)tmp;
        }

        float h_reg[2][2][4];
        #pragma unroll
        for (int grp = 0; grp < 2; ++grp)
            #pragma unroll
            for (int u = 0; u < 2; ++u) {
                const int j = 32*w + 16*u + ln;
                #pragma unroll
                for (int rg = 0; rg < 4; ++rg) {
                    const int b = base + lb0 + grp*16 + lg*4 + rg;
                    const int n = b & (N_AG - 1);
                    h_reg[grp][u][rg] = local_embed[(size_t)n * H + j];
                }
            }

        float gx[2][3][2][4];
        #pragma unroll
        for (int grp = 0; grp < 2; ++grp)
            #pragma unroll
            for (int g = 0; g < 3; ++g)
                #pragma unroll
                for (int u = 0; u < 2; ++u) {
                    const int ch = g*128 + 32*w + 16*u + ln;
                    const f32x4 v = *(const f32x4*)(gx_ws + (size_t)ch * Rc + lb0 + grp*16 + lg*4);
                    #pragma unroll
                    for (int rg = 0; rg < 4; ++rg) gx[grp][g][u][rg] = v[rg];
                }
        __syncthreads();

        int cur = 0;
        for (int t = 0; t < T_STEPS; ++t) {
            const short* hcur = cur ? &hb1[0][0] : &hb0[0][0];
            short*       hnxt = cur ? &hb0[0][0] : &hb1[0][0];

            #pragma unroll
            for (int grp = 0; grp < 2; ++grp) {
                bf16x8 af[4];
                #pragma unroll
                for (int kt = 0; kt < 4; ++kt)
                    af[kt] = *(const bf16x8*)&hcur[(grp*16 + ln)*136 + kt*32 + lg*8];

                f32x4 ga[3][2];
                #pragma unroll
                for (int g = 0; g < 3; ++g)
                    #pragma unroll
                    for (int u = 0; u < 2; ++u) ga[g][u] = (f32x4)(0.f);
                #pragma unroll
                for (int kt = 0; kt < 4; ++kt)
                    #pragma unroll
                    for (int g = 0; g < 3; ++g)
                        #pragma unroll
                        for (int u = 0; u < 2; ++u)
                            ga[g][u] = MFMA16x16x32(af[kt], wf[g][u][kt], ga[g][u]);

                #pragma unroll
                for (int u = 0; u < 2; ++u) {
                    const int j = 32*w + 16*u + ln;
                    #pragma unroll
                    for (int rg = 0; rg < 4; ++rg) {
                        const float rr = fast_sigm(gx[grp][0][u][rg] + ga[0][u][rg]);
                        const float zz = fast_sigm(gx[grp][1][u][rg] + ga[1][u][rg]);
                        const float nn = fast_tanh(gx[grp][2][u][rg] + rr * (ga[2][u][rg] + bhn[u]));
                        const float h  = (1.f - zz) * nn + zz * h_reg[grp][u][rg];
                        h_reg[grp][u][rg] = h;
                        hnxt[(grp*16 + lg*4 + rg)*136 + j] = f2b(h);
                    }
                }
            }
            __syncthreads();

            #pragma unroll
            for (int rr2 = 0; rr2 < 2; ++rr2) {
                const int r = sr + rr2*16;
                const uint4 hv = *(const uint4*)&hnxt[r*136 + seg*8];
                *(uint4*)(hist + (size_t)(lb0 + r) * (T_STEPS * H) + t * H + seg*8) = hv;
            }
            cur ^= 1;
        }
    }
}

// ===========================================================================
// Kernel B: loc/scale heads — barrier-free, LDS-free, wave-autonomous,
// DPP-based LN/linear-2 reductions (VALU pipe, no DS shuffles).
// ===========================================================================
__global__ __launch_bounds__(256, 2) void heads_kernel(
    const unsigned short* __restrict__ hist, int base, int ntiles16,
    const float* __restrict__ loc1_w, const float* __restrict__ loc1_b,
    const float* __restrict__ loc_ln_g, const float* __restrict__ loc_ln_b,
    const float* __restrict__ loc2_w, const float* __restrict__ loc2_b,
    const float* __restrict__ sc1_w, const float* __restrict__ sc1_b,
    const float* __restrict__ sc_ln_g, const float* __restrict__ sc_ln_b,
    const float* __restrict__ sc2_w, const float* __restrict__ sc2_b,
    float* __restrict__ traj)
{
    const int tid = threadIdx.x;
    const int w  = tid >> 6;
    const int l  = tid & 63;
    const int ln = l & 15;
    const int lg = l >> 4;

    const int gw = blockIdx.x * 4 + w;     // global wave id
    const int hd = gw & 1;                 // 0 = loc, 1 = sc
    const int wstride = gridDim.x * 2;     // tile stride per head

    const float* __restrict__ W1  = hd ? sc1_w   : loc1_w;
    const float* __restrict__ B1v = hd ? sc1_b   : loc1_b;
    const float* __restrict__ Gv  = hd ? sc_ln_g : loc_ln_g;
    const float* __restrict__ Bv  = hd ? sc_ln_b : loc_ln_b;
    const float* __restrict__ W2  = hd ? sc2_w   : loc2_w;
    const float* __restrict__ B2v = hd ? sc2_b   : loc2_b;

    bf16x8 wf[8][4];
    float bias1[8], lng[8], lnb[8], w2a[8], w2b[8];
    #pragma unroll
    for (int nt = 0; nt < 8; ++nt) {
        const int c = 16*nt + ln;
        #pragma unroll
        for (int kt = 0; kt < 4; ++kt)
            wf[nt][kt] = load8_cvt(W1 + (size_t)c * H + kt*32 + lg*8);
        bias1[nt] = B1v[c]; lng[nt] = Gv[c]; lnb[nt] = Bv[c];
        w2a[nt] = W2[c];    w2b[nt] = W2[H + c];
    }
    const float b2_0 = B2v[0], b2_1 = B2v[1];

    for (int tile = gw >> 1; tile < ntiles16; tile += wstride) {
        const unsigned short* rowp = hist + (size_t)(tile * 16 + ln) * H;
        bf16x8 af[4];
        #pragma unroll
        for (int kt = 0; kt < 4; ++kt)
            af[kt] = *(const bf16x8*)(rowp + kt*32 + lg*8);

        f32x4 acc[8];
        #pragma unroll
        for (int nt = 0; nt < 8; ++nt) acc[nt] = (f32x4)(0.f);
        #pragma unroll
        for (int kt = 0; kt < 4; ++kt)
            #pragma unroll
            for (int nt = 0; nt < 8; ++nt)
                acc[nt] = MFMA16x16x32(af[kt], wf[nt][kt], acc[nt]);

        #pragma unroll
        for (int rg = 0; rg < 4; ++rg) {
            float s = 0.f, q = 0.f;
            #pragma unroll
            for (int nt = 0; nt < 8; ++nt) {
                const float a = acc[nt][rg] + bias1[nt];
                acc[nt][rg] = a;
                s += a; q += a*a;
            }
            s = red16(s);
            q = red16(q);
            const float mu = s * (1.f/H);
            const float var = q * (1.f/H) - mu*mu;
            const float rs = rsqrtf(var + LN_EPS);
            const float murs = mu * rs;
            float p0 = 0.f, p1 = 0.f;
            #pragma unroll
            for (int nt = 0; nt < 8; ++nt) {
                float v = fmaf(fmaf(acc[nt][rg], rs, -murs), lng[nt], lnb[nt]);
                v = fmaxf(v, 0.f);
                p0 = fmaf(v, w2a[nt], p0);
                p1 = fmaf(v, w2b[nt], p1);
            }
            p0 = red16(p0);
            p1 = red16(p1);
            if (ln == 0) {
                const int flat = tile * 16 + lg*4 + rg;
                const int lb = flat / T_STEPS;
                const int t = flat - lb * T_STEPS;
                const int b = base + lb;
                float v0 = p0 + b2_0;
                float v1 = p1 + b2_1;
                if (hd) {
                    v0 = (v0 > 0.f ? v0 : expm1f(v0)) + 1.0f + MIN_SCALE;
                    v1 = (v1 > 0.f ? v1 : expm1f(v1)) + 1.0f + MIN_SCALE;
                }
                *(float2*)(traj + ((size_t)b * T_STEPS + t) * 4 + hd*2) = make_float2(v0, v1);
            }
        }
    }
}

// ===========================================================================
// Kernel C: pi head — weight-stationary persistent (768 blocks), DPP reduce.
// ===========================================================================
__global__ __launch_bounds__(256, 2) void pi_persist_kernel(
    const float* __restrict__ local_embed, const float* __restrict__ global_embed,
    const float* __restrict__ pi1_w, const float* __restrict__ pi1_b,
    const float* __restrict__ ln1_g, const float* __restrict__ ln1_b,
    const float* __restrict__ pi2_w, const float* __restrict__ pi2_b,
    const float* __restrict__ ln2_g, const float* __restrict__ ln2_b,
    const float* __restrict__ pi3_w, const float* __restrict__ pi3_b,
    float* __restrict__ pi_out)
{
    __shared__ short inbf[32][264];
    __shared__ short h1bf[32][136];
    __shared__ float redL[4][32][2];
    __shared__ float red3[4][32];

    const int tid = threadIdx.x;
    const int w  = tid >> 6;
    const int l  = tid & 63;
    const int ln = l & 15;
    const int lg = l >> 4;

    bf16x8 wf1[2][8];
    bf16x8 wf2[2][4];
    float b1[2], g1[2], bb1[2], b2[2], g2[2], bb2[2], w3[2];
    #pragma unroll
    for (int nt = 0; nt < 2; ++nt) {
        const int c = 32*w + 16*nt + ln;
        #pragma unroll
        for (int kt = 0; kt < 8; ++kt)
            wf1[nt][kt] = load8_cvt(pi1_w + (size_t)c * (2*H) + kt*32 + lg*8);
        #pragma unroll
        for (int kt = 0; kt < 4; ++kt)
            wf2[nt][kt] = load8_cvt(pi2_w + (size_t)c * H + kt*32 + lg*8);
        b1[nt] = pi1_b[c]; g1[nt] = ln1_g[c]; bb1[nt] = ln1_b[c];
        b2[nt] = pi2_b[c]; g2[nt] = ln2_g[c]; bb2[nt] = ln2_b[c];
        w3[nt] = pi3_w[c];
    }
    const float b3 = pi3_b[0];

    const int ntiles = B_TOT / 32;

    for (int it = blockIdx.x; it < ntiles; it += gridDim.x) {
        const int r0 = it * 32;
        {
            const int r   = tid >> 3;
            const int seg = tid & 7;
            const int b = r0 + r;
            const int n = b & (N_AG - 1);
            const float* src = (seg < 4) ? (local_embed + (size_t)n * H + seg * 32)
                                         : (global_embed + (size_t)b * I_DIM + (seg - 4) * 32);
            short tmp[32];
            #pragma unroll
            for (int i = 0; i < 8; ++i) {
                const float4 v = ((const float4*)src)[i];
                tmp[i*4+0]=f2b(v.x); tmp[i*4+1]=f2b(v.y); tmp[i*4+2]=f2b(v.z); tmp[i*4+3]=f2b(v.w);
            }
            #pragma unroll
            for (int i = 0; i < 4; ++i)
                *(uint4*)&inbf[r][seg*32 + i*8] = *(uint4*)&tmp[i*8];
        }
        __syncthreads();

        f32x4 acc1[2][2];
        #pragma unroll
        for (int m = 0; m < 2; ++m) {
            #pragma unroll
            for (int nt = 0; nt < 2; ++nt) acc1[m][nt] = (f32x4)(0.f);
            bf16x8 af[8];
            #pragma unroll
            for (int kt = 0; kt < 8; ++kt)
                af[kt] = *(const bf16x8*)&inbf[m*16 + ln][kt*32 + lg*8];
            #pragma unroll
            for (int kt = 0; kt < 8; ++kt)
                #pragma unroll
                for (int nt = 0; nt < 2; ++nt)
                    acc1[m][nt] = MFMA16x16x32(af[kt], wf1[nt][kt], acc1[m][nt]);
        }

        #pragma unroll
        for (int m = 0; m < 2; ++m)
            #pragma unroll
            for (int rg = 0; rg < 4; ++rg) {
                float s = 0.f, q = 0.f;
                #pragma unroll
                for (int nt = 0; nt < 2; ++nt) {
                    const float a = acc1[m][nt][rg] + b1[nt];
                    acc1[m][nt][rg] = a;
                    s += a; q += a*a;
                }
                s = red16(s);
                q = red16(q);
                if (ln == 0) {
                    const int row = m*16 + lg*4 + rg;
                    redL[w][row][0] = s;
                    redL[w][row][1] = q;
                }
            }
        __syncthreads();

        #pragma unroll
        for (int m = 0; m < 2; ++m)
            #pragma unroll
            for (int rg = 0; rg < 4; ++rg) {
                const int row = m*16 + lg*4 + rg;
                const float S = redL[0][row][0] + redL[1][row][0] + redL[2][row][0] + redL[3][row][0];
                const float Q = redL[0][row][1] + redL[1][row][1] + redL[2][row][1] + redL[3][row][1];
                const float mu = S * (1.f/H);
                const float var = Q * (1.f/H) - mu*mu;
                const float rs = rsqrtf(var + LN_EPS);
                #pragma unroll
                for (int nt = 0; nt < 2; ++nt) {
                    const float v = fmaxf((acc1[m][nt][rg] - mu) * rs * g1[nt] + bb1[nt], 0.f);
                    h1bf[row][32*w + 16*nt + ln] = f2b(v);
                }
            }
        __syncthreads();

        f32x4 acc2[2][2];
        #pragma unroll
        for (int m = 0; m < 2; ++m) {
            #pragma unroll
            for (int nt = 0; nt < 2; ++nt) acc2[m][nt] = (f32x4)(0.f);
            bf16x8 af[4];
            #pragma unroll
            for (int kt = 0; kt < 4; ++kt)
                af[kt] = *(const bf16x8*)&h1bf[m*16 + ln][kt*32 + lg*8];
            #pragma unroll
            for (int kt = 0; kt < 4; ++kt)
                #pragma unroll
                for (int nt = 0; nt < 2; ++nt)
                    acc2[m][nt] = MFMA16x16x32(af[kt], wf2[nt][kt], acc2[m][nt]);
        }

        #pragma unroll
        for (int m = 0; m < 2; ++m)
            #pragma unroll
            for (int rg = 0; rg < 4; ++rg) {
                float s = 0.f, q = 0.f;
                #pragma unroll
                for (int nt = 0; nt < 2; ++nt) {
                    const float a = acc2[m][nt][rg] + b2[nt];
                    acc2[m][nt][rg] = a;
                    s += a; q += a*a;
                }
                s = red16(s);
                q = red16(q);
                if (ln == 0) {
                    const int row = m*16 + lg*4 + rg;
                    redL[w][row][0] = s;
                    redL[w][row][1] = q;
                }
            }
        __syncthreads();

        #pragma unroll
        for (int m = 0; m < 2; ++m)
            #pragma unroll
            for (int rg = 0; rg < 4; ++rg) {
                const int row = m*16 + lg*4 + rg;
                const float S = redL[0][row][0] + redL[1][row][0] + redL[2][row][0] + redL[3][row][0];
                const float Q = redL[0][row][1] + redL[1][row][1] + redL[2][row][1] + redL[3][row][1];
                const float mu = S * (1.f/H);
                const float var = Q * (1.f/H) - mu*mu;
                const float rs = rsqrtf(var + LN_EPS);
                float p = 0.f;
                #pragma unroll
                for (int nt = 0; nt < 2; ++nt) {
                    const float v = fmaxf((acc2[m][nt][rg] - mu) * rs * g2[nt] + bb2[nt], 0.f);
                    p = fmaf(v, w3[nt], p);
                }
                p = red16(p);
                if (ln == 0) red3[w][row] = p;
            }
        __syncthreads();

        if (tid < 32) {
            const int row = tid;
            const float p = red3[0][row] + red3[1][row] + red3[2][row] + red3[3][row] + b3;
            const int b = r0 + row;
            const int n = b & (N_AG - 1);
            const int m = b >> 13;
            pi_out[(size_t)n * M_MODES + m] = p;
        }
        __syncthreads();
    }
}

extern "C" void kernel_launch(void* const* d_in, const int* in_sizes, int n_in,
                              void* d_out, int out_size, void* d_ws, size_t ws_size,
                              hipStream_t stream) {
    (void)in_sizes; (void)n_in; (void)out_size;
    const float* local_embed  = (const float*)d_in[0];
    const float* global_embed = (const float*)d_in[1];
    const float* W_ih   = (const float*)d_in[2];
    const float* W_hh   = (const float*)d_in[3];
    const float* b_ih   = (const float*)d_in[4];
    const float* b_hh   = (const float*)d_in[5];
    const float* loc1_w = (const float*)d_in[6];
    const float* loc1_b = (const float*)d_in[7];
    const float* loc_ln_g = (const float*)d_in[8];
    const float* loc_ln_b = (const float*)d_in[9];
    const float* loc2_w = (const float*)d_in[10];
    const float* loc2_b = (const float*)d_in[11];
    const float* sc1_w  = (const float*)d_in[12];
    const float* sc1_b  = (const float*)d_in[13];
    const float* sc_ln_g = (const float*)d_in[14];
    const float* sc_ln_b = (const float*)d_in[15];
    const float* sc2_w  = (const float*)d_in[16];
    const float* sc2_b  = (const float*)d_in[17];
    const float* pi1_w  = (const float*)d_in[18];
    const float* pi1_b  = (const float*)d_in[19];
    const float* pi_ln1_g = (const float*)d_in[20];
    const float* pi_ln1_b = (const float*)d_in[21];
    const float* pi2_w  = (const float*)d_in[22];
    const float* pi2_b  = (const float*)d_in[23];
    const float* pi_ln2_g = (const float*)d_in[24];
    const float* pi_ln2_b = (const float*)d_in[25];
    const float* pi3_w  = (const float*)d_in[26];
    const float* pi3_b  = (const float*)d_in[27];

    float* traj = (float*)d_out;
    float* pi_out = traj + (size_t)B_TOT * T_STEPS * 4;

    pi_persist_kernel<<<768, 256, 0, stream>>>(
        local_embed, global_embed, pi1_w, pi1_b, pi_ln1_g, pi_ln1_b,
        pi2_w, pi2_b, pi_ln2_g, pi_ln2_b, pi3_w, pi3_b, pi_out);

    // workspace per chunk of Rc rows: gx (transposed [384][Rc] f32) + hist
    const size_t row_bytes = 384 * sizeof(float) + (size_t)T_STEPS * H * sizeof(unsigned short);
    long long rc = (long long)(ws_size / row_bytes);
    int Rc = rc > B_TOT ? B_TOT : (int)rc;
    Rc &= ~31;

    if (Rc >= 32) {
        float* gx_ws = (float*)d_ws;
        unsigned short* hist = (unsigned short*)(gx_ws + (size_t)Rc * 384);

        for (int basep = 0; basep < B_TOT; basep += Rc) {
            const int rows = (B_TOT - basep < Rc) ? (B_TOT - basep) : Rc;

            const int gxtiles = rows / 16;
            gx_kernel<<<(gxtiles < 512 ? gxtiles : 512), 256, 0, stream>>>(
                global_embed, W_ih, b_ih, b_hh, basep, gxtiles, Rc, gx_ws);

            const int rtiles = rows / 32;
            gru_rec_kernel<<<(rtiles < 512 ? rtiles : 512), 256, 0, stream>>>(
                local_embed, gx_ws, W_hh, b_hh, basep, rtiles, Rc, hist);

            const int htiles16 = (rows * T_STEPS) / 16;
            const int hblk = (htiles16 + 1) / 2 < 2048 ? (htiles16 + 1) / 2 : 2048;
            heads_kernel<<<hblk, 256, 0, stream>>>(
                hist, basep, htiles16,
                loc1_w, loc1_b, loc_ln_g, loc_ln_b, loc2_w, loc2_b,
                sc1_w, sc1_b, sc_ln_g, sc_ln_b, sc2_w, sc2_b, traj);
        }
    }
}

// Round 10
// 641.486 us; speedup vs baseline: 2.4803x; 1.1245x over previous
//
#include <hip/hip_runtime.h>
#include <math.h>

#define H 128
#define I_DIM 128
#define T_STEPS 30
#define M_MODES 6
#define N_AG 8192
#define B_TOT (M_MODES * N_AG)   /* 49152 */
#define LN_EPS 1e-5f
#define MIN_SCALE 0.001f

typedef short bf16x8 __attribute__((ext_vector_type(8)));
typedef float f32x4 __attribute__((ext_vector_type(4)));

#define MFMA16x16x32(A, B, C) __builtin_amdgcn_mfma_f32_16x16x32_bf16(A, B, C, 0, 0, 0)

__device__ __forceinline__ short f2b(float f) {
    union { float f; unsigned u; } v; v.f = f;
    return (short)((v.u + 0x7FFFu + ((v.u >> 16) & 1u)) >> 16);
}

__device__ __forceinline__ bf16x8 load8_cvt(const float* __restrict__ p) {
    const float4 a = ((const float4*)p)[0];
    const float4 b = ((const float4*)p)[1];
    bf16x8 r;
    r[0]=f2b(a.x); r[1]=f2b(a.y); r[2]=f2b(a.z); r[3]=f2b(a.w);
    r[4]=f2b(b.x); r[5]=f2b(b.y); r[6]=f2b(b.z); r[7]=f2b(b.w);
    return r;
}

__device__ __forceinline__ float fast_sigm(float x) {
    return __builtin_amdgcn_rcpf(1.f + __expf(-x));
}
__device__ __forceinline__ float fast_tanh(float x) {
    return 1.f - 2.f * __builtin_amdgcn_rcpf(1.f + __expf(2.f * x));
}

// 16-lane all-reduce sum via DPP (VALU pipe)
#define DPP_ADD(v, ctrl)                                                     \
    v += __builtin_bit_cast(float, __builtin_amdgcn_mov_dpp(                 \
             __builtin_bit_cast(int, v), ctrl, 0xF, 0xF, true))

__device__ __forceinline__ float red16(float v) {
    DPP_ADD(v, 0xB1);    // quad_perm xor1
    DPP_ADD(v, 0x4E);    // quad_perm xor2
    DPP_ADD(v, 0x124);   // row_ror:4
    DPP_ADD(v, 0x128);   // row_ror:8
    return v;
}

// ===========================================================================
// Kernel 0: gx = x @ W_ih^T + b_ih (+ b_hh folded for r,z).  TRANSPOSED out.
// ===========================================================================
__global__ __launch_bounds__(256, 2) void gx_kernel(
    const float* __restrict__ global_embed,
    const float* __restrict__ W_ih, const float* __restrict__ b_ih,
    const float* __restrict__ b_hh,
    int base, int ntiles, int Rc, float* __restrict__ gx_ws)
{
    __shared__ short xbuf[16][136];

    const int tid = threadIdx.x;
    const int w  = tid >> 6;
    const int l  = tid & 63;
    const int ln = l & 15;
    const int lg = l >> 4;

    bf16x8 wf[6][4];
    float bias[6];
    #pragma unroll
    for (int nt = 0; nt < 6; ++nt) {
        const int ch = 96*w + 16*nt + ln;
        #pragma unroll
        for (int kt = 0; kt < 4; ++kt)
            wf[nt][kt] = load8_cvt(W_ih + (size_t)ch * I_DIM + kt*32 + lg*8);
        bias[nt] = b_ih[ch] + (ch < 2*H ? b_hh[ch] : 0.f);
    }

    const int s_r = tid >> 4, s_sg = tid & 15;

    for (int it = blockIdx.x; it < ntiles; it += gridDim.x) {
        const int r0 = it * 16;
        __syncthreads();
        {
            const float* src = global_embed + (size_t)(base + r0 + s_r) * I_DIM + s_sg*8;
            const float4 a = ((const float4*)src)[0];
            const float4 c = ((const float4*)src)[1];
            short tmp[8];
            tmp[0]=f2b(a.x); tmp[1]=f2b(a.y); tmp[2]=f2b(a.z); tmp[3]=f2b(a.w);
            tmp[4]=f2b(c.x); tmp[5]=f2b(c.y); tmp[6]=f2b(c.z); tmp[7]=f2b(c.w);
            *(uint4*)&xbuf[s_r][s_sg*8] = *(uint4*)tmp;
        }
        __syncthreads();

        bf16x8 af[4];
        #pragma unroll
        for (int kt = 0; kt < 4; ++kt)
            af[kt] = *(const bf16x8*)&xbuf[ln][kt*32 + lg*8];

        f32x4 acc[6];
        #pragma unroll
        for (int nt = 0; nt < 6; ++nt) acc[nt] = (f32x4)(0.f);
        #pragma unroll
        for (int kt = 0; kt < 4; ++kt)
            #pragma unroll
            for (int nt = 0; nt < 6; ++nt)
                acc[nt] = MFMA16x16x32(af[kt], wf[nt][kt], acc[nt]);

        #pragma unroll
        for (int nt = 0; nt < 6; ++nt) {
            const f32x4 v = acc[nt] + (f32x4)(bias[nt]);
            *(f32x4*)(gx_ws + (size_t)(96*w + 16*nt + ln) * Rc + r0 + lg*4) = v;
        }
    }
}

// ===========================================================================
// Kernel A: GRU recurrence — 32 rows/block, weight-stationary, 1 barrier/step.
// ===========================================================================
__global__ __launch_bounds__(256, 2) void gru_rec_kernel(
    const float* __restrict__ local_embed, const float* __restrict__ gx_ws,
    const float* __restrict__ W_hh, const float* __restrict__ b_hh,
    int base, int ntiles, int Rc, unsigned short* __restrict__ hist)
{
    __shared__ short hb0[32][136];
    __shared__ short hb1[32][136];

    const int tid = threadIdx.x;
    const int w  = tid >> 6;
    const int l  = tid & 63;
    const int ln = l & 15;
    const int lg = l >> 4;

    bf16x8 wf[3][2][4];
    float bhn[2];
    #pragma unroll
    for (int u = 0; u < 2; ++u) {
        const int c = 32*w + 16*u + ln;
        bhn[u] = b_hh[2*H + c];
        #pragma unroll
        for (int g = 0; g < 3; ++g) {
            const int crow = g*H + c;
            #pragma unroll
            for (int kt = 0; kt < 4; ++kt)
                wf[g][u][kt] = load8_cvt(W_hh + (size_t)crow * H + kt*32 + lg*8);
        }
    }

    const int sr  = tid >> 4;
    const int seg = tid & 15;

    for (int it = blockIdx.x; it < ntiles; it += gridDim.x) {
        const int lb0 = it * 32;
        __syncthreads();

        #pragma unroll
        for (int rr2 = 0; rr2 < 2; ++rr2) {
            const int r = sr + rr2*16;
            const int b = base + lb0 + r;
            const int n = b & (N_AG - 1);
            const float* src = local_embed + (size_t)n * H + seg*8;
            const float4 a = ((const float4*)src)[0];
            const float4 c = ((const float4*)src)[1];
            short tmp[8];
            tmp[0]=f2b(a.x); tmp[1]=f2b(a.y); tmp[2]=f2b(a.z); tmp[3]=f2b(a.w);
            tmp[4]=f2b(c.x); tmp[5]=f2b(c.y); tmp[6]=f2b(c.z); tmp[7]=f2b(c.w);
            *(uint4*)&hb0[r][seg*8] = *(uint4*)tmp;
        }

        float h_reg[2][2][4];
        #pragma unroll
        for (int grp = 0; grp < 2; ++grp)
            #pragma unroll
            for (int u = 0; u < 2; ++u) {
                const int j = 32*w + 16*u + ln;
                #pragma unroll
                for (int rg = 0; rg < 4; ++rg) {
                    const int b = base + lb0 + grp*16 + lg*4 + rg;
                    const int n = b & (N_AG - 1);
                    h_reg[grp][u][rg] = local_embed[(size_t)n * H + j];
                }
            }

        float gx[2][3][2][4];
        #pragma unroll
        for (int grp = 0; grp < 2; ++grp)
            #pragma unroll
            for (int g = 0; g < 3; ++g)
                #pragma unroll
                for (int u = 0; u < 2; ++u) {
                    const int ch = g*128 + 32*w + 16*u + ln;
                    const f32x4 v = *(const f32x4*)(gx_ws + (size_t)ch * Rc + lb0 + grp*16 + lg*4);
                    #pragma unroll
                    for (int rg = 0; rg < 4; ++rg) gx[grp][g][u][rg] = v[rg];
                }
        __syncthreads();

        int cur = 0;
        for (int t = 0; t < T_STEPS; ++t) {
            const short* hcur = cur ? &hb1[0][0] : &hb0[0][0];
            short*       hnxt = cur ? &hb0[0][0] : &hb1[0][0];

            #pragma unroll
            for (int grp = 0; grp < 2; ++grp) {
                bf16x8 af[4];
                #pragma unroll
                for (int kt = 0; kt < 4; ++kt)
                    af[kt] = *(const bf16x8*)&hcur[(grp*16 + ln)*136 + kt*32 + lg*8];

                f32x4 ga[3][2];
                #pragma unroll
                for (int g = 0; g < 3; ++g)
                    #pragma unroll
                    for (int u = 0; u < 2; ++u) ga[g][u] = (f32x4)(0.f);
                #pragma unroll
                for (int kt = 0; kt < 4; ++kt)
                    #pragma unroll
                    for (int g = 0; g < 3; ++g)
                        #pragma unroll
                        for (int u = 0; u < 2; ++u)
                            ga[g][u] = MFMA16x16x32(af[kt], wf[g][u][kt], ga[g][u]);

                #pragma unroll
                for (int u = 0; u < 2; ++u) {
                    const int j = 32*w + 16*u + ln;
                    #pragma unroll
                    for (int rg = 0; rg < 4; ++rg) {
                        const float rr = fast_sigm(gx[grp][0][u][rg] + ga[0][u][rg]);
                        const float zz = fast_sigm(gx[grp][1][u][rg] + ga[1][u][rg]);
                        const float nn = fast_tanh(gx[grp][2][u][rg] + rr * (ga[2][u][rg] + bhn[u]));
                        const float h  = (1.f - zz) * nn + zz * h_reg[grp][u][rg];
                        h_reg[grp][u][rg] = h;
                        hnxt[(grp*16 + lg*4 + rg)*136 + j] = f2b(h);
                    }
                }
            }
            __syncthreads();

            #pragma unroll
            for (int rr2 = 0; rr2 < 2; ++rr2) {
                const int r = sr + rr2*16;
                const uint4 hv = *(const uint4*)&hnxt[r*136 + seg*8];
                *(uint4*)(hist + (size_t)(lb0 + r) * (T_STEPS * H) + t * H + seg*8) = hv;
            }
            cur ^= 1;
        }
    }
}

// ===========================================================================
// Kernel B: fused heads + pi in ONE dispatch (block-range split) so the two
// latency-bound phases overlap instead of serializing on the stream.
//   blocks [0, hblk)          : loc/scale heads (barrier-free, wave-autonomous)
//   blocks [hblk, gridDim.x)  : pi head (weight-stationary persistent)
// ===========================================================================
__global__ __launch_bounds__(256, 2) void heads_pi_kernel(
    const unsigned short* __restrict__ hist, int base, int ntiles16, int hblk,
    const float* __restrict__ loc1_w, const float* __restrict__ loc1_b,
    const float* __restrict__ loc_ln_g, const float* __restrict__ loc_ln_b,
    const float* __restrict__ loc2_w, const float* __restrict__ loc2_b,
    const float* __restrict__ sc1_w, const float* __restrict__ sc1_b,
    const float* __restrict__ sc_ln_g, const float* __restrict__ sc_ln_b,
    const float* __restrict__ sc2_w, const float* __restrict__ sc2_b,
    float* __restrict__ traj,
    const float* __restrict__ local_embed, const float* __restrict__ global_embed,
    const float* __restrict__ pi1_w, const float* __restrict__ pi1_b,
    const float* __restrict__ ln1_g, const float* __restrict__ ln1_b,
    const float* __restrict__ pi2_w, const float* __restrict__ pi2_b,
    const float* __restrict__ ln2_g, const float* __restrict__ ln2_b,
    const float* __restrict__ pi3_w, const float* __restrict__ pi3_b,
    float* __restrict__ pi_out)
{
    __shared__ short inbf[32][264];       // pi-path only
    __shared__ short h1bf[32][136];
    __shared__ float redL[4][32][2];
    __shared__ float red3[4][32];

    const int tid = threadIdx.x;
    const int w  = tid >> 6;
    const int l  = tid & 63;
    const int ln = l & 15;
    const int lg = l >> 4;

    if ((int)blockIdx.x < hblk) {
        // ================= heads path =================
        const int gw = blockIdx.x * 4 + w;
        const int hd = gw & 1;
        const int wstride = hblk * 2;

        const float* __restrict__ W1  = hd ? sc1_w   : loc1_w;
        const float* __restrict__ B1v = hd ? sc1_b   : loc1_b;
        const float* __restrict__ Gv  = hd ? sc_ln_g : loc_ln_g;
        const float* __restrict__ Bv  = hd ? sc_ln_b : loc_ln_b;
        const float* __restrict__ W2  = hd ? sc2_w   : loc2_w;
        const float* __restrict__ B2v = hd ? sc2_b   : loc2_b;

        bf16x8 wf[8][4];
        float bias1[8], lng[8], lnb[8], w2a[8], w2b[8];
        #pragma unroll
        for (int nt = 0; nt < 8; ++nt) {
            const int c = 16*nt + ln;
            #pragma unroll
            for (int kt = 0; kt < 4; ++kt)
                wf[nt][kt] = load8_cvt(W1 + (size_t)c * H + kt*32 + lg*8);
            bias1[nt] = B1v[c]; lng[nt] = Gv[c]; lnb[nt] = Bv[c];
            w2a[nt] = W2[c];    w2b[nt] = W2[H + c];
        }
        const float b2_0 = B2v[0], b2_1 = B2v[1];

        int tile = gw >> 1;
        if (tile < ntiles16) {
            // prologue fetch
            bf16x8 af[4];
            {
                const unsigned short* rowp = hist + (size_t)(tile * 16 + ln) * H;
                #pragma unroll
                for (int kt = 0; kt < 4; ++kt)
                    af[kt] = *(const bf16x8*)(rowp + kt*32 + lg*8);
            }
            for (; tile < ntiles16; ) {
                f32x4 acc[8];
                #pragma unroll
                for (int nt = 0; nt < 8; ++nt) acc[nt] = (f32x4)(0.f);
                #pragma unroll
                for (int kt = 0; kt < 4; ++kt)
                    #pragma unroll
                    for (int nt = 0; nt < 8; ++nt)
                        acc[nt] = MFMA16x16x32(af[kt], wf[nt][kt], acc[nt]);

                // prefetch next tile's fragments; latency hides under epilogue
                const int nxt = tile + wstride;
                {
                    const int pf = nxt < ntiles16 ? nxt : tile;
                    const unsigned short* rowp = hist + (size_t)(pf * 16 + ln) * H;
                    #pragma unroll
                    for (int kt = 0; kt < 4; ++kt)
                        af[kt] = *(const bf16x8*)(rowp + kt*32 + lg*8);
                }

                #pragma unroll
                for (int rg = 0; rg < 4; ++rg) {
                    float s = 0.f, q = 0.f;
                    #pragma unroll
                    for (int nt = 0; nt < 8; ++nt) {
                        const float a = acc[nt][rg] + bias1[nt];
                        acc[nt][rg] = a;
                        s += a; q += a*a;
                    }
                    s = red16(s);
                    q = red16(q);
                    const float mu = s * (1.f/H);
                    const float var = q * (1.f/H) - mu*mu;
                    const float rs = rsqrtf(var + LN_EPS);
                    const float murs = mu * rs;
                    float p0 = 0.f, p1 = 0.f;
                    #pragma unroll
                    for (int nt = 0; nt < 8; ++nt) {
                        float v = fmaf(fmaf(acc[nt][rg], rs, -murs), lng[nt], lnb[nt]);
                        v = fmaxf(v, 0.f);
                        p0 = fmaf(v, w2a[nt], p0);
                        p1 = fmaf(v, w2b[nt], p1);
                    }
                    p0 = red16(p0);
                    p1 = red16(p1);
                    if (ln == 0) {
                        const int flat = tile * 16 + lg*4 + rg;
                        const int lb = flat / T_STEPS;
                        const int t = flat - lb * T_STEPS;
                        const int b = base + lb;
                        float v0 = p0 + b2_0;
                        float v1 = p1 + b2_1;
                        if (hd) {
                            v0 = (v0 > 0.f ? v0 : expm1f(v0)) + 1.0f + MIN_SCALE;
                            v1 = (v1 > 0.f ? v1 : expm1f(v1)) + 1.0f + MIN_SCALE;
                        }
                        *(float2*)(traj + ((size_t)b * T_STEPS + t) * 4 + hd*2) = make_float2(v0, v1);
                    }
                }
                tile = nxt;
            }
        }
        return;
    }

    // ================= pi path =================
    {
        const int pbid = blockIdx.x - hblk;
        const int pgrid = gridDim.x - hblk;

        bf16x8 wf1[2][8];
        bf16x8 wf2[2][4];
        float b1[2], g1[2], bb1[2], b2[2], g2[2], bb2[2], w3[2];
        #pragma unroll
        for (int nt = 0; nt < 2; ++nt) {
            const int c = 32*w + 16*nt + ln;
            #pragma unroll
            for (int kt = 0; kt < 8; ++kt)
                wf1[nt][kt] = load8_cvt(pi1_w + (size_t)c * (2*H) + kt*32 + lg*8);
            #pragma unroll
            for (int kt = 0; kt < 4; ++kt)
                wf2[nt][kt] = load8_cvt(pi2_w + (size_t)c * H + kt*32 + lg*8);
            b1[nt] = pi1_b[c]; g1[nt] = ln1_g[c]; bb1[nt] = ln1_b[c];
            b2[nt] = pi2_b[c]; g2[nt] = ln2_g[c]; bb2[nt] = ln2_b[c];
            w3[nt] = pi3_w[c];
        }
        const float b3 = pi3_b[0];

        const int ntiles = B_TOT / 32;

        for (int it = pbid; it < ntiles; it += pgrid) {
            const int r0 = it * 32;
            {
                const int r   = tid >> 3;
                const int seg = tid & 7;
                const int b = r0 + r;
                const int n = b & (N_AG - 1);
                const float* src = (seg < 4) ? (local_embed + (size_t)n * H + seg * 32)
                                             : (global_embed + (size_t)b * I_DIM + (seg - 4) * 32);
                short tmp[32];
                #pragma unroll
                for (int i = 0; i < 8; ++i) {
                    const float4 v = ((const float4*)src)[i];
                    tmp[i*4+0]=f2b(v.x); tmp[i*4+1]=f2b(v.y); tmp[i*4+2]=f2b(v.z); tmp[i*4+3]=f2b(v.w);
                }
                #pragma unroll
                for (int i = 0; i < 4; ++i)
                    *(uint4*)&inbf[r][seg*32 + i*8] = *(uint4*)&tmp[i*8];
            }
            __syncthreads();

            f32x4 acc1[2][2];
            #pragma unroll
            for (int m = 0; m < 2; ++m) {
                #pragma unroll
                for (int nt = 0; nt < 2; ++nt) acc1[m][nt] = (f32x4)(0.f);
                bf16x8 af[8];
                #pragma unroll
                for (int kt = 0; kt < 8; ++kt)
                    af[kt] = *(const bf16x8*)&inbf[m*16 + ln][kt*32 + lg*8];
                #pragma unroll
                for (int kt = 0; kt < 8; ++kt)
                    #pragma unroll
                    for (int nt = 0; nt < 2; ++nt)
                        acc1[m][nt] = MFMA16x16x32(af[kt], wf1[nt][kt], acc1[m][nt]);
            }

            #pragma unroll
            for (int m = 0; m < 2; ++m)
                #pragma unroll
                for (int rg = 0; rg < 4; ++rg) {
                    float s = 0.f, q = 0.f;
                    #pragma unroll
                    for (int nt = 0; nt < 2; ++nt) {
                        const float a = acc1[m][nt][rg] + b1[nt];
                        acc1[m][nt][rg] = a;
                        s += a; q += a*a;
                    }
                    s = red16(s);
                    q = red16(q);
                    if (ln == 0) {
                        const int row = m*16 + lg*4 + rg;
                        redL[w][row][0] = s;
                        redL[w][row][1] = q;
                    }
                }
            __syncthreads();

            #pragma unroll
            for (int m = 0; m < 2; ++m)
                #pragma unroll
                for (int rg = 0; rg < 4; ++rg) {
                    const int row = m*16 + lg*4 + rg;
                    const float S = redL[0][row][0] + redL[1][row][0] + redL[2][row][0] + redL[3][row][0];
                    const float Q = redL[0][row][1] + redL[1][row][1] + redL[2][row][1] + redL[3][row][1];
                    const float mu = S * (1.f/H);
                    const float var = Q * (1.f/H) - mu*mu;
                    const float rs = rsqrtf(var + LN_EPS);
                    #pragma unroll
                    for (int nt = 0; nt < 2; ++nt) {
                        const float v = fmaxf((acc1[m][nt][rg] - mu) * rs * g1[nt] + bb1[nt], 0.f);
                        h1bf[row][32*w + 16*nt + ln] = f2b(v);
                    }
                }
            __syncthreads();

            f32x4 acc2[2][2];
            #pragma unroll
            for (int m = 0; m < 2; ++m) {
                #pragma unroll
                for (int nt = 0; nt < 2; ++nt) acc2[m][nt] = (f32x4)(0.f);
                bf16x8 af[4];
                #pragma unroll
                for (int kt = 0; kt < 4; ++kt)
                    af[kt] = *(const bf16x8*)&h1bf[m*16 + ln][kt*32 + lg*8];
                #pragma unroll
                for (int kt = 0; kt < 4; ++kt)
                    #pragma unroll
                    for (int nt = 0; nt < 2; ++nt)
                        acc2[m][nt] = MFMA16x16x32(af[kt], wf2[nt][kt], acc2[m][nt]);
            }

            #pragma unroll
            for (int m = 0; m < 2; ++m)
                #pragma unroll
                for (int rg = 0; rg < 4; ++rg) {
                    float s = 0.f, q = 0.f;
                    #pragma unroll
                    for (int nt = 0; nt < 2; ++nt) {
                        const float a = acc2[m][nt][rg] + b2[nt];
                        acc2[m][nt][rg] = a;
                        s += a; q += a*a;
                    }
                    s = red16(s);
                    q = red16(q);
                    if (ln == 0) {
                        const int row = m*16 + lg*4 + rg;
                        redL[w][row][0] = s;
                        redL[w][row][1] = q;
                    }
                }
            __syncthreads();

            #pragma unroll
            for (int m = 0; m < 2; ++m)
                #pragma unroll
                for (int rg = 0; rg < 4; ++rg) {
                    const int row = m*16 + lg*4 + rg;
                    const float S = redL[0][row][0] + redL[1][row][0] + redL[2][row][0] + redL[3][row][0];
                    const float Q = redL[0][row][1] + redL[1][row][1] + redL[2][row][1] + redL[3][row][1];
                    const float mu = S * (1.f/H);
                    const float var = Q * (1.f/H) - mu*mu;
                    const float rs = rsqrtf(var + LN_EPS);
                    float p = 0.f;
                    #pragma unroll
                    for (int nt = 0; nt < 2; ++nt) {
                        const float v = fmaxf((acc2[m][nt][rg] - mu) * rs * g2[nt] + bb2[nt], 0.f);
                        p = fmaf(v, w3[nt], p);
                    }
                    p = red16(p);
                    if (ln == 0) red3[w][row] = p;
                }
            __syncthreads();

            if (tid < 32) {
                const int row = tid;
                const float p = red3[0][row] + red3[1][row] + red3[2][row] + red3[3][row] + b3;
                const int b = r0 + row;
                const int n = b & (N_AG - 1);
                const int m = b >> 13;
                pi_out[(size_t)n * M_MODES + m] = p;
            }
            __syncthreads();
        }
    }
}

extern "C" void kernel_launch(void* const* d_in, const int* in_sizes, int n_in,
                              void* d_out, int out_size, void* d_ws, size_t ws_size,
                              hipStream_t stream) {
    (void)in_sizes; (void)n_in; (void)out_size;
    const float* local_embed  = (const float*)d_in[0];
    const float* global_embed = (const float*)d_in[1];
    const float* W_ih   = (const float*)d_in[2];
    const float* W_hh   = (const float*)d_in[3];
    const float* b_ih   = (const float*)d_in[4];
    const float* b_hh   = (const float*)d_in[5];
    const float* loc1_w = (const float*)d_in[6];
    const float* loc1_b = (const float*)d_in[7];
    const float* loc_ln_g = (const float*)d_in[8];
    const float* loc_ln_b = (const float*)d_in[9];
    const float* loc2_w = (const float*)d_in[10];
    const float* loc2_b = (const float*)d_in[11];
    const float* sc1_w  = (const float*)d_in[12];
    const float* sc1_b  = (const float*)d_in[13];
    const float* sc_ln_g = (const float*)d_in[14];
    const float* sc_ln_b = (const float*)d_in[15];
    const float* sc2_w  = (const float*)d_in[16];
    const float* sc2_b  = (const float*)d_in[17];
    const float* pi1_w  = (const float*)d_in[18];
    const float* pi1_b  = (const float*)d_in[19];
    const float* pi_ln1_g = (const float*)d_in[20];
    const float* pi_ln1_b = (const float*)d_in[21];
    const float* pi2_w  = (const float*)d_in[22];
    const float* pi2_b  = (const float*)d_in[23];
    const float* pi_ln2_g = (const float*)d_in[24];
    const float* pi_ln2_b = (const float*)d_in[25];
    const float* pi3_w  = (const float*)d_in[26];
    const float* pi3_b  = (const float*)d_in[27];

    float* traj = (float*)d_out;
    float* pi_out = traj + (size_t)B_TOT * T_STEPS * 4;

    // workspace per chunk of Rc rows: gx (transposed [384][Rc] f32) + hist
    const size_t row_bytes = 384 * sizeof(float) + (size_t)T_STEPS * H * sizeof(unsigned short);
    long long rc = (long long)(ws_size / row_bytes);
    int Rc = rc > B_TOT ? B_TOT : (int)rc;
    Rc &= ~31;

    if (Rc >= 32) {
        float* gx_ws = (float*)d_ws;
        unsigned short* hist = (unsigned short*)(gx_ws + (size_t)Rc * 384);
        bool first = true;

        for (int basep = 0; basep < B_TOT; basep += Rc) {
            const int rows = (B_TOT - basep < Rc) ? (B_TOT - basep) : Rc;

            const int gxtiles = rows / 16;
            gx_kernel<<<(gxtiles < 512 ? gxtiles : 512), 256, 0, stream>>>(
                global_embed, W_ih, b_ih, b_hh, basep, gxtiles, Rc, gx_ws);

            const int rtiles = rows / 32;
            gru_rec_kernel<<<(rtiles < 512 ? rtiles : 512), 256, 0, stream>>>(
                local_embed, gx_ws, W_hh, b_hh, basep, rtiles, Rc, hist);

            const int htiles16 = (rows * T_STEPS) / 16;
            int hblk = (htiles16 + 1) / 2;
            if (hblk > 1024) hblk = 1024;
            const int piblk = first ? 768 : 0;
            heads_pi_kernel<<<hblk + piblk, 256, 0, stream>>>(
                hist, basep, htiles16, hblk,
                loc1_w, loc1_b, loc_ln_g, loc_ln_b, loc2_w, loc2_b,
                sc1_w, sc1_b, sc_ln_g, sc_ln_b, sc2_w, sc2_b, traj,
                local_embed, global_embed,
                pi1_w, pi1_b, pi_ln1_g, pi_ln1_b,
                pi2_w, pi2_b, pi_ln2_g, pi_ln2_b, pi3_w, pi3_b, pi_out);
            first = false;
        }
    }
}

// Round 11
// 629.386 us; speedup vs baseline: 2.5280x; 1.0192x over previous
//
#include <hip/hip_runtime.h>
#include <math.h>

#define H 128
#define I_DIM 128
#define T_STEPS 30
#define M_MODES 6
#define N_AG 8192
#define B_TOT (M_MODES * N_AG)   /* 49152 */
#define LN_EPS 1e-5f
#define MIN_SCALE 0.001f

typedef short bf16x8 __attribute__((ext_vector_type(8)));
typedef float f32x4 __attribute__((ext_vector_type(4)));

#define MFMA16x16x32(A, B, C) __builtin_amdgcn_mfma_f32_16x16x32_bf16(A, B, C, 0, 0, 0)

__device__ __forceinline__ short f2b(float f) {
    union { float f; unsigned u; } v; v.f = f;
    return (short)((v.u + 0x7FFFu + ((v.u >> 16) & 1u)) >> 16);
}

__device__ __forceinline__ bf16x8 load8_cvt(const float* __restrict__ p) {
    const float4 a = ((const float4*)p)[0];
    const float4 b = ((const float4*)p)[1];
    bf16x8 r;
    r[0]=f2b(a.x); r[1]=f2b(a.y); r[2]=f2b(a.z); r[3]=f2b(a.w);
    r[4]=f2b(b.x); r[5]=f2b(b.y); r[6]=f2b(b.z); r[7]=f2b(b.w);
    return r;
}

__device__ __forceinline__ float fast_sigm(float x) {
    return __builtin_amdgcn_rcpf(1.f + __expf(-x));
}
__device__ __forceinline__ float fast_tanh(float x) {
    return 1.f - 2.f * __builtin_amdgcn_rcpf(1.f + __expf(2.f * x));
}

// 16-lane all-reduce sum via DPP (VALU pipe)
#define DPP_ADD(v, ctrl)                                                     \
    v += __builtin_bit_cast(float, __builtin_amdgcn_mov_dpp(                 \
             __builtin_bit_cast(int, v), ctrl, 0xF, 0xF, true))

__device__ __forceinline__ float red16(float v) {
    DPP_ADD(v, 0xB1);
    DPP_ADD(v, 0x4E);
    DPP_ADD(v, 0x124);
    DPP_ADD(v, 0x128);
    return v;
}

// ===========================================================================
// Kernel 0: gx = x @ W_ih^T + b_ih (+ b_hh folded for r,z).  TRANSPOSED out.
// ===========================================================================
__global__ __launch_bounds__(256, 2) void gx_kernel(
    const float* __restrict__ global_embed,
    const float* __restrict__ W_ih, const float* __restrict__ b_ih,
    const float* __restrict__ b_hh,
    int base, int ntiles, int Rc, float* __restrict__ gx_ws)
{
    __shared__ short xbuf[16][136];

    const int tid = threadIdx.x;
    const int w  = tid >> 6;
    const int l  = tid & 63;
    const int ln = l & 15;
    const int lg = l >> 4;

    bf16x8 wf[6][4];
    float bias[6];
    #pragma unroll
    for (int nt = 0; nt < 6; ++nt) {
        const int ch = 96*w + 16*nt + ln;
        #pragma unroll
        for (int kt = 0; kt < 4; ++kt)
            wf[nt][kt] = load8_cvt(W_ih + (size_t)ch * I_DIM + kt*32 + lg*8);
        bias[nt] = b_ih[ch] + (ch < 2*H ? b_hh[ch] : 0.f);
    }

    const int s_r = tid >> 4, s_sg = tid & 15;

    for (int it = blockIdx.x; it < ntiles; it += gridDim.x) {
        const int r0 = it * 16;
        __syncthreads();
        {
            const float* src = global_embed + (size_t)(base + r0 + s_r) * I_DIM + s_sg*8;
            const float4 a = ((const float4*)src)[0];
            const float4 c = ((const float4*)src)[1];
            short tmp[8];
            tmp[0]=f2b(a.x); tmp[1]=f2b(a.y); tmp[2]=f2b(a.z); tmp[3]=f2b(a.w);
            tmp[4]=f2b(c.x); tmp[5]=f2b(c.y); tmp[6]=f2b(c.z); tmp[7]=f2b(c.w);
            *(uint4*)&xbuf[s_r][s_sg*8] = *(uint4*)tmp;
        }
        __syncthreads();

        bf16x8 af[4];
        #pragma unroll
        for (int kt = 0; kt < 4; ++kt)
            af[kt] = *(const bf16x8*)&xbuf[ln][kt*32 + lg*8];

        f32x4 acc[6];
        #pragma unroll
        for (int nt = 0; nt < 6; ++nt) acc[nt] = (f32x4)(0.f);
        #pragma unroll
        for (int kt = 0; kt < 4; ++kt)
            #pragma unroll
            for (int nt = 0; nt < 6; ++nt)
                acc[nt] = MFMA16x16x32(af[kt], wf[nt][kt], acc[nt]);

        #pragma unroll
        for (int nt = 0; nt < 6; ++nt) {
            const f32x4 v = acc[nt] + (f32x4)(bias[nt]);
            *(f32x4*)(gx_ws + (size_t)(96*w + 16*nt + ln) * Rc + r0 + lg*4) = v;
        }
    }
}

// ===========================================================================
// Fused kernel: 512 threads = 8 waves.
//   blocks [0, F):  wave-specialized GRU (waves 0-3) + loc/sc heads (4-7),
//                   h passed through double-buffered LDS; NO hist buffer.
//                   Separate per-role loops with MATCHED barrier counts so
//                   register live-ranges don't union (round-5 spill lesson).
//   blocks [F, ..): pi head, two independent 256-thread groups per block.
// ===========================================================================
#define PI_INBF_OFF   0
#define PI_H1_OFF     33792
#define PI_REDL_OFF   51200
#define PI_RED3_OFF   53248
#define SM_BYTES      54272

__global__ __launch_bounds__(512, 2) void fused_kernel(
    const float* __restrict__ local_embed, const float* __restrict__ gx_ws,
    const float* __restrict__ W_hh, const float* __restrict__ b_hh,
    int base, int ntiles, int Rc, int F,
    const float* __restrict__ loc1_w, const float* __restrict__ loc1_b,
    const float* __restrict__ loc_ln_g, const float* __restrict__ loc_ln_b,
    const float* __restrict__ loc2_w, const float* __restrict__ loc2_b,
    const float* __restrict__ sc1_w, const float* __restrict__ sc1_b,
    const float* __restrict__ sc_ln_g, const float* __restrict__ sc_ln_b,
    const float* __restrict__ sc2_w, const float* __restrict__ sc2_b,
    float* __restrict__ traj,
    const float* __restrict__ global_embed,
    const float* __restrict__ pi1_w, const float* __restrict__ pi1_b,
    const float* __restrict__ ln1_g, const float* __restrict__ ln1_b,
    const float* __restrict__ pi2_w, const float* __restrict__ pi2_b,
    const float* __restrict__ ln2_g, const float* __restrict__ ln2_b,
    const float* __restrict__ pi3_w, const float* __restrict__ pi3_b,
    float* __restrict__ pi_out)
{
    __shared__ __align__(16) char smraw[SM_BYTES];

    const int tid = threadIdx.x;
    const int w  = tid >> 6;          // wave 0..7
    const int l  = tid & 63;
    const int ln = l & 15;
    const int lg = l >> 4;

    if ((int)blockIdx.x < F) {
        short (*hb0p)[136] = (short(*)[136])smraw;
        short (*hb1p)[136] = (short(*)[136])(smraw + 8704);

        if (w < 4) {
            // ================= GRU waves =================
            bf16x8 wf[3][2][4];
            float bhn[2];
            #pragma unroll
            for (int u = 0; u < 2; ++u) {
                const int c = 32*w + 16*u + ln;
                bhn[u] = b_hh[2*H + c];
                #pragma unroll
                for (int g = 0; g < 3; ++g) {
                    const int crow = g*H + c;
                    #pragma unroll
                    for (int kt = 0; kt < 4; ++kt)
                        wf[g][u][kt] = load8_cvt(W_hh + (size_t)crow * H + kt*32 + lg*8);
                }
            }

            for (int it = blockIdx.x; it < ntiles; it += F) {
                const int lb0 = it * 32;
                __syncthreads();                       // B-top: LDS reuse safe

                // stage h0 -> hb0 (256 threads: row tid>>3, 2 x 16B segments)
                {
                    const int r  = tid >> 3;           // 0..31
                    const int sg = tid & 7;
                    const int b = base + lb0 + r;
                    const int n = b & (N_AG - 1);
                    const float* src = local_embed + (size_t)n * H;
                    #pragma unroll
                    for (int hseg = 0; hseg < 2; ++hseg) {
                        const int s8 = sg + hseg*8;    // 0..15
                        const float4 a = ((const float4*)(src + s8*8))[0];
                        const float4 c = ((const float4*)(src + s8*8))[1];
                        short tmp[8];
                        tmp[0]=f2b(a.x); tmp[1]=f2b(a.y); tmp[2]=f2b(a.z); tmp[3]=f2b(a.w);
                        tmp[4]=f2b(c.x); tmp[5]=f2b(c.y); tmp[6]=f2b(c.z); tmp[7]=f2b(c.w);
                        *(uint4*)&hb0p[r][s8*8] = *(uint4*)tmp;
                    }
                }

                // f32 master h + gx for owned channels
                float h_reg[2][2][4];
                #pragma unroll
                for (int grp = 0; grp < 2; ++grp)
                    #pragma unroll
                    for (int u = 0; u < 2; ++u) {
                        const int j = 32*w + 16*u + ln;
                        #pragma unroll
                        for (int rg = 0; rg < 4; ++rg) {
                            const int b = base + lb0 + grp*16 + lg*4 + rg;
                            const int n = b & (N_AG - 1);
                            h_reg[grp][u][rg] = local_embed[(size_t)n * H + j];
                        }
                    }
                float gx[2][3][2][4];
                #pragma unroll
                for (int grp = 0; grp < 2; ++grp)
                    #pragma unroll
                    for (int g = 0; g < 3; ++g)
                        #pragma unroll
                        for (int u = 0; u < 2; ++u) {
                            const int ch = g*128 + 32*w + 16*u + ln;
                            const f32x4 v = *(const f32x4*)(gx_ws + (size_t)ch * Rc + lb0 + grp*16 + lg*4);
                            #pragma unroll
                            for (int rg = 0; rg < 4; ++rg) gx[grp][g][u][rg] = v[rg];
                        }
                __syncthreads();                       // B-stage: h0 visible

                int cur = 0;
                for (int i = 0; i <= T_STEPS; ++i) {
                    if (i < T_STEPS) {
                        short (*hc)[136] = cur ? hb1p : hb0p;
                        short (*hx)[136] = cur ? hb0p : hb1p;
                        #pragma unroll
                        for (int grp = 0; grp < 2; ++grp) {
                            bf16x8 af[4];
                            #pragma unroll
                            for (int kt = 0; kt < 4; ++kt)
                                af[kt] = *(const bf16x8*)&hc[grp*16 + ln][kt*32 + lg*8];

                            f32x4 ga[3][2];
                            #pragma unroll
                            for (int g = 0; g < 3; ++g)
                                #pragma unroll
                                for (int u = 0; u < 2; ++u) ga[g][u] = (f32x4)(0.f);
                            #pragma unroll
                            for (int kt = 0; kt < 4; ++kt)
                                #pragma unroll
                                for (int g = 0; g < 3; ++g)
                                    #pragma unroll
                                    for (int u = 0; u < 2; ++u)
                                        ga[g][u] = MFMA16x16x32(af[kt], wf[g][u][kt], ga[g][u]);

                            #pragma unroll
                            for (int u = 0; u < 2; ++u) {
                                const int j = 32*w + 16*u + ln;
                                #pragma unroll
                                for (int rg = 0; rg < 4; ++rg) {
                                    const float rr = fast_sigm(gx[grp][0][u][rg] + ga[0][u][rg]);
                                    const float zz = fast_sigm(gx[grp][1][u][rg] + ga[1][u][rg]);
                                    const float nn = fast_tanh(gx[grp][2][u][rg] + rr * (ga[2][u][rg] + bhn[u]));
                                    const float h  = (1.f - zz) * nn + zz * h_reg[grp][u][rg];
                                    h_reg[grp][u][rg] = h;
                                    hx[grp*16 + lg*4 + rg][j] = f2b(h);
                                }
                            }
                        }
                    }
                    __syncthreads();                   // B-step
                    cur ^= 1;
                }
            }
        } else {
            // ================= heads waves =================
            const int hw = w - 4;
            const int hd = hw & 1;                 // 0 = loc, 1 = sc
            const int mrow = (hw >> 1) * 16;       // rows 0-15 / 16-31

            const float* __restrict__ W1  = hd ? sc1_w   : loc1_w;
            const float* __restrict__ B1v = hd ? sc1_b   : loc1_b;
            const float* __restrict__ Gv  = hd ? sc_ln_g : loc_ln_g;
            const float* __restrict__ Bv  = hd ? sc_ln_b : loc_ln_b;
            const float* __restrict__ W2  = hd ? sc2_w   : loc2_w;
            const float* __restrict__ B2v = hd ? sc2_b   : loc2_b;

            bf16x8 whf[8][4];
            float bias1[8], lng[8], lnb[8], w2a[8], w2b[8];
            #pragma unroll
            for (int nt = 0; nt < 8; ++nt) {
                const int c = 16*nt + ln;
                #pragma unroll
                for (int kt = 0; kt < 4; ++kt)
                    whf[nt][kt] = load8_cvt(W1 + (size_t)c * H + kt*32 + lg*8);
                bias1[nt] = B1v[c]; lng[nt] = Gv[c]; lnb[nt] = Bv[c];
                w2a[nt] = W2[c];    w2b[nt] = W2[H + c];
            }
            const float b2_0 = B2v[0], b2_1 = B2v[1];

            for (int it = blockIdx.x; it < ntiles; it += F) {
                const int lb0 = it * 32;
                __syncthreads();                       // B-top (match)
                __syncthreads();                       // B-stage (match)

                int cur = 0;
                for (int i = 0; i <= T_STEPS; ++i) {
                    if (i >= 1) {
                        short (*hc)[136] = cur ? hb1p : hb0p;
                        bf16x8 af[4];
                        #pragma unroll
                        for (int kt = 0; kt < 4; ++kt)
                            af[kt] = *(const bf16x8*)&hc[mrow + ln][kt*32 + lg*8];

                        f32x4 acc[8];
                        #pragma unroll
                        for (int nt = 0; nt < 8; ++nt) acc[nt] = (f32x4)(0.f);
                        #pragma unroll
                        for (int kt = 0; kt < 4; ++kt)
                            #pragma unroll
                            for (int nt = 0; nt < 8; ++nt)
                                acc[nt] = MFMA16x16x32(af[kt], whf[nt][kt], acc[nt]);

                        const int t = i - 1;
                        #pragma unroll
                        for (int rg = 0; rg < 4; ++rg) {
                            float s = 0.f, q = 0.f;
                            #pragma unroll
                            for (int nt = 0; nt < 8; ++nt) {
                                const float a = acc[nt][rg] + bias1[nt];
                                acc[nt][rg] = a;
                                s += a; q += a*a;
                            }
                            s = red16(s);
                            q = red16(q);
                            const float mu = s * (1.f/H);
                            const float var = q * (1.f/H) - mu*mu;
                            const float rs = rsqrtf(var + LN_EPS);
                            const float murs = mu * rs;
                            float p0 = 0.f, p1 = 0.f;
                            #pragma unroll
                            for (int nt = 0; nt < 8; ++nt) {
                                float v = fmaf(fmaf(acc[nt][rg], rs, -murs), lng[nt], lnb[nt]);
                                v = fmaxf(v, 0.f);
                                p0 = fmaf(v, w2a[nt], p0);
                                p1 = fmaf(v, w2b[nt], p1);
                            }
                            p0 = red16(p0);
                            p1 = red16(p1);
                            if (ln == 0) {
                                const int b = base + lb0 + mrow + lg*4 + rg;
                                float v0 = p0 + b2_0;
                                float v1 = p1 + b2_1;
                                if (hd) {
                                    v0 = (v0 > 0.f ? v0 : expm1f(v0)) + 1.0f + MIN_SCALE;
                                    v1 = (v1 > 0.f ? v1 : expm1f(v1)) + 1.0f + MIN_SCALE;
                                }
                                *(float2*)(traj + ((size_t)b * T_STEPS + t) * 4 + hd*2) = make_float2(v0, v1);
                            }
                        }
                    }
                    __syncthreads();                   // B-step (match)
                    cur ^= 1;
                }
            }
        }
        return;
    }

    // ================= pi path (2 x 256-thread groups) =================
    {
        const int pbid = blockIdx.x - F;
        const int pgrid = gridDim.x - F;
        const int sub  = tid >> 8;                 // group 0/1
        const int stid = tid & 255;
        const int w4 = stid >> 6;

        short (*inbf)[264] = (short(*)[264])(smraw + PI_INBF_OFF + (size_t)sub*16896);
        short (*h1bf)[136] = (short(*)[136])(smraw + PI_H1_OFF   + (size_t)sub*8704);
        float (*redL)[32][2] = (float(*)[32][2])(smraw + PI_REDL_OFF + (size_t)sub*1024);
        float (*red3)[32]    = (float(*)[32])(smraw + PI_RED3_OFF + (size_t)sub*512);

        bf16x8 wf1[2][8];
        bf16x8 wf2[2][4];
        float b1[2], g1[2], bb1[2], b2[2], g2[2], bb2[2], w3[2];
        #pragma unroll
        for (int nt = 0; nt < 2; ++nt) {
            const int c = 32*w4 + 16*nt + ln;
            #pragma unroll
            for (int kt = 0; kt < 8; ++kt)
                wf1[nt][kt] = load8_cvt(pi1_w + (size_t)c * (2*H) + kt*32 + lg*8);
            #pragma unroll
            for (int kt = 0; kt < 4; ++kt)
                wf2[nt][kt] = load8_cvt(pi2_w + (size_t)c * H + kt*32 + lg*8);
            b1[nt] = pi1_b[c]; g1[nt] = ln1_g[c]; bb1[nt] = ln1_b[c];
            b2[nt] = pi2_b[c]; g2[nt] = ln2_g[c]; bb2[nt] = ln2_b[c];
            w3[nt] = pi3_w[c];
        }
        const float b3 = pi3_b[0];

        const int npairs = (B_TOT / 32) / 2;       // 768

        for (int p = pbid; p < npairs; p += pgrid) {
            const int r0 = (p*2 + sub) * 32;
            {
                const int r   = stid >> 3;
                const int seg = stid & 7;
                const int b = r0 + r;
                const int n = b & (N_AG - 1);
                const float* src = (seg < 4) ? (local_embed + (size_t)n * H + seg * 32)
                                             : (global_embed + (size_t)b * I_DIM + (seg - 4) * 32);
                short tmp[32];
                #pragma unroll
                for (int i = 0; i < 8; ++i) {
                    const float4 v = ((const float4*)src)[i];
                    tmp[i*4+0]=f2b(v.x); tmp[i*4+1]=f2b(v.y); tmp[i*4+2]=f2b(v.z); tmp[i*4+3]=f2b(v.w);
                }
                #pragma unroll
                for (int i = 0; i < 4; ++i)
                    *(uint4*)&inbf[r][seg*32 + i*8] = *(uint4*)&tmp[i*8];
            }
            __syncthreads();

            f32x4 acc1[2][2];
            #pragma unroll
            for (int m = 0; m < 2; ++m) {
                #pragma unroll
                for (int nt = 0; nt < 2; ++nt) acc1[m][nt] = (f32x4)(0.f);
                bf16x8 af[8];
                #pragma unroll
                for (int kt = 0; kt < 8; ++kt)
                    af[kt] = *(const bf16x8*)&inbf[m*16 + ln][kt*32 + lg*8];
                #pragma unroll
                for (int kt = 0; kt < 8; ++kt)
                    #pragma unroll
                    for (int nt = 0; nt < 2; ++nt)
                        acc1[m][nt] = MFMA16x16x32(af[kt], wf1[nt][kt], acc1[m][nt]);
            }

            #pragma unroll
            for (int m = 0; m < 2; ++m)
                #pragma unroll
                for (int rg = 0; rg < 4; ++rg) {
                    float s = 0.f, q = 0.f;
                    #pragma unroll
                    for (int nt = 0; nt < 2; ++nt) {
                        const float a = acc1[m][nt][rg] + b1[nt];
                        acc1[m][nt][rg] = a;
                        s += a; q += a*a;
                    }
                    s = red16(s);
                    q = red16(q);
                    if (ln == 0) {
                        const int row = m*16 + lg*4 + rg;
                        redL[w4][row][0] = s;
                        redL[w4][row][1] = q;
                    }
                }
            __syncthreads();

            #pragma unroll
            for (int m = 0; m < 2; ++m)
                #pragma unroll
                for (int rg = 0; rg < 4; ++rg) {
                    const int row = m*16 + lg*4 + rg;
                    const float S = redL[0][row][0] + redL[1][row][0] + redL[2][row][0] + redL[3][row][0];
                    const float Q = redL[0][row][1] + redL[1][row][1] + redL[2][row][1] + redL[3][row][1];
                    const float mu = S * (1.f/H);
                    const float var = Q * (1.f/H) - mu*mu;
                    const float rs = rsqrtf(var + LN_EPS);
                    #pragma unroll
                    for (int nt = 0; nt < 2; ++nt) {
                        const float v = fmaxf((acc1[m][nt][rg] - mu) * rs * g1[nt] + bb1[nt], 0.f);
                        h1bf[row][32*w4 + 16*nt + ln] = f2b(v);
                    }
                }
            __syncthreads();

            f32x4 acc2[2][2];
            #pragma unroll
            for (int m = 0; m < 2; ++m) {
                #pragma unroll
                for (int nt = 0; nt < 2; ++nt) acc2[m][nt] = (f32x4)(0.f);
                bf16x8 af[4];
                #pragma unroll
                for (int kt = 0; kt < 4; ++kt)
                    af[kt] = *(const bf16x8*)&h1bf[m*16 + ln][kt*32 + lg*8];
                #pragma unroll
                for (int kt = 0; kt < 4; ++kt)
                    #pragma unroll
                    for (int nt = 0; nt < 2; ++nt)
                        acc2[m][nt] = MFMA16x16x32(af[kt], wf2[nt][kt], acc2[m][nt]);
            }

            #pragma unroll
            for (int m = 0; m < 2; ++m)
                #pragma unroll
                for (int rg = 0; rg < 4; ++rg) {
                    float s = 0.f, q = 0.f;
                    #pragma unroll
                    for (int nt = 0; nt < 2; ++nt) {
                        const float a = acc2[m][nt][rg] + b2[nt];
                        acc2[m][nt][rg] = a;
                        s += a; q += a*a;
                    }
                    s = red16(s);
                    q = red16(q);
                    if (ln == 0) {
                        const int row = m*16 + lg*4 + rg;
                        redL[w4][row][0] = s;
                        redL[w4][row][1] = q;
                    }
                }
            __syncthreads();

            #pragma unroll
            for (int m = 0; m < 2; ++m)
                #pragma unroll
                for (int rg = 0; rg < 4; ++rg) {
                    const int row = m*16 + lg*4 + rg;
                    const float S = redL[0][row][0] + redL[1][row][0] + redL[2][row][0] + redL[3][row][0];
                    const float Q = redL[0][row][1] + redL[1][row][1] + redL[2][row][1] + redL[3][row][1];
                    const float mu = S * (1.f/H);
                    const float var = Q * (1.f/H) - mu*mu;
                    const float rs = rsqrtf(var + LN_EPS);
                    float p2 = 0.f;
                    #pragma unroll
                    for (int nt = 0; nt < 2; ++nt) {
                        const float v = fmaxf((acc2[m][nt][rg] - mu) * rs * g2[nt] + bb2[nt], 0.f);
                        p2 = fmaf(v, w3[nt], p2);
                    }
                    p2 = red16(p2);
                    if (ln == 0) red3[w4][row] = p2;
                }
            __syncthreads();

            if (stid < 32) {
                const int row = stid;
                const float pv = red3[0][row] + red3[1][row] + red3[2][row] + red3[3][row] + b3;
                const int b = r0 + row;
                const int n = b & (N_AG - 1);
                const int m = b >> 13;
                pi_out[(size_t)n * M_MODES + m] = pv;
            }
            __syncthreads();
        }
    }
}

extern "C" void kernel_launch(void* const* d_in, const int* in_sizes, int n_in,
                              void* d_out, int out_size, void* d_ws, size_t ws_size,
                              hipStream_t stream) {
    (void)in_sizes; (void)n_in; (void)out_size;
    const float* local_embed  = (const float*)d_in[0];
    const float* global_embed = (const float*)d_in[1];
    const float* W_ih   = (const float*)d_in[2];
    const float* W_hh   = (const float*)d_in[3];
    const float* b_ih   = (const float*)d_in[4];
    const float* b_hh   = (const float*)d_in[5];
    const float* loc1_w = (const float*)d_in[6];
    const float* loc1_b = (const float*)d_in[7];
    const float* loc_ln_g = (const float*)d_in[8];
    const float* loc_ln_b = (const float*)d_in[9];
    const float* loc2_w = (const float*)d_in[10];
    const float* loc2_b = (const float*)d_in[11];
    const float* sc1_w  = (const float*)d_in[12];
    const float* sc1_b  = (const float*)d_in[13];
    const float* sc_ln_g = (const float*)d_in[14];
    const float* sc_ln_b = (const float*)d_in[15];
    const float* sc2_w  = (const float*)d_in[16];
    const float* sc2_b  = (const float*)d_in[17];
    const float* pi1_w  = (const float*)d_in[18];
    const float* pi1_b  = (const float*)d_in[19];
    const float* pi_ln1_g = (const float*)d_in[20];
    const float* pi_ln1_b = (const float*)d_in[21];
    const float* pi2_w  = (const float*)d_in[22];
    const float* pi2_b  = (const float*)d_in[23];
    const float* pi_ln2_g = (const float*)d_in[24];
    const float* pi_ln2_b = (const float*)d_in[25];
    const float* pi3_w  = (const float*)d_in[26];
    const float* pi3_b  = (const float*)d_in[27];

    float* traj = (float*)d_out;
    float* pi_out = traj + (size_t)B_TOT * T_STEPS * 4;

    // workspace: gx only (transposed [384][Rc] f32)
    const size_t row_bytes = 384 * sizeof(float);
    long long rc = (long long)(ws_size / row_bytes);
    int Rc = rc > B_TOT ? B_TOT : (int)rc;
    Rc &= ~31;

    if (Rc >= 32) {
        float* gx_ws = (float*)d_ws;
        bool first = true;

        for (int basep = 0; basep < B_TOT; basep += Rc) {
            const int rows = (B_TOT - basep < Rc) ? (B_TOT - basep) : Rc;

            const int gxtiles = rows / 16;
            gx_kernel<<<(gxtiles < 512 ? gxtiles : 512), 256, 0, stream>>>(
                global_embed, W_ih, b_ih, b_hh, basep, gxtiles, Rc, gx_ws);

            const int ntiles = rows / 32;
            int F = ntiles < 224 ? ntiles : 224;
            const int P = first ? 32 : 0;
            fused_kernel<<<F + P, 512, 0, stream>>>(
                local_embed, gx_ws, W_hh, b_hh, basep, ntiles, Rc, F,
                loc1_w, loc1_b, loc_ln_g, loc_ln_b, loc2_w, loc2_b,
                sc1_w, sc1_b, sc_ln_g, sc_ln_b, sc2_w, sc2_b, traj,
                global_embed,
                pi1_w, pi1_b, pi_ln1_g, pi_ln1_b,
                pi2_w, pi2_b, pi_ln2_g, pi_ln2_b, pi3_w, pi3_b, pi_out);
            first = false;
        }
    }
}

// Round 12
// 589.150 us; speedup vs baseline: 2.7006x; 1.0683x over previous
//
#include <hip/hip_runtime.h>
#include <math.h>

#define H 128
#define I_DIM 128
#define T_STEPS 30
#define M_MODES 6
#define N_AG 8192
#define B_TOT (M_MODES * N_AG)   /* 49152 */
#define LN_EPS 1e-5f
#define MIN_SCALE 0.001f
#define LOG2E 1.44269504088896f

typedef short bf16x8 __attribute__((ext_vector_type(8)));
typedef float f32x4 __attribute__((ext_vector_type(4)));

#define MFMA16x16x32(A, B, C) __builtin_amdgcn_mfma_f32_16x16x32_bf16(A, B, C, 0, 0, 0)

__device__ __forceinline__ short f2b(float f) {
    union { float f; unsigned u; } v; v.f = f;
    return (short)((v.u + 0x7FFFu + ((v.u >> 16) & 1u)) >> 16);
}

__device__ __forceinline__ bf16x8 load8_cvt(const float* __restrict__ p) {
    const float4 a = ((const float4*)p)[0];
    const float4 b = ((const float4*)p)[1];
    bf16x8 r;
    r[0]=f2b(a.x); r[1]=f2b(a.y); r[2]=f2b(a.z); r[3]=f2b(a.w);
    r[4]=f2b(b.x); r[5]=f2b(b.y); r[6]=f2b(b.z); r[7]=f2b(b.w);
    return r;
}

// scaled variant (exp2 pre-scaling folded into weights before bf16 rounding)
__device__ __forceinline__ bf16x8 load8_cvt_s(const float* __restrict__ p, float s) {
    const float4 a = ((const float4*)p)[0];
    const float4 b = ((const float4*)p)[1];
    bf16x8 r;
    r[0]=f2b(a.x*s); r[1]=f2b(a.y*s); r[2]=f2b(a.z*s); r[3]=f2b(a.w*s);
    r[4]=f2b(b.x*s); r[5]=f2b(b.y*s); r[6]=f2b(b.z*s); r[7]=f2b(b.w*s);
    return r;
}

// base-2 gate functions: inputs pre-scaled by log2e (sigm) / 2*log2e (tanh)
__device__ __forceinline__ float sigm2(float xp) {
    return __builtin_amdgcn_rcpf(1.f + __builtin_amdgcn_exp2f(-xp));
}
__device__ __forceinline__ float tanh2(float yp) {   // yp = 2*log2e*x
    return 1.f - 2.f * __builtin_amdgcn_rcpf(1.f + __builtin_amdgcn_exp2f(yp));
}

// 16-lane all-reduce sum via DPP (VALU pipe)
#define DPP_ADD(v, ctrl)                                                     \
    v += __builtin_bit_cast(float, __builtin_amdgcn_mov_dpp(                 \
             __builtin_bit_cast(int, v), ctrl, 0xF, 0xF, true))

__device__ __forceinline__ float red16(float v) {
    DPP_ADD(v, 0xB1);
    DPP_ADD(v, 0x4E);
    DPP_ADD(v, 0x124);
    DPP_ADD(v, 0x128);
    return v;
}

// ===========================================================================
// Kernel 0: gx = x @ W_ih^T + b_ih (+ b_hh folded for r,z), all pre-scaled
// for exp2 gates (r,z rows x log2e; n rows x 2log2e). TRANSPOSED out.
// ===========================================================================
__global__ __launch_bounds__(256, 2) void gx_kernel(
    const float* __restrict__ global_embed,
    const float* __restrict__ W_ih, const float* __restrict__ b_ih,
    const float* __restrict__ b_hh,
    int base, int ntiles, int Rc, float* __restrict__ gx_ws)
{
    __shared__ short xbuf[16][136];

    const int tid = threadIdx.x;
    const int w  = tid >> 6;
    const int l  = tid & 63;
    const int ln = l & 15;
    const int lg = l >> 4;

    bf16x8 wf[6][4];
    float bias[6];
    #pragma unroll
    for (int nt = 0; nt < 6; ++nt) {
        const int ch = 96*w + 16*nt + ln;
        const float sc = (ch < 2*H) ? LOG2E : (2.f * LOG2E);
        #pragma unroll
        for (int kt = 0; kt < 4; ++kt)
            wf[nt][kt] = load8_cvt_s(W_ih + (size_t)ch * I_DIM + kt*32 + lg*8, sc);
        bias[nt] = (b_ih[ch] + (ch < 2*H ? b_hh[ch] : 0.f)) * sc;
    }

    const int s_r = tid >> 4, s_sg = tid & 15;

    for (int it = blockIdx.x; it < ntiles; it += gridDim.x) {
        const int r0 = it * 16;
        __syncthreads();
        {
            const float* src = global_embed + (size_t)(base + r0 + s_r) * I_DIM + s_sg*8;
            const float4 a = ((const float4*)src)[0];
            const float4 c = ((const float4*)src)[1];
            short tmp[8];
            tmp[0]=f2b(a.x); tmp[1]=f2b(a.y); tmp[2]=f2b(a.z); tmp[3]=f2b(a.w);
            tmp[4]=f2b(c.x); tmp[5]=f2b(c.y); tmp[6]=f2b(c.z); tmp[7]=f2b(c.w);
            *(uint4*)&xbuf[s_r][s_sg*8] = *(uint4*)tmp;
        }
        __syncthreads();

        bf16x8 af[4];
        #pragma unroll
        for (int kt = 0; kt < 4; ++kt)
            af[kt] = *(const bf16x8*)&xbuf[ln][kt*32 + lg*8];

        f32x4 acc[6];
        #pragma unroll
        for (int nt = 0; nt < 6; ++nt) acc[nt] = (f32x4)(0.f);
        #pragma unroll
        for (int kt = 0; kt < 4; ++kt)
            #pragma unroll
            for (int nt = 0; nt < 6; ++nt)
                acc[nt] = MFMA16x16x32(af[kt], wf[nt][kt], acc[nt]);

        #pragma unroll
        for (int nt = 0; nt < 6; ++nt) {
            const f32x4 v = acc[nt] + (f32x4)(bias[nt]);
            *(f32x4*)(gx_ws + (size_t)(96*w + 16*nt + ln) * Rc + r0 + lg*4) = v;
        }
    }
}

// ===========================================================================
// Fused kernel: 512 threads = 8 waves.
//   blocks [0, F):  wave-specialized GRU (waves 0-3) + loc/sc heads (4-7).
//   blocks [F, ..): pi head, two independent 256-thread groups per block.
// ===========================================================================
#define PI_INBF_OFF   0
#define PI_H1_OFF     33792
#define PI_REDL_OFF   51200
#define PI_RED3_OFF   53248
#define SM_BYTES      54272

__global__ __launch_bounds__(512, 2) void fused_kernel(
    const float* __restrict__ local_embed, const float* __restrict__ gx_ws,
    const float* __restrict__ W_hh, const float* __restrict__ b_hh,
    int base, int ntiles, int Rc, int F,
    const float* __restrict__ loc1_w, const float* __restrict__ loc1_b,
    const float* __restrict__ loc_ln_g, const float* __restrict__ loc_ln_b,
    const float* __restrict__ loc2_w, const float* __restrict__ loc2_b,
    const float* __restrict__ sc1_w, const float* __restrict__ sc1_b,
    const float* __restrict__ sc_ln_g, const float* __restrict__ sc_ln_b,
    const float* __restrict__ sc2_w, const float* __restrict__ sc2_b,
    float* __restrict__ traj,
    const float* __restrict__ global_embed,
    const float* __restrict__ pi1_w, const float* __restrict__ pi1_b,
    const float* __restrict__ ln1_g, const float* __restrict__ ln1_b,
    const float* __restrict__ pi2_w, const float* __restrict__ pi2_b,
    const float* __restrict__ ln2_g, const float* __restrict__ ln2_b,
    const float* __restrict__ pi3_w, const float* __restrict__ pi3_b,
    float* __restrict__ pi_out)
{
    __shared__ __align__(16) char smraw[SM_BYTES];

    const int tid = threadIdx.x;
    const int w  = tid >> 6;          // wave 0..7
    const int l  = tid & 63;
    const int ln = l & 15;
    const int lg = l >> 4;

    if ((int)blockIdx.x < F) {
        short (*hb0p)[136] = (short(*)[136])smraw;
        short (*hb1p)[136] = (short(*)[136])(smraw + 8704);

        if (w < 4) {
            // ================= GRU waves =================
            bf16x8 wf[3][2][4];
            float bhn[2];
            #pragma unroll
            for (int u = 0; u < 2; ++u) {
                const int c = 32*w + 16*u + ln;
                bhn[u] = b_hh[2*H + c] * (2.f * LOG2E);
                #pragma unroll
                for (int g = 0; g < 3; ++g) {
                    const int crow = g*H + c;
                    const float sc = (g < 2) ? LOG2E : (2.f * LOG2E);
                    #pragma unroll
                    for (int kt = 0; kt < 4; ++kt)
                        wf[g][u][kt] = load8_cvt_s(W_hh + (size_t)crow * H + kt*32 + lg*8, sc);
                }
            }

            for (int it = blockIdx.x; it < ntiles; it += F) {
                const int lb0 = it * 32;
                __syncthreads();                       // B-top: LDS reuse safe

                // stage h0 -> hb0
                {
                    const int r  = tid >> 3;           // 0..31
                    const int sg = tid & 7;
                    const int b = base + lb0 + r;
                    const int n = b & (N_AG - 1);
                    const float* src = local_embed + (size_t)n * H;
                    #pragma unroll
                    for (int hseg = 0; hseg < 2; ++hseg) {
                        const int s8 = sg + hseg*8;    // 0..15
                        const float4 a = ((const float4*)(src + s8*8))[0];
                        const float4 c = ((const float4*)(src + s8*8))[1];
                        short tmp[8];
                        tmp[0]=f2b(a.x); tmp[1]=f2b(a.y); tmp[2]=f2b(a.z); tmp[3]=f2b(a.w);
                        tmp[4]=f2b(c.x); tmp[5]=f2b(c.y); tmp[6]=f2b(c.z); tmp[7]=f2b(c.w);
                        *(uint4*)&hb0p[r][s8*8] = *(uint4*)tmp;
                    }
                }

                float h_reg[2][2][4];
                #pragma unroll
                for (int grp = 0; grp < 2; ++grp)
                    #pragma unroll
                    for (int u = 0; u < 2; ++u) {
                        const int j = 32*w + 16*u + ln;
                        #pragma unroll
                        for (int rg = 0; rg < 4; ++rg) {
                            const int b = base + lb0 + grp*16 + lg*4 + rg;
                            const int n = b & (N_AG - 1);
                            h_reg[grp][u][rg] = local_embed[(size_t)n * H + j];
                        }
                    }
                float gx[2][3][2][4];
                #pragma unroll
                for (int grp = 0; grp < 2; ++grp)
                    #pragma unroll
                    for (int g = 0; g < 3; ++g)
                        #pragma unroll
                        for (int u = 0; u < 2; ++u) {
                            const int ch = g*128 + 32*w + 16*u + ln;
                            const f32x4 v = *(const f32x4*)(gx_ws + (size_t)ch * Rc + lb0 + grp*16 + lg*4);
                            #pragma unroll
                            for (int rg = 0; rg < 4; ++rg) gx[grp][g][u][rg] = v[rg];
                        }
                __syncthreads();                       // B-stage: h0 visible

                int cur = 0;
                for (int i = 0; i <= T_STEPS; ++i) {
                    if (i < T_STEPS) {
                        short (*hc)[136] = cur ? hb1p : hb0p;
                        short (*hx)[136] = cur ? hb0p : hb1p;
                        #pragma unroll
                        for (int grp = 0; grp < 2; ++grp) {
                            bf16x8 af[4];
                            #pragma unroll
                            for (int kt = 0; kt < 4; ++kt)
                                af[kt] = *(const bf16x8*)&hc[grp*16 + ln][kt*32 + lg*8];

                            f32x4 ga[3][2];
                            #pragma unroll
                            for (int g = 0; g < 3; ++g)
                                #pragma unroll
                                for (int u = 0; u < 2; ++u) ga[g][u] = (f32x4)(0.f);
                            #pragma unroll
                            for (int kt = 0; kt < 4; ++kt)
                                #pragma unroll
                                for (int g = 0; g < 3; ++g)
                                    #pragma unroll
                                    for (int u = 0; u < 2; ++u)
                                        ga[g][u] = MFMA16x16x32(af[kt], wf[g][u][kt], ga[g][u]);

                            #pragma unroll
                            for (int u = 0; u < 2; ++u) {
                                const int j = 32*w + 16*u + ln;
                                #pragma unroll
                                for (int rg = 0; rg < 4; ++rg) {
                                    const float rr = sigm2(gx[grp][0][u][rg] + ga[0][u][rg]);
                                    const float zz = sigm2(gx[grp][1][u][rg] + ga[1][u][rg]);
                                    const float nn = tanh2(gx[grp][2][u][rg] + rr * (ga[2][u][rg] + bhn[u]));
                                    const float h  = nn + zz * (h_reg[grp][u][rg] - nn);
                                    h_reg[grp][u][rg] = h;
                                    hx[grp*16 + lg*4 + rg][j] = f2b(h);
                                }
                            }
                        }
                    }
                    __syncthreads();                   // B-step
                    cur ^= 1;
                }
            }
        } else {
            // ================= heads waves =================
            const int hw = w - 4;
            const int hd = hw & 1;                 // 0 = loc, 1 = sc
            const int mrow = (hw >> 1) * 16;       // rows 0-15 / 16-31

            const float* __restrict__ W1  = hd ? sc1_w   : loc1_w;
            const float* __restrict__ B1v = hd ? sc1_b   : loc1_b;
            const float* __restrict__ Gv  = hd ? sc_ln_g : loc_ln_g;
            const float* __restrict__ Bv  = hd ? sc_ln_b : loc_ln_b;
            const float* __restrict__ W2  = hd ? sc2_w   : loc2_w;
            const float* __restrict__ B2v = hd ? sc2_b   : loc2_b;

            bf16x8 whf[8][4];
            float bias1[8], lng[8], lnb[8], w2a[8], w2b[8];
            #pragma unroll
            for (int nt = 0; nt < 8; ++nt) {
                const int c = 16*nt + ln;
                #pragma unroll
                for (int kt = 0; kt < 4; ++kt)
                    whf[nt][kt] = load8_cvt(W1 + (size_t)c * H + kt*32 + lg*8);
                bias1[nt] = B1v[c]; lng[nt] = Gv[c]; lnb[nt] = Bv[c];
                w2a[nt] = W2[c];    w2b[nt] = W2[H + c];
            }
            const float b2_0 = B2v[0], b2_1 = B2v[1];

            for (int it = blockIdx.x; it < ntiles; it += F) {
                const int lb0 = it * 32;
                __syncthreads();                       // B-top (match)
                __syncthreads();                       // B-stage (match)

                int cur = 0;
                for (int i = 0; i <= T_STEPS; ++i) {
                    if (i >= 1) {
                        short (*hc)[136] = cur ? hb1p : hb0p;
                        bf16x8 af[4];
                        #pragma unroll
                        for (int kt = 0; kt < 4; ++kt)
                            af[kt] = *(const bf16x8*)&hc[mrow + ln][kt*32 + lg*8];

                        f32x4 acc[8];
                        #pragma unroll
                        for (int nt = 0; nt < 8; ++nt) acc[nt] = (f32x4)(0.f);
                        #pragma unroll
                        for (int kt = 0; kt < 4; ++kt)
                            #pragma unroll
                            for (int nt = 0; nt < 8; ++nt)
                                acc[nt] = MFMA16x16x32(af[kt], whf[nt][kt], acc[nt]);

                        const int t = i - 1;
                        #pragma unroll
                        for (int rg = 0; rg < 4; ++rg) {
                            float s = 0.f, q = 0.f;
                            #pragma unroll
                            for (int nt = 0; nt < 8; ++nt) {
                                const float a = acc[nt][rg] + bias1[nt];
                                acc[nt][rg] = a;
                                s += a; q += a*a;
                            }
                            s = red16(s);
                            q = red16(q);
                            const float mu = s * (1.f/H);
                            const float var = q * (1.f/H) - mu*mu;
                            const float rs = rsqrtf(var + LN_EPS);
                            const float murs = mu * rs;
                            float p0 = 0.f, p1 = 0.f;
                            #pragma unroll
                            for (int nt = 0; nt < 8; ++nt) {
                                float v = fmaf(fmaf(acc[nt][rg], rs, -murs), lng[nt], lnb[nt]);
                                v = fmaxf(v, 0.f);
                                p0 = fmaf(v, w2a[nt], p0);
                                p1 = fmaf(v, w2b[nt], p1);
                            }
                            p0 = red16(p0);
                            p1 = red16(p1);
                            if (ln == 0) {
                                const int b = base + lb0 + mrow + lg*4 + rg;
                                float v0 = p0 + b2_0;
                                float v1 = p1 + b2_1;
                                if (hd) {
                                    v0 = (v0 > 0.f ? v0 : expm1f(v0)) + 1.0f + MIN_SCALE;
                                    v1 = (v1 > 0.f ? v1 : expm1f(v1)) + 1.0f + MIN_SCALE;
                                }
                                *(float2*)(traj + ((size_t)b * T_STEPS + t) * 4 + hd*2) = make_float2(v0, v1);
                            }
                        }
                    }
                    __syncthreads();                   // B-step (match)
                    cur ^= 1;
                }
            }
        }
        return;
    }

    // ================= pi path (2 x 256-thread groups) =================
    {
        const int pbid = blockIdx.x - F;
        const int pgrid = gridDim.x - F;
        const int sub  = tid >> 8;                 // group 0/1
        const int stid = tid & 255;
        const int w4 = stid >> 6;

        short (*inbf)[264] = (short(*)[264])(smraw + PI_INBF_OFF + (size_t)sub*16896);
        short (*h1bf)[136] = (short(*)[136])(smraw + PI_H1_OFF   + (size_t)sub*8704);
        float (*redL)[32][2] = (float(*)[32][2])(smraw + PI_REDL_OFF + (size_t)sub*1024);
        float (*red3)[32]    = (float(*)[32])(smraw + PI_RED3_OFF + (size_t)sub*512);

        bf16x8 wf1[2][8];
        bf16x8 wf2[2][4];
        float b1[2], g1[2], bb1[2], b2[2], g2[2], bb2[2], w3[2];
        #pragma unroll
        for (int nt = 0; nt < 2; ++nt) {
            const int c = 32*w4 + 16*nt + ln;
            #pragma unroll
            for (int kt = 0; kt < 8; ++kt)
                wf1[nt][kt] = load8_cvt(pi1_w + (size_t)c * (2*H) + kt*32 + lg*8);
            #pragma unroll
            for (int kt = 0; kt < 4; ++kt)
                wf2[nt][kt] = load8_cvt(pi2_w + (size_t)c * H + kt*32 + lg*8);
            b1[nt] = pi1_b[c]; g1[nt] = ln1_g[c]; bb1[nt] = ln1_b[c];
            b2[nt] = pi2_b[c]; g2[nt] = ln2_g[c]; bb2[nt] = ln2_b[c];
            w3[nt] = pi3_w[c];
        }
        const float b3 = pi3_b[0];

        const int npairs = (B_TOT / 32) / 2;       // 768

        for (int p = pbid; p < npairs; p += pgrid) {
            const int r0 = (p*2 + sub) * 32;
            {
                const int r   = stid >> 3;
                const int seg = stid & 7;
                const int b = r0 + r;
                const int n = b & (N_AG - 1);
                const float* src = (seg < 4) ? (local_embed + (size_t)n * H + seg * 32)
                                             : (global_embed + (size_t)b * I_DIM + (seg - 4) * 32);
                short tmp[32];
                #pragma unroll
                for (int i = 0; i < 8; ++i) {
                    const float4 v = ((const float4*)src)[i];
                    tmp[i*4+0]=f2b(v.x); tmp[i*4+1]=f2b(v.y); tmp[i*4+2]=f2b(v.z); tmp[i*4+3]=f2b(v.w);
                }
                #pragma unroll
                for (int i = 0; i < 4; ++i)
                    *(uint4*)&inbf[r][seg*32 + i*8] = *(uint4*)&tmp[i*8];
            }
            __syncthreads();

            f32x4 acc1[2][2];
            #pragma unroll
            for (int m = 0; m < 2; ++m) {
                #pragma unroll
                for (int nt = 0; nt < 2; ++nt) acc1[m][nt] = (f32x4)(0.f);
                bf16x8 af[8];
                #pragma unroll
                for (int kt = 0; kt < 8; ++kt)
                    af[kt] = *(const bf16x8*)&inbf[m*16 + ln][kt*32 + lg*8];
                #pragma unroll
                for (int kt = 0; kt < 8; ++kt)
                    #pragma unroll
                    for (int nt = 0; nt < 2; ++nt)
                        acc1[m][nt] = MFMA16x16x32(af[kt], wf1[nt][kt], acc1[m][nt]);
            }

            #pragma unroll
            for (int m = 0; m < 2; ++m)
                #pragma unroll
                for (int rg = 0; rg < 4; ++rg) {
                    float s = 0.f, q = 0.f;
                    #pragma unroll
                    for (int nt = 0; nt < 2; ++nt) {
                        const float a = acc1[m][nt][rg] + b1[nt];
                        acc1[m][nt][rg] = a;
                        s += a; q += a*a;
                    }
                    s = red16(s);
                    q = red16(q);
                    if (ln == 0) {
                        const int row = m*16 + lg*4 + rg;
                        redL[w4][row][0] = s;
                        redL[w4][row][1] = q;
                    }
                }
            __syncthreads();

            #pragma unroll
            for (int m = 0; m < 2; ++m)
                #pragma unroll
                for (int rg = 0; rg < 4; ++rg) {
                    const int row = m*16 + lg*4 + rg;
                    const float S = redL[0][row][0] + redL[1][row][0] + redL[2][row][0] + redL[3][row][0];
                    const float Q = redL[0][row][1] + redL[1][row][1] + redL[2][row][1] + redL[3][row][1];
                    const float mu = S * (1.f/H);
                    const float var = Q * (1.f/H) - mu*mu;
                    const float rs = rsqrtf(var + LN_EPS);
                    #pragma unroll
                    for (int nt = 0; nt < 2; ++nt) {
                        const float v = fmaxf((acc1[m][nt][rg] - mu) * rs * g1[nt] + bb1[nt], 0.f);
                        h1bf[row][32*w4 + 16*nt + ln] = f2b(v);
                    }
                }
            __syncthreads();

            f32x4 acc2[2][2];
            #pragma unroll
            for (int m = 0; m < 2; ++m) {
                #pragma unroll
                for (int nt = 0; nt < 2; ++nt) acc2[m][nt] = (f32x4)(0.f);
                bf16x8 af[4];
                #pragma unroll
                for (int kt = 0; kt < 4; ++kt)
                    af[kt] = *(const bf16x8*)&h1bf[m*16 + ln][kt*32 + lg*8];
                #pragma unroll
                for (int kt = 0; kt < 4; ++kt)
                    #pragma unroll
                    for (int nt = 0; nt < 2; ++nt)
                        acc2[m][nt] = MFMA16x16x32(af[kt], wf2[nt][kt], acc2[m][nt]);
            }

            #pragma unroll
            for (int m = 0; m < 2; ++m)
                #pragma unroll
                for (int rg = 0; rg < 4; ++rg) {
                    float s = 0.f, q = 0.f;
                    #pragma unroll
                    for (int nt = 0; nt < 2; ++nt) {
                        const float a = acc2[m][nt][rg] + b2[nt];
                        acc2[m][nt][rg] = a;
                        s += a; q += a*a;
                    }
                    s = red16(s);
                    q = red16(q);
                    if (ln == 0) {
                        const int row = m*16 + lg*4 + rg;
                        redL[w4][row][0] = s;
                        redL[w4][row][1] = q;
                    }
                }
            __syncthreads();

            #pragma unroll
            for (int m = 0; m < 2; ++m)
                #pragma unroll
                for (int rg = 0; rg < 4; ++rg) {
                    const int row = m*16 + lg*4 + rg;
                    const float S = redL[0][row][0] + redL[1][row][0] + redL[2][row][0] + redL[3][row][0];
                    const float Q = redL[0][row][1] + redL[1][row][1] + redL[2][row][1] + redL[3][row][1];
                    const float mu = S * (1.f/H);
                    const float var = Q * (1.f/H) - mu*mu;
                    const float rs = rsqrtf(var + LN_EPS);
                    float p2 = 0.f;
                    #pragma unroll
                    for (int nt = 0; nt < 2; ++nt) {
                        const float v = fmaxf((acc2[m][nt][rg] - mu) * rs * g2[nt] + bb2[nt], 0.f);
                        p2 = fmaf(v, w3[nt], p2);
                    }
                    p2 = red16(p2);
                    if (ln == 0) red3[w4][row] = p2;
                }
            __syncthreads();

            if (stid < 32) {
                const int row = stid;
                const float pv = red3[0][row] + red3[1][row] + red3[2][row] + red3[3][row] + b3;
                const int b = r0 + row;
                const int n = b & (N_AG - 1);
                const int m = b >> 13;
                pi_out[(size_t)n * M_MODES + m] = pv;
            }
            __syncthreads();
        }
    }
}

extern "C" void kernel_launch(void* const* d_in, const int* in_sizes, int n_in,
                              void* d_out, int out_size, void* d_ws, size_t ws_size,
                              hipStream_t stream) {
    (void)in_sizes; (void)n_in; (void)out_size;
    const float* local_embed  = (const float*)d_in[0];
    const float* global_embed = (const float*)d_in[1];
    const float* W_ih   = (const float*)d_in[2];
    const float* W_hh   = (const float*)d_in[3];
    const float* b_ih   = (const float*)d_in[4];
    const float* b_hh   = (const float*)d_in[5];
    const float* loc1_w = (const float*)d_in[6];
    const float* loc1_b = (const float*)d_in[7];
    const float* loc_ln_g = (const float*)d_in[8];
    const float* loc_ln_b = (const float*)d_in[9];
    const float* loc2_w = (const float*)d_in[10];
    const float* loc2_b = (const float*)d_in[11];
    const float* sc1_w  = (const float*)d_in[12];
    const float* sc1_b  = (const float*)d_in[13];
    const float* sc_ln_g = (const float*)d_in[14];
    const float* sc_ln_b = (const float*)d_in[15];
    const float* sc2_w  = (const float*)d_in[16];
    const float* sc2_b  = (const float*)d_in[17];
    const float* pi1_w  = (const float*)d_in[18];
    const float* pi1_b  = (const float*)d_in[19];
    const float* pi_ln1_g = (const float*)d_in[20];
    const float* pi_ln1_b = (const float*)d_in[21];
    const float* pi2_w  = (const float*)d_in[22];
    const float* pi2_b  = (const float*)d_in[23];
    const float* pi_ln2_g = (const float*)d_in[24];
    const float* pi_ln2_b = (const float*)d_in[25];
    const float* pi3_w  = (const float*)d_in[26];
    const float* pi3_b  = (const float*)d_in[27];

    float* traj = (float*)d_out;
    float* pi_out = traj + (size_t)B_TOT * T_STEPS * 4;

    // workspace: gx only (transposed [384][Rc] f32)
    const size_t row_bytes = 384 * sizeof(float);
    long long rc = (long long)(ws_size / row_bytes);
    int Rc = rc > B_TOT ? B_TOT : (int)rc;
    Rc &= ~31;

    if (Rc >= 32) {
        float* gx_ws = (float*)d_ws;
        bool first = true;

        for (int basep = 0; basep < B_TOT; basep += Rc) {
            const int rows = (B_TOT - basep < Rc) ? (B_TOT - basep) : Rc;

            const int gxtiles = rows / 16;
            gx_kernel<<<(gxtiles < 512 ? gxtiles : 512), 256, 0, stream>>>(
                global_embed, W_ih, b_ih, b_hh, basep, gxtiles, Rc, gx_ws);

            const int ntiles = rows / 32;
            int F = ntiles < 768 ? ntiles : 768;
            const int P = first ? 256 : 0;
            fused_kernel<<<F + P, 512, 0, stream>>>(
                local_embed, gx_ws, W_hh, b_hh, basep, ntiles, Rc, F,
                loc1_w, loc1_b, loc_ln_g, loc_ln_b, loc2_w, loc2_b,
                sc1_w, sc1_b, sc_ln_g, sc_ln_b, sc2_w, sc2_b, traj,
                global_embed,
                pi1_w, pi1_b, pi_ln1_g, pi_ln1_b,
                pi2_w, pi2_b, pi_ln2_g, pi_ln2_b, pi3_w, pi3_b, pi_out);
            first = false;
        }
    }
}

// Round 13
// 568.218 us; speedup vs baseline: 2.8001x; 1.0368x over previous
//
#include <hip/hip_runtime.h>
#include <math.h>

#define H 128
#define I_DIM 128
#define T_STEPS 30
#define M_MODES 6
#define N_AG 8192
#define B_TOT (M_MODES * N_AG)   /* 49152 */
#define LN_EPS 1e-5f
#define MIN_SCALE 0.001f
#define LOG2E 1.44269504088896f

typedef short bf16x8 __attribute__((ext_vector_type(8)));
typedef float f32x4 __attribute__((ext_vector_type(4)));

#define MFMA16x16x32(A, B, C) __builtin_amdgcn_mfma_f32_16x16x32_bf16(A, B, C, 0, 0, 0)

__device__ __forceinline__ unsigned cvt_pk(float lo, float hi) {
    unsigned r;
    asm("v_cvt_pk_bf16_f32 %0, %1, %2" : "=v"(r) : "v"(lo), "v"(hi));
    return r;
}

__device__ __forceinline__ uint4 pack8(float4 a, float4 b) {
    uint4 r;
    r.x = cvt_pk(a.x, a.y); r.y = cvt_pk(a.z, a.w);
    r.z = cvt_pk(b.x, b.y); r.w = cvt_pk(b.z, b.w);
    return r;
}

__device__ __forceinline__ bf16x8 load8_cvt(const float* __restrict__ p) {
    return __builtin_bit_cast(bf16x8, pack8(((const float4*)p)[0], ((const float4*)p)[1]));
}

__device__ __forceinline__ bf16x8 load8_cvt_s(const float* __restrict__ p, float s) {
    float4 a = ((const float4*)p)[0];
    float4 b = ((const float4*)p)[1];
    a.x*=s; a.y*=s; a.z*=s; a.w*=s;
    b.x*=s; b.y*=s; b.z*=s; b.w*=s;
    return __builtin_bit_cast(bf16x8, pack8(a, b));
}

__device__ __forceinline__ short f2b(float f) {
    union { float f; unsigned u; } v; v.f = f;
    return (short)((v.u + 0x7FFFu + ((v.u >> 16) & 1u)) >> 16);
}

// base-2 gate functions (inputs pre-scaled by log2e / 2*log2e)
__device__ __forceinline__ float sigm2(float xp) {
    return __builtin_amdgcn_rcpf(1.f + __builtin_amdgcn_exp2f(-xp));
}
__device__ __forceinline__ float tanh2(float yp) {
    return 1.f - 2.f * __builtin_amdgcn_rcpf(1.f + __builtin_amdgcn_exp2f(yp));
}

// 16-lane all-reduce sum via DPP (VALU pipe)
#define DPP_ADD(v, ctrl)                                                     \
    v += __builtin_bit_cast(float, __builtin_amdgcn_mov_dpp(                 \
             __builtin_bit_cast(int, v), ctrl, 0xF, 0xF, true))

__device__ __forceinline__ float red16(float v) {
    DPP_ADD(v, 0xB1);
    DPP_ADD(v, 0x4E);
    DPP_ADD(v, 0x124);
    DPP_ADD(v, 0x128);
    return v;
}

// ===========================================================================
// Fused kernel: 512 threads = 8 waves.
//  blocks [0,F): wave-specialized GRU (waves 0-3) + loc/sc heads (waves 4-7).
//    gx computed in-kernel per tile (W_ih loaded into the SAME wf registers,
//    then overwritten with W_hh). x staged by heads waves, h0 by GRU waves.
//    Heads traj stores deferred one step so barrier vmcnt drain is free.
//  blocks [F,..): pi head, two independent 256-thread groups per block.
// ===========================================================================
#define HB0 0
#define HB1 8704
#define PI_INBF_OFF   0
#define PI_H1_OFF     33792
#define PI_REDL_OFF   51200
#define PI_RED3_OFF   53248
#define SM_BYTES      54272

__global__ __launch_bounds__(512, 2) void fused_kernel(
    const float* __restrict__ local_embed, const float* __restrict__ global_embed,
    const float* __restrict__ W_ih, const float* __restrict__ W_hh,
    const float* __restrict__ b_ih, const float* __restrict__ b_hh,
    int ntiles, int F,
    const float* __restrict__ loc1_w, const float* __restrict__ loc1_b,
    const float* __restrict__ loc_ln_g, const float* __restrict__ loc_ln_b,
    const float* __restrict__ loc2_w, const float* __restrict__ loc2_b,
    const float* __restrict__ sc1_w, const float* __restrict__ sc1_b,
    const float* __restrict__ sc_ln_g, const float* __restrict__ sc_ln_b,
    const float* __restrict__ sc2_w, const float* __restrict__ sc2_b,
    float* __restrict__ traj,
    const float* __restrict__ pi1_w, const float* __restrict__ pi1_b,
    const float* __restrict__ ln1_g, const float* __restrict__ ln1_b,
    const float* __restrict__ pi2_w, const float* __restrict__ pi2_b,
    const float* __restrict__ ln2_g, const float* __restrict__ ln2_b,
    const float* __restrict__ pi3_w, const float* __restrict__ pi3_b,
    float* __restrict__ pi_out)
{
    __shared__ __align__(16) char smraw[SM_BYTES];

    const int tid = threadIdx.x;
    const int w  = tid >> 6;          // wave 0..7
    const int l  = tid & 63;
    const int ln = l & 15;
    const int lg = l >> 4;

    if ((int)blockIdx.x < F) {
        if (w < 4) {
            // ================= GRU waves =================
            float bias_ih[3][2], bhn[2];
            #pragma unroll
            for (int u = 0; u < 2; ++u) {
                const int c = 32*w + 16*u + ln;
                bhn[u] = b_hh[2*H + c] * (2.f * LOG2E);
                #pragma unroll
                for (int g = 0; g < 3; ++g) {
                    const float sc = (g < 2) ? LOG2E : (2.f * LOG2E);
                    bias_ih[g][u] = (b_ih[g*H + c] + (g < 2 ? b_hh[g*H + c] : 0.f)) * sc;
                }
            }
            const int ro = ln*272 + lg*16;                 // af read base (per grp:+4352, per kt:+64)
            const int wb = (lg*4)*272 + (32*w + ln)*2;     // h write base
            const int sr_ = tid >> 3;                      // staging row 0..31
            const int ssg = tid & 7;

            bf16x8 wf[3][2][4];

            for (int it = blockIdx.x; it < ntiles; it += F) {
                const int lb0 = it * 32;
                __syncthreads();                           // B-top

                // stage h0 -> hb0
                {
                    const int n = (lb0 + sr_) & (N_AG - 1);
                    const float* src = local_embed + (size_t)n * H;
                    #pragma unroll
                    for (int hseg = 0; hseg < 2; ++hseg) {
                        const int s8 = ssg + hseg*8;
                        const float4 a = ((const float4*)(src + s8*8))[0];
                        const float4 c = ((const float4*)(src + s8*8))[1];
                        *(uint4*)(smraw + HB0 + sr_*272 + s8*16) = pack8(a, c);
                    }
                }

                // f32 master h0
                float h_reg[2][2][4];
                #pragma unroll
                for (int grp = 0; grp < 2; ++grp)
                    #pragma unroll
                    for (int u = 0; u < 2; ++u) {
                        const int j = 32*w + 16*u + ln;
                        #pragma unroll
                        for (int rg = 0; rg < 4; ++rg) {
                            const int n = (lb0 + grp*16 + lg*4 + rg) & (N_AG - 1);
                            h_reg[grp][u][rg] = local_embed[(size_t)n * H + j];
                        }
                    }

                // W_ih fragments (scaled) into wf
                #pragma unroll
                for (int u = 0; u < 2; ++u)
                    #pragma unroll
                    for (int g = 0; g < 3; ++g) {
                        const int crow = g*H + 32*w + 16*u + ln;
                        const float sc = (g < 2) ? LOG2E : (2.f * LOG2E);
                        #pragma unroll
                        for (int kt = 0; kt < 4; ++kt)
                            wf[g][u][kt] = load8_cvt_s(W_ih + (size_t)crow * I_DIM + kt*32 + lg*8, sc);
                    }
                __syncthreads();                           // B-stage (x,h0 staged)

                // gx = x @ W_ih^T (+bias)
                float gx[2][3][2][4];
                #pragma unroll
                for (int grp = 0; grp < 2; ++grp) {
                    bf16x8 ax[4];
                    #pragma unroll
                    for (int kt = 0; kt < 4; ++kt)
                        ax[kt] = *(const bf16x8*)(smraw + HB1 + ro + grp*4352 + kt*64);
                    f32x4 ag[3][2];
                    #pragma unroll
                    for (int g = 0; g < 3; ++g)
                        #pragma unroll
                        for (int u = 0; u < 2; ++u) ag[g][u] = (f32x4)(0.f);
                    #pragma unroll
                    for (int kt = 0; kt < 4; ++kt)
                        #pragma unroll
                        for (int g = 0; g < 3; ++g)
                            #pragma unroll
                            for (int u = 0; u < 2; ++u)
                                ag[g][u] = MFMA16x16x32(ax[kt], wf[g][u][kt], ag[g][u]);
                    #pragma unroll
                    for (int g = 0; g < 3; ++g)
                        #pragma unroll
                        for (int u = 0; u < 2; ++u)
                            #pragma unroll
                            for (int rg = 0; rg < 4; ++rg)
                                gx[grp][g][u][rg] = ag[g][u][rg] + bias_ih[g][u];
                }

                // overwrite wf with W_hh fragments (scaled)
                #pragma unroll
                for (int u = 0; u < 2; ++u)
                    #pragma unroll
                    for (int g = 0; g < 3; ++g) {
                        const int crow = g*H + 32*w + 16*u + ln;
                        const float sc = (g < 2) ? LOG2E : (2.f * LOG2E);
                        #pragma unroll
                        for (int kt = 0; kt < 4; ++kt)
                            wf[g][u][kt] = load8_cvt_s(W_hh + (size_t)crow * H + kt*32 + lg*8, sc);
                    }
                __syncthreads();                           // B-gx (hb1 free now)

                int rd_off = HB0, wr_off = HB1;
                for (int i = 0; i <= T_STEPS; ++i) {
                    if (i < T_STEPS) {
                        #pragma unroll
                        for (int grp = 0; grp < 2; ++grp) {
                            bf16x8 af[4];
                            #pragma unroll
                            for (int kt = 0; kt < 4; ++kt)
                                af[kt] = *(const bf16x8*)(smraw + rd_off + ro + grp*4352 + kt*64);

                            f32x4 ga[3][2];
                            #pragma unroll
                            for (int g = 0; g < 3; ++g)
                                #pragma unroll
                                for (int u = 0; u < 2; ++u) ga[g][u] = (f32x4)(0.f);
                            #pragma unroll
                            for (int kt = 0; kt < 4; ++kt)
                                #pragma unroll
                                for (int g = 0; g < 3; ++g)
                                    #pragma unroll
                                    for (int u = 0; u < 2; ++u)
                                        ga[g][u] = MFMA16x16x32(af[kt], wf[g][u][kt], ga[g][u]);

                            #pragma unroll
                            for (int u = 0; u < 2; ++u) {
                                float hv[4];
                                #pragma unroll
                                for (int rg = 0; rg < 4; ++rg) {
                                    const float rr = sigm2(gx[grp][0][u][rg] + ga[0][u][rg]);
                                    const float zz = sigm2(gx[grp][1][u][rg] + ga[1][u][rg]);
                                    const float nn = tanh2(gx[grp][2][u][rg] + rr * (ga[2][u][rg] + bhn[u]));
                                    const float h  = nn + zz * (h_reg[grp][u][rg] - nn);
                                    h_reg[grp][u][rg] = h;
                                    hv[rg] = h;
                                }
                                const unsigned p0 = cvt_pk(hv[0], hv[1]);
                                const unsigned p1 = cvt_pk(hv[2], hv[3]);
                                const int wa = wr_off + wb + grp*4352 + u*32;
                                *(short*)(smraw + wa)        = (short)p0;
                                *(short*)(smraw + wa + 272)  = (short)(p0 >> 16);
                                *(short*)(smraw + wa + 544)  = (short)p1;
                                *(short*)(smraw + wa + 816)  = (short)(p1 >> 16);
                            }
                        }
                    }
                    __syncthreads();                       // B-step
                    rd_off ^= 8704; wr_off ^= 8704;
                }
            }
        } else {
            // ================= heads waves =================
            const int hw = w - 4;
            const int hd = hw & 1;                 // 0 = loc, 1 = sc
            const int mrow = (hw >> 1) * 16;

            const float* __restrict__ W1  = hd ? sc1_w   : loc1_w;
            const float* __restrict__ B1v = hd ? sc1_b   : loc1_b;
            const float* __restrict__ Gv  = hd ? sc_ln_g : loc_ln_g;
            const float* __restrict__ Bv  = hd ? sc_ln_b : loc_ln_b;
            const float* __restrict__ W2  = hd ? sc2_w   : loc2_w;
            const float* __restrict__ B2v = hd ? sc2_b   : loc2_b;

            bf16x8 whf[8][4];
            float bias1[8], lng[8], lnb[8], w2a[8], w2b[8];
            #pragma unroll
            for (int nt = 0; nt < 8; ++nt) {
                const int c = 16*nt + ln;
                #pragma unroll
                for (int kt = 0; kt < 4; ++kt)
                    whf[nt][kt] = load8_cvt(W1 + (size_t)c * H + kt*32 + lg*8);
                bias1[nt] = B1v[c]; lng[nt] = Gv[c]; lnb[nt] = Bv[c];
                w2a[nt] = W2[c];    w2b[nt] = W2[H + c];
            }
            const float b2_0 = B2v[0], b2_1 = B2v[1];
            const int ho = (mrow + ln)*272 + lg*16;
            const int sr_ = (tid - 256) >> 3;      // 0..31
            const int ssg = tid & 7;

            for (int it = blockIdx.x; it < ntiles; it += F) {
                const int lb0 = it * 32;
                __syncthreads();                           // B-top

                // stage x -> hb1
                {
                    const float* src = global_embed + (size_t)(lb0 + sr_) * I_DIM;
                    #pragma unroll
                    for (int hseg = 0; hseg < 2; ++hseg) {
                        const int s8 = ssg + hseg*8;
                        const float4 a = ((const float4*)(src + s8*8))[0];
                        const float4 c = ((const float4*)(src + s8*8))[1];
                        *(uint4*)(smraw + HB1 + sr_*272 + s8*16) = pack8(a, c);
                    }
                }
                __syncthreads();                           // B-stage
                __syncthreads();                           // B-gx

                int rd_off = HB0;
                float2 pend[4];
                for (int i = 0; i <= T_STEPS; ++i) {
                    // flush previous step's outputs (retires under this step)
                    if (i >= 2 && ln == 0) {
                        #pragma unroll
                        for (int rg = 0; rg < 4; ++rg) {
                            const int b = lb0 + mrow + lg*4 + rg;
                            *(float2*)(traj + ((size_t)b * T_STEPS + (i - 2)) * 4 + hd*2) = pend[rg];
                        }
                    }
                    if (i >= 1) {
                        bf16x8 af[4];
                        #pragma unroll
                        for (int kt = 0; kt < 4; ++kt)
                            af[kt] = *(const bf16x8*)(smraw + rd_off + ho + kt*64);

                        f32x4 acc[8];
                        #pragma unroll
                        for (int nt = 0; nt < 8; ++nt) acc[nt] = (f32x4)(0.f);
                        #pragma unroll
                        for (int kt = 0; kt < 4; ++kt)
                            #pragma unroll
                            for (int nt = 0; nt < 8; ++nt)
                                acc[nt] = MFMA16x16x32(af[kt], whf[nt][kt], acc[nt]);

                        #pragma unroll
                        for (int rg = 0; rg < 4; ++rg) {
                            float s = 0.f, q = 0.f;
                            #pragma unroll
                            for (int nt = 0; nt < 8; ++nt) {
                                const float a = acc[nt][rg] + bias1[nt];
                                acc[nt][rg] = a;
                                s += a; q += a*a;
                            }
                            s = red16(s);
                            q = red16(q);
                            const float mu = s * (1.f/H);
                            const float var = q * (1.f/H) - mu*mu;
                            const float rs = rsqrtf(var + LN_EPS);
                            const float murs = mu * rs;
                            float p0 = 0.f, p1 = 0.f;
                            #pragma unroll
                            for (int nt = 0; nt < 8; ++nt) {
                                float v = fmaf(fmaf(acc[nt][rg], rs, -murs), lng[nt], lnb[nt]);
                                v = fmaxf(v, 0.f);
                                p0 = fmaf(v, w2a[nt], p0);
                                p1 = fmaf(v, w2b[nt], p1);
                            }
                            p0 = red16(p0);
                            p1 = red16(p1);
                            float v0 = p0 + b2_0;
                            float v1 = p1 + b2_1;
                            if (hd) {
                                v0 = (v0 > 0.f ? v0 : expm1f(v0)) + 1.0f + MIN_SCALE;
                                v1 = (v1 > 0.f ? v1 : expm1f(v1)) + 1.0f + MIN_SCALE;
                            }
                            pend[rg] = make_float2(v0, v1);
                        }
                    }
                    __syncthreads();                       // B-step
                    rd_off ^= 8704;
                }
                // final flush (t = 29)
                if (ln == 0) {
                    #pragma unroll
                    for (int rg = 0; rg < 4; ++rg) {
                        const int b = lb0 + mrow + lg*4 + rg;
                        *(float2*)(traj + ((size_t)b * T_STEPS + (T_STEPS - 1)) * 4 + hd*2) = pend[rg];
                    }
                }
            }
        }
        return;
    }

    // ================= pi path (2 x 256-thread groups) =================
    {
        const int pbid = blockIdx.x - F;
        const int pgrid = gridDim.x - F;
        const int sub  = tid >> 8;
        const int stid = tid & 255;
        const int w4 = stid >> 6;

        short (*inbf)[264] = (short(*)[264])(smraw + PI_INBF_OFF + (size_t)sub*16896);
        short (*h1bf)[136] = (short(*)[136])(smraw + PI_H1_OFF   + (size_t)sub*8704);
        float (*redL)[32][2] = (float(*)[32][2])(smraw + PI_REDL_OFF + (size_t)sub*1024);
        float (*red3)[32]    = (float(*)[32])(smraw + PI_RED3_OFF + (size_t)sub*512);

        bf16x8 wf1[2][8];
        bf16x8 wf2[2][4];
        float b1[2], g1[2], bb1[2], b2[2], g2[2], bb2[2], w3[2];
        #pragma unroll
        for (int nt = 0; nt < 2; ++nt) {
            const int c = 32*w4 + 16*nt + ln;
            #pragma unroll
            for (int kt = 0; kt < 8; ++kt)
                wf1[nt][kt] = load8_cvt(pi1_w + (size_t)c * (2*H) + kt*32 + lg*8);
            #pragma unroll
            for (int kt = 0; kt < 4; ++kt)
                wf2[nt][kt] = load8_cvt(pi2_w + (size_t)c * H + kt*32 + lg*8);
            b1[nt] = pi1_b[c]; g1[nt] = ln1_g[c]; bb1[nt] = ln1_b[c];
            b2[nt] = pi2_b[c]; g2[nt] = ln2_g[c]; bb2[nt] = ln2_b[c];
            w3[nt] = pi3_w[c];
        }
        const float b3 = pi3_b[0];

        const int npairs = (B_TOT / 32) / 2;

        for (int p = pbid; p < npairs; p += pgrid) {
            const int r0 = (p*2 + sub) * 32;
            {
                const int r   = stid >> 3;
                const int seg = stid & 7;
                const int b = r0 + r;
                const int n = b & (N_AG - 1);
                const float* src = (seg < 4) ? (local_embed + (size_t)n * H + seg * 32)
                                             : (global_embed + (size_t)b * I_DIM + (seg - 4) * 32);
                #pragma unroll
                for (int i = 0; i < 4; ++i) {
                    const float4 a = ((const float4*)src)[2*i];
                    const float4 c = ((const float4*)src)[2*i+1];
                    *(uint4*)&inbf[r][seg*32 + i*8] = pack8(a, c);
                }
            }
            __syncthreads();

            f32x4 acc1[2][2];
            #pragma unroll
            for (int m = 0; m < 2; ++m) {
                #pragma unroll
                for (int nt = 0; nt < 2; ++nt) acc1[m][nt] = (f32x4)(0.f);
                bf16x8 af[8];
                #pragma unroll
                for (int kt = 0; kt < 8; ++kt)
                    af[kt] = *(const bf16x8*)&inbf[m*16 + ln][kt*32 + lg*8];
                #pragma unroll
                for (int kt = 0; kt < 8; ++kt)
                    #pragma unroll
                    for (int nt = 0; nt < 2; ++nt)
                        acc1[m][nt] = MFMA16x16x32(af[kt], wf1[nt][kt], acc1[m][nt]);
            }

            #pragma unroll
            for (int m = 0; m < 2; ++m)
                #pragma unroll
                for (int rg = 0; rg < 4; ++rg) {
                    float s = 0.f, q = 0.f;
                    #pragma unroll
                    for (int nt = 0; nt < 2; ++nt) {
                        const float a = acc1[m][nt][rg] + b1[nt];
                        acc1[m][nt][rg] = a;
                        s += a; q += a*a;
                    }
                    s = red16(s);
                    q = red16(q);
                    if (ln == 0) {
                        const int row = m*16 + lg*4 + rg;
                        redL[w4][row][0] = s;
                        redL[w4][row][1] = q;
                    }
                }
            __syncthreads();

            #pragma unroll
            for (int m = 0; m < 2; ++m)
                #pragma unroll
                for (int rg = 0; rg < 4; ++rg) {
                    const int row = m*16 + lg*4 + rg;
                    const float S = redL[0][row][0] + redL[1][row][0] + redL[2][row][0] + redL[3][row][0];
                    const float Q = redL[0][row][1] + redL[1][row][1] + redL[2][row][1] + redL[3][row][1];
                    const float mu = S * (1.f/H);
                    const float var = Q * (1.f/H) - mu*mu;
                    const float rs = rsqrtf(var + LN_EPS);
                    #pragma unroll
                    for (int nt = 0; nt < 2; ++nt) {
                        const float v = fmaxf((acc1[m][nt][rg] - mu) * rs * g1[nt] + bb1[nt], 0.f);
                        h1bf[row][32*w4 + 16*nt + ln] = f2b(v);
                    }
                }
            __syncthreads();

            f32x4 acc2[2][2];
            #pragma unroll
            for (int m = 0; m < 2; ++m) {
                #pragma unroll
                for (int nt = 0; nt < 2; ++nt) acc2[m][nt] = (f32x4)(0.f);
                bf16x8 af[4];
                #pragma unroll
                for (int kt = 0; kt < 4; ++kt)
                    af[kt] = *(const bf16x8*)&h1bf[m*16 + ln][kt*32 + lg*8];
                #pragma unroll
                for (int kt = 0; kt < 4; ++kt)
                    #pragma unroll
                    for (int nt = 0; nt < 2; ++nt)
                        acc2[m][nt] = MFMA16x16x32(af[kt], wf2[nt][kt], acc2[m][nt]);
            }

            #pragma unroll
            for (int m = 0; m < 2; ++m)
                #pragma unroll
                for (int rg = 0; rg < 4; ++rg) {
                    float s = 0.f, q = 0.f;
                    #pragma unroll
                    for (int nt = 0; nt < 2; ++nt) {
                        const float a = acc2[m][nt][rg] + b2[nt];
                        acc2[m][nt][rg] = a;
                        s += a; q += a*a;
                    }
                    s = red16(s);
                    q = red16(q);
                    if (ln == 0) {
                        const int row = m*16 + lg*4 + rg;
                        redL[w4][row][0] = s;
                        redL[w4][row][1] = q;
                    }
                }
            __syncthreads();

            #pragma unroll
            for (int m = 0; m < 2; ++m)
                #pragma unroll
                for (int rg = 0; rg < 4; ++rg) {
                    const int row = m*16 + lg*4 + rg;
                    const float S = redL[0][row][0] + redL[1][row][0] + redL[2][row][0] + redL[3][row][0];
                    const float Q = redL[0][row][1] + redL[1][row][1] + redL[2][row][1] + redL[3][row][1];
                    const float mu = S * (1.f/H);
                    const float var = Q * (1.f/H) - mu*mu;
                    const float rs = rsqrtf(var + LN_EPS);
                    float p2 = 0.f;
                    #pragma unroll
                    for (int nt = 0; nt < 2; ++nt) {
                        const float v = fmaxf((acc2[m][nt][rg] - mu) * rs * g2[nt] + bb2[nt], 0.f);
                        p2 = fmaf(v, w3[nt], p2);
                    }
                    p2 = red16(p2);
                    if (ln == 0) red3[w4][row] = p2;
                }
            __syncthreads();

            if (stid < 32) {
                const int row = stid;
                const float pv = red3[0][row] + red3[1][row] + red3[2][row] + red3[3][row] + b3;
                const int b = r0 + row;
                const int n = b & (N_AG - 1);
                const int m = b >> 13;
                pi_out[(size_t)n * M_MODES + m] = pv;
            }
            __syncthreads();
        }
    }
}

extern "C" void kernel_launch(void* const* d_in, const int* in_sizes, int n_in,
                              void* d_out, int out_size, void* d_ws, size_t ws_size,
                              hipStream_t stream) {
    (void)in_sizes; (void)n_in; (void)out_size; (void)d_ws; (void)ws_size;
    const float* local_embed  = (const float*)d_in[0];
    const float* global_embed = (const float*)d_in[1];
    const float* W_ih   = (const float*)d_in[2];
    const float* W_hh   = (const float*)d_in[3];
    const float* b_ih   = (const float*)d_in[4];
    const float* b_hh   = (const float*)d_in[5];
    const float* loc1_w = (const float*)d_in[6];
    const float* loc1_b = (const float*)d_in[7];
    const float* loc_ln_g = (const float*)d_in[8];
    const float* loc_ln_b = (const float*)d_in[9];
    const float* loc2_w = (const float*)d_in[10];
    const float* loc2_b = (const float*)d_in[11];
    const float* sc1_w  = (const float*)d_in[12];
    const float* sc1_b  = (const float*)d_in[13];
    const float* sc_ln_g = (const float*)d_in[14];
    const float* sc_ln_b = (const float*)d_in[15];
    const float* sc2_w  = (const float*)d_in[16];
    const float* sc2_b  = (const float*)d_in[17];
    const float* pi1_w  = (const float*)d_in[18];
    const float* pi1_b  = (const float*)d_in[19];
    const float* pi_ln1_g = (const float*)d_in[20];
    const float* pi_ln1_b = (const float*)d_in[21];
    const float* pi2_w  = (const float*)d_in[22];
    const float* pi2_b  = (const float*)d_in[23];
    const float* pi_ln2_g = (const float*)d_in[24];
    const float* pi_ln2_b = (const float*)d_in[25];
    const float* pi3_w  = (const float*)d_in[26];
    const float* pi3_b  = (const float*)d_in[27];

    float* traj = (float*)d_out;
    float* pi_out = traj + (size_t)B_TOT * T_STEPS * 4;

    const int ntiles = B_TOT / 32;   // 1536
    const int F = 768;               // 2 tiles per fused block
    const int P = 256;               // pi blocks

    fused_kernel<<<F + P, 512, 0, stream>>>(
        local_embed, global_embed, W_ih, W_hh, b_ih, b_hh,
        ntiles, F,
        loc1_w, loc1_b, loc_ln_g, loc_ln_b, loc2_w, loc2_b,
        sc1_w, sc1_b, sc_ln_g, sc_ln_b, sc2_w, sc2_b, traj,
        pi1_w, pi1_b, pi_ln1_g, pi_ln1_b,
        pi2_w, pi2_b, pi_ln2_g, pi_ln2_b, pi3_w, pi3_b, pi_out);
}

// Round 14
// 516.823 us; speedup vs baseline: 3.0786x; 1.0994x over previous
//
#include <hip/hip_runtime.h>
#include <math.h>

#define H 128
#define I_DIM 128
#define T_STEPS 30
#define M_MODES 6
#define N_AG 8192
#define B_TOT (M_MODES * N_AG)   /* 49152 */
#define LN_EPS 1e-5f
#define MIN_SCALE 0.001f
#define LOG2E 1.44269504088896f

typedef short bf16x8 __attribute__((ext_vector_type(8)));
typedef float f32x4 __attribute__((ext_vector_type(4)));

#define MFMA16x16x32(A, B, C) __builtin_amdgcn_mfma_f32_16x16x32_bf16(A, B, C, 0, 0, 0)

__device__ __forceinline__ unsigned cvt_pk(float lo, float hi) {
    unsigned r;
    asm("v_cvt_pk_bf16_f32 %0, %1, %2" : "=v"(r) : "v"(lo), "v"(hi));
    return r;
}

__device__ __forceinline__ uint4 pack8(float4 a, float4 b) {
    uint4 r;
    r.x = cvt_pk(a.x, a.y); r.y = cvt_pk(a.z, a.w);
    r.z = cvt_pk(b.x, b.y); r.w = cvt_pk(b.z, b.w);
    return r;
}

__device__ __forceinline__ bf16x8 load8_cvt(const float* __restrict__ p) {
    return __builtin_bit_cast(bf16x8, pack8(((const float4*)p)[0], ((const float4*)p)[1]));
}

__device__ __forceinline__ bf16x8 load8_cvt_s(const float* __restrict__ p, float s) {
    float4 a = ((const float4*)p)[0];
    float4 b = ((const float4*)p)[1];
    a.x*=s; a.y*=s; a.z*=s; a.w*=s;
    b.x*=s; b.y*=s; b.z*=s; b.w*=s;
    return __builtin_bit_cast(bf16x8, pack8(a, b));
}

__device__ __forceinline__ short f2b(float f) {
    union { float f; unsigned u; } v; v.f = f;
    return (short)((v.u + 0x7FFFu + ((v.u >> 16) & 1u)) >> 16);
}

// base-2 gate functions (inputs pre-scaled by log2e / 2*log2e)
__device__ __forceinline__ float sigm2(float xp) {
    return __builtin_amdgcn_rcpf(1.f + __builtin_amdgcn_exp2f(-xp));
}
__device__ __forceinline__ float tanh2(float yp) {
    return 1.f - 2.f * __builtin_amdgcn_rcpf(1.f + __builtin_amdgcn_exp2f(yp));
}

// elu(v)+1+MIN_SCALE, cheap: v>0 ? v+1+MIN : exp2(v*log2e)+MIN
__device__ __forceinline__ float elu1(float v) {
    return v > 0.f ? (v + (1.0f + MIN_SCALE))
                   : (__builtin_amdgcn_exp2f(v * LOG2E) + MIN_SCALE);
}

// 16-lane all-reduce sum via DPP (VALU pipe)
#define DPP_ADD(v, ctrl)                                                     \
    v += __builtin_bit_cast(float, __builtin_amdgcn_mov_dpp(                 \
             __builtin_bit_cast(int, v), ctrl, 0xF, 0xF, true))

__device__ __forceinline__ float red16(float v) {
    DPP_ADD(v, 0xB1);
    DPP_ADD(v, 0x4E);
    DPP_ADD(v, 0x124);
    DPP_ADD(v, 0x128);
    return v;
}

// ===========================================================================
// Single fused kernel: 768 blocks x 512 threads (8 waves).
//  Phase 1 (per block, 2 tiles): wave-specialized GRU (waves 0-3) +
//    loc/sc heads (waves 4-7); gx in-kernel (W_ih -> same wf regs -> W_hh);
//    h through double-buffered LDS; deferred traj stores.
//  Phase 2 (per block, 1 pi pair): pi head, 2 x 256-thread groups.
// ===========================================================================
#define HB0 0
#define HB1 8704
#define PI_INBF_OFF   0
#define PI_H1_OFF     33792
#define PI_REDL_OFF   51200
#define PI_RED3_OFF   53248
#define SM_BYTES      54272

__global__ __launch_bounds__(512, 2) void fused_kernel(
    const float* __restrict__ local_embed, const float* __restrict__ global_embed,
    const float* __restrict__ W_ih, const float* __restrict__ W_hh,
    const float* __restrict__ b_ih, const float* __restrict__ b_hh,
    int ntiles, int F,
    const float* __restrict__ loc1_w, const float* __restrict__ loc1_b,
    const float* __restrict__ loc_ln_g, const float* __restrict__ loc_ln_b,
    const float* __restrict__ loc2_w, const float* __restrict__ loc2_b,
    const float* __restrict__ sc1_w, const float* __restrict__ sc1_b,
    const float* __restrict__ sc_ln_g, const float* __restrict__ sc_ln_b,
    const float* __restrict__ sc2_w, const float* __restrict__ sc2_b,
    float* __restrict__ traj,
    const float* __restrict__ pi1_w, const float* __restrict__ pi1_b,
    const float* __restrict__ ln1_g, const float* __restrict__ ln1_b,
    const float* __restrict__ pi2_w, const float* __restrict__ pi2_b,
    const float* __restrict__ ln2_g, const float* __restrict__ ln2_b,
    const float* __restrict__ pi3_w, const float* __restrict__ pi3_b,
    float* __restrict__ pi_out)
{
    __shared__ __align__(16) char smraw[SM_BYTES];

    const int tid = threadIdx.x;
    const int w  = tid >> 6;          // wave 0..7
    const int l  = tid & 63;
    const int ln = l & 15;
    const int lg = l >> 4;

    // ======================= Phase 1: GRU + heads =======================
    if (w < 4) {
        // ================= GRU waves =================
        float bias_ih[3][2], bhn[2];
        #pragma unroll
        for (int u = 0; u < 2; ++u) {
            const int c = 32*w + 16*u + ln;
            bhn[u] = b_hh[2*H + c] * (2.f * LOG2E);
            #pragma unroll
            for (int g = 0; g < 3; ++g) {
                const float sc = (g < 2) ? LOG2E : (2.f * LOG2E);
                bias_ih[g][u] = (b_ih[g*H + c] + (g < 2 ? b_hh[g*H + c] : 0.f)) * sc;
            }
        }
        const int ro = ln*272 + lg*16;
        const int wb = (lg*4)*272 + (32*w + ln)*2;
        const int sr_ = tid >> 3;
        const int ssg = tid & 7;

        bf16x8 wf[3][2][4];

        for (int it = blockIdx.x; it < ntiles; it += F) {
            const int lb0 = it * 32;
            __syncthreads();                           // B-top

            // stage h0 -> hb0
            {
                const int n = (lb0 + sr_) & (N_AG - 1);
                const float* src = local_embed + (size_t)n * H;
                #pragma unroll
                for (int hseg = 0; hseg < 2; ++hseg) {
                    const int s8 = ssg + hseg*8;
                    const float4 a = ((const float4*)(src + s8*8))[0];
                    const float4 c = ((const float4*)(src + s8*8))[1];
                    *(uint4*)(smraw + HB0 + sr_*272 + s8*16) = pack8(a, c);
                }
            }

            float h_reg[2][2][4];
            #pragma unroll
            for (int grp = 0; grp < 2; ++grp)
                #pragma unroll
                for (int u = 0; u < 2; ++u) {
                    const int j = 32*w + 16*u + ln;
                    #pragma unroll
                    for (int rg = 0; rg < 4; ++rg) {
                        const int n = (lb0 + grp*16 + lg*4 + rg) & (N_AG - 1);
                        h_reg[grp][u][rg] = local_embed[(size_t)n * H + j];
                    }
                }

            // W_ih fragments (scaled) into wf
            #pragma unroll
            for (int u = 0; u < 2; ++u)
                #pragma unroll
                for (int g = 0; g < 3; ++g) {
                    const int crow = g*H + 32*w + 16*u + ln;
                    const float sc = (g < 2) ? LOG2E : (2.f * LOG2E);
                    #pragma unroll
                    for (int kt = 0; kt < 4; ++kt)
                        wf[g][u][kt] = load8_cvt_s(W_ih + (size_t)crow * I_DIM + kt*32 + lg*8, sc);
                }
            __syncthreads();                           // B-stage

            // gx = x @ W_ih^T (+bias)
            float gx[2][3][2][4];
            #pragma unroll
            for (int grp = 0; grp < 2; ++grp) {
                bf16x8 ax[4];
                #pragma unroll
                for (int kt = 0; kt < 4; ++kt)
                    ax[kt] = *(const bf16x8*)(smraw + HB1 + ro + grp*4352 + kt*64);
                f32x4 ag[3][2];
                #pragma unroll
                for (int g = 0; g < 3; ++g)
                    #pragma unroll
                    for (int u = 0; u < 2; ++u) ag[g][u] = (f32x4)(0.f);
                #pragma unroll
                for (int kt = 0; kt < 4; ++kt)
                    #pragma unroll
                    for (int g = 0; g < 3; ++g)
                        #pragma unroll
                        for (int u = 0; u < 2; ++u)
                            ag[g][u] = MFMA16x16x32(ax[kt], wf[g][u][kt], ag[g][u]);
                #pragma unroll
                for (int g = 0; g < 3; ++g)
                    #pragma unroll
                    for (int u = 0; u < 2; ++u)
                        #pragma unroll
                        for (int rg = 0; rg < 4; ++rg)
                            gx[grp][g][u][rg] = ag[g][u][rg] + bias_ih[g][u];
            }

            // overwrite wf with W_hh fragments (scaled)
            #pragma unroll
            for (int u = 0; u < 2; ++u)
                #pragma unroll
                for (int g = 0; g < 3; ++g) {
                    const int crow = g*H + 32*w + 16*u + ln;
                    const float sc = (g < 2) ? LOG2E : (2.f * LOG2E);
                    #pragma unroll
                    for (int kt = 0; kt < 4; ++kt)
                        wf[g][u][kt] = load8_cvt_s(W_hh + (size_t)crow * H + kt*32 + lg*8, sc);
                }
            __syncthreads();                           // B-gx

            int rd_off = HB0, wr_off = HB1;
            for (int i = 0; i <= T_STEPS; ++i) {
                if (i < T_STEPS) {
                    #pragma unroll
                    for (int grp = 0; grp < 2; ++grp) {
                        bf16x8 af[4];
                        #pragma unroll
                        for (int kt = 0; kt < 4; ++kt)
                            af[kt] = *(const bf16x8*)(smraw + rd_off + ro + grp*4352 + kt*64);

                        f32x4 ga[3][2];
                        #pragma unroll
                        for (int g = 0; g < 3; ++g)
                            #pragma unroll
                            for (int u = 0; u < 2; ++u) ga[g][u] = (f32x4)(0.f);
                        #pragma unroll
                        for (int kt = 0; kt < 4; ++kt)
                            #pragma unroll
                            for (int g = 0; g < 3; ++g)
                                #pragma unroll
                                for (int u = 0; u < 2; ++u)
                                    ga[g][u] = MFMA16x16x32(af[kt], wf[g][u][kt], ga[g][u]);

                        #pragma unroll
                        for (int u = 0; u < 2; ++u) {
                            float hv[4];
                            #pragma unroll
                            for (int rg = 0; rg < 4; ++rg) {
                                const float rr = sigm2(gx[grp][0][u][rg] + ga[0][u][rg]);
                                const float zz = sigm2(gx[grp][1][u][rg] + ga[1][u][rg]);
                                const float nn = tanh2(gx[grp][2][u][rg] + rr * (ga[2][u][rg] + bhn[u]));
                                const float h  = nn + zz * (h_reg[grp][u][rg] - nn);
                                h_reg[grp][u][rg] = h;
                                hv[rg] = h;
                            }
                            const unsigned p0 = cvt_pk(hv[0], hv[1]);
                            const unsigned p1 = cvt_pk(hv[2], hv[3]);
                            const int wa = wr_off + wb + grp*4352 + u*32;
                            *(short*)(smraw + wa)        = (short)p0;
                            *(short*)(smraw + wa + 272)  = (short)(p0 >> 16);
                            *(short*)(smraw + wa + 544)  = (short)p1;
                            *(short*)(smraw + wa + 816)  = (short)(p1 >> 16);
                        }
                    }
                }
                __syncthreads();                       // B-step
                rd_off ^= 8704; wr_off ^= 8704;
            }
        }
    } else {
        // ================= heads waves =================
        const int hw = w - 4;
        const int hd = hw & 1;
        const int mrow = (hw >> 1) * 16;

        const float* __restrict__ W1  = hd ? sc1_w   : loc1_w;
        const float* __restrict__ B1v = hd ? sc1_b   : loc1_b;
        const float* __restrict__ Gv  = hd ? sc_ln_g : loc_ln_g;
        const float* __restrict__ Bv  = hd ? sc_ln_b : loc_ln_b;
        const float* __restrict__ W2  = hd ? sc2_w   : loc2_w;
        const float* __restrict__ B2v = hd ? sc2_b   : loc2_b;

        bf16x8 whf[8][4];
        float bias1[8], lng[8], lnb[8], w2a[8], w2b[8];
        #pragma unroll
        for (int nt = 0; nt < 8; ++nt) {
            const int c = 16*nt + ln;
            #pragma unroll
            for (int kt = 0; kt < 4; ++kt)
                whf[nt][kt] = load8_cvt(W1 + (size_t)c * H + kt*32 + lg*8);
            bias1[nt] = B1v[c]; lng[nt] = Gv[c]; lnb[nt] = Bv[c];
            w2a[nt] = W2[c];    w2b[nt] = W2[H + c];
        }
        const float b2_0 = B2v[0], b2_1 = B2v[1];
        const int ho = (mrow + ln)*272 + lg*16;
        const int sr_ = (tid - 256) >> 3;
        const int ssg = tid & 7;

        for (int it = blockIdx.x; it < ntiles; it += F) {
            const int lb0 = it * 32;
            __syncthreads();                           // B-top

            // stage x -> hb1
            {
                const float* src = global_embed + (size_t)(lb0 + sr_) * I_DIM;
                #pragma unroll
                for (int hseg = 0; hseg < 2; ++hseg) {
                    const int s8 = ssg + hseg*8;
                    const float4 a = ((const float4*)(src + s8*8))[0];
                    const float4 c = ((const float4*)(src + s8*8))[1];
                    *(uint4*)(smraw + HB1 + sr_*272 + s8*16) = pack8(a, c);
                }
            }
            __syncthreads();                           // B-stage
            __syncthreads();                           // B-gx

            int rd_off = HB0;
            float2 pend[4];
            for (int i = 0; i <= T_STEPS; ++i) {
                if (i >= 2 && ln == 0) {
                    #pragma unroll
                    for (int rg = 0; rg < 4; ++rg) {
                        const int b = lb0 + mrow + lg*4 + rg;
                        *(float2*)(traj + ((size_t)b * T_STEPS + (i - 2)) * 4 + hd*2) = pend[rg];
                    }
                }
                if (i >= 1) {
                    bf16x8 af[4];
                    #pragma unroll
                    for (int kt = 0; kt < 4; ++kt)
                        af[kt] = *(const bf16x8*)(smraw + rd_off + ho + kt*64);

                    f32x4 acc[8];
                    #pragma unroll
                    for (int nt = 0; nt < 8; ++nt) acc[nt] = (f32x4)(0.f);
                    #pragma unroll
                    for (int kt = 0; kt < 4; ++kt)
                        #pragma unroll
                        for (int nt = 0; nt < 8; ++nt)
                            acc[nt] = MFMA16x16x32(af[kt], whf[nt][kt], acc[nt]);

                    #pragma unroll
                    for (int rg = 0; rg < 4; ++rg) {
                        float s = 0.f, q = 0.f;
                        #pragma unroll
                        for (int nt = 0; nt < 8; ++nt) {
                            const float a = acc[nt][rg] + bias1[nt];
                            acc[nt][rg] = a;
                            s += a; q += a*a;
                        }
                        s = red16(s);
                        q = red16(q);
                        const float mu = s * (1.f/H);
                        const float var = q * (1.f/H) - mu*mu;
                        const float rs = rsqrtf(var + LN_EPS);
                        const float murs = mu * rs;
                        float p0 = 0.f, p1 = 0.f;
                        #pragma unroll
                        for (int nt = 0; nt < 8; ++nt) {
                            float v = fmaf(fmaf(acc[nt][rg], rs, -murs), lng[nt], lnb[nt]);
                            v = fmaxf(v, 0.f);
                            p0 = fmaf(v, w2a[nt], p0);
                            p1 = fmaf(v, w2b[nt], p1);
                        }
                        p0 = red16(p0);
                        p1 = red16(p1);
                        float v0 = p0 + b2_0;
                        float v1 = p1 + b2_1;
                        if (hd) {
                            v0 = elu1(v0);
                            v1 = elu1(v1);
                        }
                        pend[rg] = make_float2(v0, v1);
                    }
                }
                __syncthreads();                       // B-step
                rd_off ^= 8704;
            }
            if (ln == 0) {
                #pragma unroll
                for (int rg = 0; rg < 4; ++rg) {
                    const int b = lb0 + mrow + lg*4 + rg;
                    *(float2*)(traj + ((size_t)b * T_STEPS + (T_STEPS - 1)) * 4 + hd*2) = pend[rg];
                }
            }
        }
    }

    // ======================= Phase 2: pi pair =======================
    {
        const int sub  = tid >> 8;
        const int stid = tid & 255;
        const int w4 = stid >> 6;

        short (*inbf)[264] = (short(*)[264])(smraw + PI_INBF_OFF + (size_t)sub*16896);
        short (*h1bf)[136] = (short(*)[136])(smraw + PI_H1_OFF   + (size_t)sub*8704);
        float (*redL)[32][2] = (float(*)[32][2])(smraw + PI_REDL_OFF + (size_t)sub*1024);
        float (*red3)[32]    = (float(*)[32])(smraw + PI_RED3_OFF + (size_t)sub*512);

        bf16x8 wf1[2][8];
        bf16x8 wf2[2][4];
        float b1[2], g1[2], bb1[2], b2[2], g2[2], bb2[2], w3[2];
        #pragma unroll
        for (int nt = 0; nt < 2; ++nt) {
            const int c = 32*w4 + 16*nt + ln;
            #pragma unroll
            for (int kt = 0; kt < 8; ++kt)
                wf1[nt][kt] = load8_cvt(pi1_w + (size_t)c * (2*H) + kt*32 + lg*8);
            #pragma unroll
            for (int kt = 0; kt < 4; ++kt)
                wf2[nt][kt] = load8_cvt(pi2_w + (size_t)c * H + kt*32 + lg*8);
            b1[nt] = pi1_b[c]; g1[nt] = ln1_g[c]; bb1[nt] = ln1_b[c];
            b2[nt] = pi2_b[c]; g2[nt] = ln2_g[c]; bb2[nt] = ln2_b[c];
            w3[nt] = pi3_w[c];
        }
        const float b3 = pi3_b[0];

        const int r0 = ((int)blockIdx.x*2 + sub) * 32;
        __syncthreads();          // phase-1 LDS fully retired (both roles synced)
        {
            const int r   = stid >> 3;
            const int seg = stid & 7;
            const int b = r0 + r;
            const int n = b & (N_AG - 1);
            const float* src = (seg < 4) ? (local_embed + (size_t)n * H + seg * 32)
                                         : (global_embed + (size_t)b * I_DIM + (seg - 4) * 32);
            #pragma unroll
            for (int i = 0; i < 4; ++i) {
                const float4 a = ((const float4*)src)[2*i];
                const float4 c = ((const float4*)src)[2*i+1];
                *(uint4*)&inbf[r][seg*32 + i*8] = pack8(a, c);
            }
        }
        __syncthreads();

        f32x4 acc1[2][2];
        #pragma unroll
        for (int m = 0; m < 2; ++m) {
            #pragma unroll
            for (int nt = 0; nt < 2; ++nt) acc1[m][nt] = (f32x4)(0.f);
            bf16x8 af[8];
            #pragma unroll
            for (int kt = 0; kt < 8; ++kt)
                af[kt] = *(const bf16x8*)&inbf[m*16 + ln][kt*32 + lg*8];
            #pragma unroll
            for (int kt = 0; kt < 8; ++kt)
                #pragma unroll
                for (int nt = 0; nt < 2; ++nt)
                    acc1[m][nt] = MFMA16x16x32(af[kt], wf1[nt][kt], acc1[m][nt]);
        }

        #pragma unroll
        for (int m = 0; m < 2; ++m)
            #pragma unroll
            for (int rg = 0; rg < 4; ++rg) {
                float s = 0.f, q = 0.f;
                #pragma unroll
                for (int nt = 0; nt < 2; ++nt) {
                    const float a = acc1[m][nt][rg] + b1[nt];
                    acc1[m][nt][rg] = a;
                    s += a; q += a*a;
                }
                s = red16(s);
                q = red16(q);
                if (ln == 0) {
                    const int row = m*16 + lg*4 + rg;
                    redL[w4][row][0] = s;
                    redL[w4][row][1] = q;
                }
            }
        __syncthreads();

        #pragma unroll
        for (int m = 0; m < 2; ++m)
            #pragma unroll
            for (int rg = 0; rg < 4; ++rg) {
                const int row = m*16 + lg*4 + rg;
                const float S = redL[0][row][0] + redL[1][row][0] + redL[2][row][0] + redL[3][row][0];
                const float Q = redL[0][row][1] + redL[1][row][1] + redL[2][row][1] + redL[3][row][1];
                const float mu = S * (1.f/H);
                const float var = Q * (1.f/H) - mu*mu;
                const float rs = rsqrtf(var + LN_EPS);
                #pragma unroll
                for (int nt = 0; nt < 2; ++nt) {
                    const float v = fmaxf((acc1[m][nt][rg] - mu) * rs * g1[nt] + bb1[nt], 0.f);
                    h1bf[row][32*w4 + 16*nt + ln] = f2b(v);
                }
            }
        __syncthreads();

        f32x4 acc2[2][2];
        #pragma unroll
        for (int m = 0; m < 2; ++m) {
            #pragma unroll
            for (int nt = 0; nt < 2; ++nt) acc2[m][nt] = (f32x4)(0.f);
            bf16x8 af[4];
            #pragma unroll
            for (int kt = 0; kt < 4; ++kt)
                af[kt] = *(const bf16x8*)&h1bf[m*16 + ln][kt*32 + lg*8];
            #pragma unroll
            for (int kt = 0; kt < 4; ++kt)
                #pragma unroll
                for (int nt = 0; nt < 2; ++nt)
                    acc2[m][nt] = MFMA16x16x32(af[kt], wf2[nt][kt], acc2[m][nt]);
        }

        #pragma unroll
        for (int m = 0; m < 2; ++m)
            #pragma unroll
            for (int rg = 0; rg < 4; ++rg) {
                float s = 0.f, q = 0.f;
                #pragma unroll
                for (int nt = 0; nt < 2; ++nt) {
                    const float a = acc2[m][nt][rg] + b2[nt];
                    acc2[m][nt][rg] = a;
                    s += a; q += a*a;
                }
                s = red16(s);
                q = red16(q);
                if (ln == 0) {
                    const int row = m*16 + lg*4 + rg;
                    redL[w4][row][0] = s;
                    redL[w4][row][1] = q;
                }
            }
        __syncthreads();

        #pragma unroll
        for (int m = 0; m < 2; ++m)
            #pragma unroll
            for (int rg = 0; rg < 4; ++rg) {
                const int row = m*16 + lg*4 + rg;
                const float S = redL[0][row][0] + redL[1][row][0] + redL[2][row][0] + redL[3][row][0];
                const float Q = redL[0][row][1] + redL[1][row][1] + redL[2][row][1] + redL[3][row][1];
                const float mu = S * (1.f/H);
                const float var = Q * (1.f/H) - mu*mu;
                const float rs = rsqrtf(var + LN_EPS);
                float p2 = 0.f;
                #pragma unroll
                for (int nt = 0; nt < 2; ++nt) {
                    const float v = fmaxf((acc2[m][nt][rg] - mu) * rs * g2[nt] + bb2[nt], 0.f);
                    p2 = fmaf(v, w3[nt], p2);
                }
                p2 = red16(p2);
                if (ln == 0) red3[w4][row] = p2;
            }
        __syncthreads();

        if (stid < 32) {
            const int row = stid;
            const float pv = red3[0][row] + red3[1][row] + red3[2][row] + red3[3][row] + b3;
            const int b = r0 + row;
            const int n = b & (N_AG - 1);
            const int m = b >> 13;
            pi_out[(size_t)n * M_MODES + m] = pv;
        }
    }
}

extern "C" void kernel_launch(void* const* d_in, const int* in_sizes, int n_in,
                              void* d_out, int out_size, void* d_ws, size_t ws_size,
                              hipStream_t stream) {
    (void)in_sizes; (void)n_in; (void)out_size; (void)d_ws; (void)ws_size;
    const float* local_embed  = (const float*)d_in[0];
    const float* global_embed = (const float*)d_in[1];
    const float* W_ih   = (const float*)d_in[2];
    const float* W_hh   = (const float*)d_in[3];
    const float* b_ih   = (const float*)d_in[4];
    const float* b_hh   = (const float*)d_in[5];
    const float* loc1_w = (const float*)d_in[6];
    const float* loc1_b = (const float*)d_in[7];
    const float* loc_ln_g = (const float*)d_in[8];
    const float* loc_ln_b = (const float*)d_in[9];
    const float* loc2_w = (const float*)d_in[10];
    const float* loc2_b = (const float*)d_in[11];
    const float* sc1_w  = (const float*)d_in[12];
    const float* sc1_b  = (const float*)d_in[13];
    const float* sc_ln_g = (const float*)d_in[14];
    const float* sc_ln_b = (const float*)d_in[15];
    const float* sc2_w  = (const float*)d_in[16];
    const float* sc2_b  = (const float*)d_in[17];
    const float* pi1_w  = (const float*)d_in[18];
    const float* pi1_b  = (const float*)d_in[19];
    const float* pi_ln1_g = (const float*)d_in[20];
    const float* pi_ln1_b = (const float*)d_in[21];
    const float* pi2_w  = (const float*)d_in[22];
    const float* pi2_b  = (const float*)d_in[23];
    const float* pi_ln2_g = (const float*)d_in[24];
    const float* pi_ln2_b = (const float*)d_in[25];
    const float* pi3_w  = (const float*)d_in[26];
    const float* pi3_b  = (const float*)d_in[27];

    float* traj = (float*)d_out;
    float* pi_out = traj + (size_t)B_TOT * T_STEPS * 4;

    const int ntiles = B_TOT / 32;   // 1536
    const int F = 768;               // 2 GRU/heads tiles + 1 pi pair per block

    fused_kernel<<<F, 512, 0, stream>>>(
        local_embed, global_embed, W_ih, W_hh, b_ih, b_hh,
        ntiles, F,
        loc1_w, loc1_b, loc_ln_g, loc_ln_b, loc2_w, loc2_b,
        sc1_w, sc1_b, sc_ln_g, sc_ln_b, sc2_w, sc2_b, traj,
        pi1_w, pi1_b, pi_ln1_g, pi_ln1_b,
        pi2_w, pi2_b, pi_ln2_g, pi_ln2_b, pi3_w, pi3_b, pi_out);
}